// Round 3
// baseline (1650.413 us; speedup 1.0000x reference)
//
#include <hip/hip_runtime.h>

// PointNet++ Set Abstraction for MI355X (gfx950).
// prep -> FPS -> ball-query -> L0(mfma) -> stat -> L1 -> stat -> L2(+pool) -> stat -> final.
// FPS replicates reference f32 elementwise arithmetic exactly (non-FMA, same order).
// Ball-query dot uses an FMA chain replicating BLAS sgemm accumulation (the np
// reference lowers einsum -> matmul -> BLAS). Activations stored f32 (in-place
// buffer reused across layers); GEMMs use hi/lo split-bf16 MFMA (near-f32).

typedef __bf16 bf16x8 __attribute__((ext_vector_type(8)));
typedef float f32x4 __attribute__((ext_vector_type(4)));

#define B_ 16
#define N_ 8192
#define S_ 1024
#define K_ 32
#define M_ 524288   // B*S*K rows
#define NBLK_ 4096  // M/128

__device__ __forceinline__ f32x4 mfma16(bf16x8 a, bf16x8 b, f32x4 c) {
  return __builtin_amdgcn_mfma_f32_16x16x32_bf16(a, b, c, 0, 0, 0);
}

__device__ __forceinline__ void split8(const float* v, bf16x8& hi, bf16x8& lo) {
#pragma unroll
  for (int e = 0; e < 8; ++e) {
    __bf16 h = (__bf16)v[e];
    hi[e] = h;
    lo[e] = (__bf16)(v[e] - (float)h);
  }
}

// ---------------- prep: SoA xyz, |p|^2, hi/lo split weights ----------------
__global__ __launch_bounds__(256) void prep_kernel(
    const float* __restrict__ xyz, const float* __restrict__ w0,
    const float* __restrict__ w1, const float* __restrict__ w2,
    float* __restrict__ sox, float* __restrict__ soy, float* __restrict__ soz,
    float* __restrict__ pp,
    __bf16* __restrict__ w0h, __bf16* __restrict__ w0l,
    __bf16* __restrict__ w1h, __bf16* __restrict__ w1l,
    __bf16* __restrict__ w2h, __bf16* __restrict__ w2l) {
#pragma clang fp contract(off)
  int gid = blockIdx.x * 256 + threadIdx.x;
  if (gid < B_ * N_) {
    float x = xyz[gid * 3 + 0], y = xyz[gid * 3 + 1], z = xyz[gid * 3 + 2];
    sox[gid] = x; soy[gid] = y; soz[gid] = z;
    pp[gid] = (x * x + y * y) + z * z;  // exact reference order
  } else {
    int j = gid - B_ * N_;
    float v; __bf16* ph; __bf16* pl; int jj;
    if (j < 6656) {            // W0: [64][104], real c<67
      int o = j / 104, c = j % 104;
      v = (c < 67) ? w0[o * 67 + c] : 0.f; ph = w0h; pl = w0l; jj = j;
    } else if (j < 6656 + 4608) {  // W1: [64][72], real c<64
      jj = j - 6656;
      int o = jj / 72, c = jj % 72;
      v = (c < 64) ? w1[o * 64 + c] : 0.f; ph = w1h; pl = w1l;
    } else if (j < 6656 + 4608 + 9216) {  // W2: [128][72]
      jj = j - 6656 - 4608;
      int o = jj / 72, c = jj % 72;
      v = (c < 64) ? w2[o * 64 + c] : 0.f; ph = w2h; pl = w2l;
    } else return;
    __bf16 h = (__bf16)v;
    ph[jj] = h;
    pl[jj] = (__bf16)(v - (float)h);
  }
}

// ---------------- FPS: one block per batch ----------------
__global__ __launch_bounds__(1024) void fps_kernel(
    const float* __restrict__ sox, const float* __restrict__ soy,
    const float* __restrict__ soz, float* __restrict__ out /* new_xyz (B,S,3) */) {
#pragma clang fp contract(off)
  const int b = blockIdx.x;
  const int t = threadIdx.x;
  __shared__ float sx[N_], sy[N_], sz[N_];
  __shared__ unsigned long long wkey[16];
  __shared__ unsigned long long winner_s;
  const size_t base = (size_t)b * N_;
  for (int i = t; i < N_; i += 1024) { sx[i] = sox[base + i]; sy[i] = soy[base + i]; sz[i] = soz[base + i]; }
  __syncthreads();
  float px[8], py[8], pz[8], dist[8];
#pragma unroll
  for (int w = 0; w < 8; ++w) {
    int i = t + w * 1024;
    px[w] = sx[i]; py[w] = sy[i]; pz[w] = sz[i];
    dist[w] = 1e10f;
  }
  const int lane = t & 63, wid = t >> 6;
  float* outB = out + (size_t)b * S_ * 3;
  int far = 0;
  for (int s = 0; s < S_; ++s) {
    float cx = sx[far], cy = sy[far], cz = sz[far];
    if (t == 0) { outB[s * 3 + 0] = cx; outB[s * 3 + 1] = cy; outB[s * 3 + 2] = cz; }
    float bv = -1.0f; int bi = 0;
#pragma unroll
    for (int w = 0; w < 8; ++w) {
      float dx = px[w] - cx, dy = py[w] - cy, dz = pz[w] - cz;
      float d = (dx * dx + dy * dy) + dz * dz;   // exact reference order, no fma
      float nd = fminf(dist[w], d);
      dist[w] = nd;
      if (nd > bv) { bv = nd; bi = t + w * 1024; }  // strict > keeps first (lowest) idx
    }
    unsigned long long key =
        ((unsigned long long)__float_as_uint(bv) << 32) |
        (unsigned long long)(0xFFFFFFFFu - (unsigned)bi);
#pragma unroll
    for (int off = 32; off >= 1; off >>= 1) {
      unsigned long long o = __shfl_xor(key, off, 64);
      if (o > key) key = o;
    }
    if (lane == 0) wkey[wid] = key;
    __syncthreads();
    if (wid == 0) {
      unsigned long long k2 = wkey[lane & 15];
#pragma unroll
      for (int off = 8; off >= 1; off >>= 1) {
        unsigned long long o = __shfl_xor(k2, off, 64);
        if (o > k2) k2 = o;
      }
      if (lane == 0) winner_s = k2;
    }
    __syncthreads();
    far = (int)(0xFFFFFFFFu - (unsigned)(winner_s & 0xFFFFFFFFull));
  }
}

// ---------------- ball query: 16 queries per block ----------------
__global__ __launch_bounds__(1024) void ballq_kernel(
    const float* __restrict__ sox, const float* __restrict__ soy,
    const float* __restrict__ soz, const float* __restrict__ pp,
    const float* __restrict__ newxyz, int* __restrict__ idxout) {
#pragma clang fp contract(off)
  __shared__ float sx[N_], sy[N_], sz[N_], sp[N_];
  __shared__ int sel[16][32];
  const int t = threadIdx.x;
  const int g = blockIdx.x;
  const int b = g >> 6;
  const int q0 = (g & 63) << 4;
  const size_t base = (size_t)b * N_;
  {
    const float4* fx = (const float4*)(sox + base);
    const float4* fy = (const float4*)(soy + base);
    const float4* fz = (const float4*)(soz + base);
    const float4* fp = (const float4*)(pp + base);
    for (int i = t; i < N_ / 4; i += 1024) {
      ((float4*)sx)[i] = fx[i]; ((float4*)sy)[i] = fy[i];
      ((float4*)sz)[i] = fz[i]; ((float4*)sp)[i] = fp[i];
    }
  }
  __syncthreads();
  const int wid = t >> 6, lane = t & 63;
  const int q = q0 + wid;
  const float* qp = newxyz + ((size_t)b * S_ + q) * 3;
  const float qx = qp[0], qy = qp[1], qz = qp[2];
  const float qq = (qx * qx + qy * qy) + qz * qz;
  const float rr = (float)(0.4 * 0.4);
  int nsel = 0;
  for (int c0 = 0; c0 < N_ && nsel < 32; c0 += 64) {
    int i = c0 + lane;
    // BLAS-style FMA accumulation chain (matches einsum->matmul lowering):
    float dot = fmaf(qz, sz[i], fmaf(qy, sy[i], qx * sx[i]));
    float d = -2.0f * dot;
    d = d + qq;
    d = d + sp[i];
    unsigned long long m = __ballot(!(d > rr));
    if ((m >> lane) & 1ull) {
      int rank = nsel + __popcll(m & ((1ull << lane) - 1ull));
      if (rank < 32) sel[wid][rank] = i;
    }
    nsel += __popcll(m);
  }
  __syncthreads();
  int nv = nsel < 32 ? nsel : 32;
  int first = sel[wid][0];
  if (lane < 32)
    idxout[(((size_t)b * S_ + q) << 5) + lane] = (lane < nv) ? sel[wid][lane] : first;
}

// ---------------- layer 0: gather+concat -> split GEMM 67->64 (K padded 96) ----------------
__global__ __launch_bounds__(256) void layer0_kernel(
    const float* __restrict__ sox, const float* __restrict__ soy,
    const float* __restrict__ soz, const float* __restrict__ points,
    const float* __restrict__ newxyz, const int* __restrict__ idx,
    const __bf16* __restrict__ wh, const __bf16* __restrict__ wl,
    float* __restrict__ yout, float* __restrict__ partial) {
  __shared__ __align__(16) __bf16 Ah[128 * 104];
  __shared__ __align__(16) __bf16 Al[128 * 104];
  __shared__ __align__(16) __bf16 Bh[64 * 104];
  __shared__ __align__(16) __bf16 Bl[64 * 104];
  __shared__ float swsum[4][64], swsq[4][64];
  const int t = threadIdx.x;
  const int blk = blockIdx.x;
  const size_t row0 = (size_t)blk * 128;
  {
    const int4* sh4 = (const int4*)wh;
    const int4* sl4 = (const int4*)wl;
    int4* dh4 = (int4*)Bh;
    int4* dl4 = (int4*)Bl;
    for (int k = t; k < 832; k += 256) { dh4[k] = sh4[k]; dl4[k] = sl4[k]; }
  }
  {
    const int r = t >> 1, half = t & 1;
    const size_t row = row0 + r;
    const int b = (int)(row >> 15);
    const int s = (int)((row >> 5) & 1023);
    const int i = idx[row];
    const size_t bi = (size_t)b * N_ + i;
    const float* pt = points + bi * 64;
    const float* nx = newxyz + ((size_t)b * S_ + s) * 3;
    const int jb = half ? 6 : 0, je = half ? 13 : 6;
    float gx = 0.f, gy = 0.f, gz = 0.f;
    if (!half) { gx = sox[bi] - nx[0]; gy = soy[bi] - nx[1]; gz = soz[bi] - nx[2]; }
#pragma unroll 13
    for (int j = jb; j < je; ++j) {
      float v[8];
#pragma unroll
      for (int e = 0; e < 8; ++e) {
        const int c = j * 8 + e;
        v[e] = (c == 0) ? gx : (c == 1) ? gy : (c == 2) ? gz
               : (c < 67) ? pt[c - 3] : 0.f;
      }
      bf16x8 hi, lo;
      split8(v, hi, lo);
      *(bf16x8*)(Ah + r * 104 + j * 8) = hi;
      *(bf16x8*)(Al + r * 104 + j * 8) = lo;
    }
  }
  __syncthreads();
  const int wid = t >> 6, lane = t & 63;
  const int wrow = wid * 32;
  const int lrow = lane & 15, lk = (lane >> 4) * 8;
  f32x4 acc[2][4];
#pragma unroll
  for (int a_ = 0; a_ < 2; ++a_)
#pragma unroll
    for (int b_ = 0; b_ < 4; ++b_) acc[a_][b_] = (f32x4){0.f, 0.f, 0.f, 0.f};
#pragma unroll
  for (int ks = 0; ks < 3; ++ks) {
    const int ko = ks * 32 + lk;
    bf16x8 ah0 = *(const bf16x8*)(Ah + (wrow + lrow) * 104 + ko);
    bf16x8 al0 = *(const bf16x8*)(Al + (wrow + lrow) * 104 + ko);
    bf16x8 ah1 = *(const bf16x8*)(Ah + (wrow + 16 + lrow) * 104 + ko);
    bf16x8 al1 = *(const bf16x8*)(Al + (wrow + 16 + lrow) * 104 + ko);
#pragma unroll
    for (int cf = 0; cf < 4; ++cf) {
      bf16x8 bh = *(const bf16x8*)(Bh + (cf * 16 + lrow) * 104 + ko);
      bf16x8 bl = *(const bf16x8*)(Bl + (cf * 16 + lrow) * 104 + ko);
      acc[0][cf] = mfma16(ah0, bh, acc[0][cf]);
      acc[0][cf] = mfma16(al0, bh, acc[0][cf]);
      acc[0][cf] = mfma16(ah0, bl, acc[0][cf]);
      acc[1][cf] = mfma16(ah1, bh, acc[1][cf]);
      acc[1][cf] = mfma16(al1, bh, acc[1][cf]);
      acc[1][cf] = mfma16(ah1, bl, acc[1][cf]);
    }
  }
#pragma unroll
  for (int cf = 0; cf < 4; ++cf) {
    float s = 0.f, s2 = 0.f;
    const int col = cf * 16 + lrow;
#pragma unroll
    for (int rf = 0; rf < 2; ++rf) {
      const int rbase = wrow + rf * 16 + (lane >> 4) * 4;
#pragma unroll
      for (int q = 0; q < 4; ++q) {
        float v = acc[rf][cf][q];
        yout[(row0 + rbase + q) * 64 + col] = v;
        s += v; s2 += v * v;
      }
    }
    s += __shfl_xor(s, 16, 64); s += __shfl_xor(s, 32, 64);
    s2 += __shfl_xor(s2, 16, 64); s2 += __shfl_xor(s2, 32, 64);
    if ((lane >> 4) == 0) { swsum[wid][col] = s; swsq[wid][col] = s2; }
  }
  __syncthreads();
  if (t < 128) {
    const int c = t & 63;
    float v = (t < 64) ? (swsum[0][c] + swsum[1][c] + swsum[2][c] + swsum[3][c])
                       : (swsq[0][c] + swsq[1][c] + swsq[2][c] + swsq[3][c]);
    partial[(size_t)t * NBLK_ + blk] = v;
  }
}

// ---------------- stat: mean/var -> (a, shift) ----------------
__global__ __launch_bounds__(64) void stat_kernel(
    const float* __restrict__ partial, const float* __restrict__ g,
    const float* __restrict__ bt, float* __restrict__ ab, int nch) {
  const int o = blockIdx.x, t = threadIdx.x;
  float s = 0.f, s2 = 0.f;
  for (int i = t; i < NBLK_; i += 64) {
    s += partial[(size_t)o * NBLK_ + i];
    s2 += partial[(size_t)(nch + o) * NBLK_ + i];
  }
#pragma unroll
  for (int off = 32; off >= 1; off >>= 1) {
    s += __shfl_xor(s, off, 64);
    s2 += __shfl_xor(s2, off, 64);
  }
  if (t == 0) {
    const float minv = 1.0f / (float)M_;
    float mean = s * minv;
    float var = s2 * minv - mean * mean;
    float a = g[o] * rsqrtf(var + 1e-5f);
    ab[o] = a;
    ab[128 + o] = bt[o] - mean * a;
  }
}

// ---------------- layer 1: BN0+ReLU on load -> split GEMM 64->64 (in-place y) ----------------
__global__ __launch_bounds__(256) void layer1_kernel(
    float* y /* f32 activations, read rows then overwritten (same block) */,
    const __bf16* __restrict__ wh, const __bf16* __restrict__ wl,
    const float* __restrict__ ab, float* __restrict__ partial) {
  __shared__ __align__(16) __bf16 Ah[128 * 72];
  __shared__ __align__(16) __bf16 Al[128 * 72];
  __shared__ __align__(16) __bf16 Bh[64 * 72];
  __shared__ __align__(16) __bf16 Bl[64 * 72];
  __shared__ float sa[64], sb[64];
  __shared__ float swsum[4][64], swsq[4][64];
  const int t = threadIdx.x;
  const int blk = blockIdx.x;
  const size_t row0 = (size_t)blk * 128;
  if (t < 64) { sa[t] = ab[t]; sb[t] = ab[128 + t]; }
  {
    const int4* sh4 = (const int4*)wh;
    const int4* sl4 = (const int4*)wl;
    int4* dh4 = (int4*)Bh;
    int4* dl4 = (int4*)Bl;
    for (int k = t; k < 576; k += 256) { dh4[k] = sh4[k]; dl4[k] = sl4[k]; }
  }
  __syncthreads();
  {
    const int r = t >> 1, half = t & 1;
    const float4* s4 = (const float4*)(y + (row0 + r) * 64 + half * 32);
#pragma unroll
    for (int j = 0; j < 4; ++j) {
      float4 u = s4[j * 2], w = s4[j * 2 + 1];
      float v[8] = {u.x, u.y, u.z, u.w, w.x, w.y, w.z, w.w};
#pragma unroll
      for (int e = 0; e < 8; ++e) {
        const int c = half * 32 + j * 8 + e;
        v[e] = fmaxf(v[e] * sa[c] + sb[c], 0.f);
      }
      bf16x8 hi, lo;
      split8(v, hi, lo);
      *(bf16x8*)(Ah + r * 72 + half * 32 + j * 8) = hi;
      *(bf16x8*)(Al + r * 72 + half * 32 + j * 8) = lo;
    }
  }
  __syncthreads();
  const int wid = t >> 6, lane = t & 63;
  const int wrow = wid * 32;
  const int lrow = lane & 15, lk = (lane >> 4) * 8;
  f32x4 acc[2][4];
#pragma unroll
  for (int a_ = 0; a_ < 2; ++a_)
#pragma unroll
    for (int b_ = 0; b_ < 4; ++b_) acc[a_][b_] = (f32x4){0.f, 0.f, 0.f, 0.f};
#pragma unroll
  for (int ks = 0; ks < 2; ++ks) {
    const int ko = ks * 32 + lk;
    bf16x8 ah0 = *(const bf16x8*)(Ah + (wrow + lrow) * 72 + ko);
    bf16x8 al0 = *(const bf16x8*)(Al + (wrow + lrow) * 72 + ko);
    bf16x8 ah1 = *(const bf16x8*)(Ah + (wrow + 16 + lrow) * 72 + ko);
    bf16x8 al1 = *(const bf16x8*)(Al + (wrow + 16 + lrow) * 72 + ko);
#pragma unroll
    for (int cf = 0; cf < 4; ++cf) {
      bf16x8 bh = *(const bf16x8*)(Bh + (cf * 16 + lrow) * 72 + ko);
      bf16x8 bl = *(const bf16x8*)(Bl + (cf * 16 + lrow) * 72 + ko);
      acc[0][cf] = mfma16(ah0, bh, acc[0][cf]);
      acc[0][cf] = mfma16(al0, bh, acc[0][cf]);
      acc[0][cf] = mfma16(ah0, bl, acc[0][cf]);
      acc[1][cf] = mfma16(ah1, bh, acc[1][cf]);
      acc[1][cf] = mfma16(al1, bh, acc[1][cf]);
      acc[1][cf] = mfma16(ah1, bl, acc[1][cf]);
    }
  }
#pragma unroll
  for (int cf = 0; cf < 4; ++cf) {
    float s = 0.f, s2 = 0.f;
    const int col = cf * 16 + lrow;
#pragma unroll
    for (int rf = 0; rf < 2; ++rf) {
      const int rbase = wrow + rf * 16 + (lane >> 4) * 4;
#pragma unroll
      for (int q = 0; q < 4; ++q) {
        float v = acc[rf][cf][q];
        y[(row0 + rbase + q) * 64 + col] = v;
        s += v; s2 += v * v;
      }
    }
    s += __shfl_xor(s, 16, 64); s += __shfl_xor(s, 32, 64);
    s2 += __shfl_xor(s2, 16, 64); s2 += __shfl_xor(s2, 32, 64);
    if ((lane >> 4) == 0) { swsum[wid][col] = s; swsq[wid][col] = s2; }
  }
  __syncthreads();
  if (t < 128) {
    const int c = t & 63;
    float v = (t < 64) ? (swsum[0][c] + swsum[1][c] + swsum[2][c] + swsum[3][c])
                       : (swsq[0][c] + swsq[1][c] + swsq[2][c] + swsq[3][c]);
    partial[(size_t)t * NBLK_ + blk] = v;
  }
}

// ---------------- layer 2: BN1+ReLU -> split GEMM 64->128 + fused max/min pool ----------------
__global__ __launch_bounds__(256) void layer2_kernel(
    const float* __restrict__ yin, const __bf16* __restrict__ wh,
    const __bf16* __restrict__ wl, const float* __restrict__ ab,
    float* __restrict__ ymax, float* __restrict__ ymin,
    float* __restrict__ partial) {
  __shared__ __align__(16) __bf16 Ah[128 * 72];
  __shared__ __align__(16) __bf16 Al[128 * 72];
  __shared__ __align__(16) __bf16 Bh[128 * 72];
  __shared__ __align__(16) __bf16 Bl[128 * 72];
  __shared__ float sa[64], sb[64];
  __shared__ float swsum[4][128], swsq[4][128];
  const int t = threadIdx.x;
  const int blk = blockIdx.x;
  const size_t row0 = (size_t)blk * 128;
  if (t < 64) { sa[t] = ab[t]; sb[t] = ab[128 + t]; }
  {
    const int4* sh4 = (const int4*)wh;
    const int4* sl4 = (const int4*)wl;
    int4* dh4 = (int4*)Bh;
    int4* dl4 = (int4*)Bl;
    for (int k = t; k < 1152; k += 256) { dh4[k] = sh4[k]; dl4[k] = sl4[k]; }
  }
  __syncthreads();
  {
    const int r = t >> 1, half = t & 1;
    const float4* s4 = (const float4*)(yin + (row0 + r) * 64 + half * 32);
#pragma unroll
    for (int j = 0; j < 4; ++j) {
      float4 u = s4[j * 2], w = s4[j * 2 + 1];
      float v[8] = {u.x, u.y, u.z, u.w, w.x, w.y, w.z, w.w};
#pragma unroll
      for (int e = 0; e < 8; ++e) {
        const int c = half * 32 + j * 8 + e;
        v[e] = fmaxf(v[e] * sa[c] + sb[c], 0.f);
      }
      bf16x8 hi, lo;
      split8(v, hi, lo);
      *(bf16x8*)(Ah + r * 72 + half * 32 + j * 8) = hi;
      *(bf16x8*)(Al + r * 72 + half * 32 + j * 8) = lo;
    }
  }
  __syncthreads();
  const int wid = t >> 6, lane = t & 63;
  const int wrow = wid * 32;
  const int lrow = lane & 15, lk = (lane >> 4) * 8;
  f32x4 acc[2][8];
#pragma unroll
  for (int a_ = 0; a_ < 2; ++a_)
#pragma unroll
    for (int b_ = 0; b_ < 8; ++b_) acc[a_][b_] = (f32x4){0.f, 0.f, 0.f, 0.f};
#pragma unroll
  for (int ks = 0; ks < 2; ++ks) {
    const int ko = ks * 32 + lk;
    bf16x8 ah0 = *(const bf16x8*)(Ah + (wrow + lrow) * 72 + ko);
    bf16x8 al0 = *(const bf16x8*)(Al + (wrow + lrow) * 72 + ko);
    bf16x8 ah1 = *(const bf16x8*)(Ah + (wrow + 16 + lrow) * 72 + ko);
    bf16x8 al1 = *(const bf16x8*)(Al + (wrow + 16 + lrow) * 72 + ko);
#pragma unroll
    for (int cf = 0; cf < 8; ++cf) {
      bf16x8 bh = *(const bf16x8*)(Bh + (cf * 16 + lrow) * 72 + ko);
      bf16x8 bl = *(const bf16x8*)(Bl + (cf * 16 + lrow) * 72 + ko);
      acc[0][cf] = mfma16(ah0, bh, acc[0][cf]);
      acc[0][cf] = mfma16(al0, bh, acc[0][cf]);
      acc[0][cf] = mfma16(ah0, bl, acc[0][cf]);
      acc[1][cf] = mfma16(ah1, bh, acc[1][cf]);
      acc[1][cf] = mfma16(al1, bh, acc[1][cf]);
      acc[1][cf] = mfma16(ah1, bl, acc[1][cf]);
    }
  }
  // each wave's 32 rows form exactly one (b,s) group
  const size_t bs = (size_t)blk * 4 + wid;
#pragma unroll
  for (int cf = 0; cf < 8; ++cf) {
    float s = 0.f, s2 = 0.f, mx = -3.4e38f, mn = 3.4e38f;
    const int col = cf * 16 + lrow;
#pragma unroll
    for (int rf = 0; rf < 2; ++rf)
#pragma unroll
      for (int q = 0; q < 4; ++q) {
        float v = acc[rf][cf][q];
        s += v; s2 += v * v;
        mx = fmaxf(mx, v); mn = fminf(mn, v);
      }
    s += __shfl_xor(s, 16, 64); s += __shfl_xor(s, 32, 64);
    s2 += __shfl_xor(s2, 16, 64); s2 += __shfl_xor(s2, 32, 64);
    mx = fmaxf(mx, __shfl_xor(mx, 16, 64)); mx = fmaxf(mx, __shfl_xor(mx, 32, 64));
    mn = fminf(mn, __shfl_xor(mn, 16, 64)); mn = fminf(mn, __shfl_xor(mn, 32, 64));
    if ((lane >> 4) == 0) {
      ymax[bs * 128 + col] = mx;
      ymin[bs * 128 + col] = mn;
      swsum[wid][col] = s; swsq[wid][col] = s2;
    }
  }
  __syncthreads();
  if (t < 128) {
    float v = swsum[0][t] + swsum[1][t] + swsum[2][t] + swsum[3][t];
    partial[(size_t)t * NBLK_ + blk] = v;
  } else {
    const int c = t - 128;
    float v = swsq[0][c] + swsq[1][c] + swsq[2][c] + swsq[3][c];
    partial[(size_t)t * NBLK_ + blk] = v;
  }
}

// ---------------- final: BN2+ReLU on pooled values ----------------
__global__ __launch_bounds__(256) void final_kernel(
    const float* __restrict__ ymax, const float* __restrict__ ymin,
    const float* __restrict__ ab, float* __restrict__ out) {
  const int gid = blockIdx.x * 256 + threadIdx.x;  // B*S*128
  const int col = gid & 127;
  const float a = ab[col];
  const float v = (a >= 0.f) ? ymax[gid] : ymin[gid];  // monotonicity of BN+ReLU vs sign(a)
  out[gid] = fmaxf(v * a + ab[128 + col], 0.f);
}

extern "C" void kernel_launch(void* const* d_in, const int* in_sizes, int n_in,
                              void* d_out, int out_size, void* d_ws, size_t ws_size,
                              hipStream_t stream) {
  const float* xyz = (const float*)d_in[0];
  const float* points = (const float*)d_in[1];
  const float* w0 = (const float*)d_in[2];
  const float* g0 = (const float*)d_in[4];
  const float* bt0 = (const float*)d_in[5];
  const float* w1 = (const float*)d_in[6];
  const float* g1 = (const float*)d_in[8];
  const float* bt1 = (const float*)d_in[9];
  const float* w2 = (const float*)d_in[10];
  const float* g2 = (const float*)d_in[12];
  const float* bt2 = (const float*)d_in[13];
  float* out = (float*)d_out;
  char* ws = (char*)d_ws;

  float* sox = (float*)(ws + 0);
  float* soy = (float*)(ws + 524288);
  float* soz = (float*)(ws + 1048576);
  float* pp  = (float*)(ws + 1572864);
  __bf16* w0h = (__bf16*)(ws + 2097152);   // 13312 B
  __bf16* w0l = (__bf16*)(ws + 2110464);
  __bf16* w1h = (__bf16*)(ws + 2123776);   // 9216 B
  __bf16* w1l = (__bf16*)(ws + 2132992);
  __bf16* w2h = (__bf16*)(ws + 2142208);   // 18432 B
  __bf16* w2l = (__bf16*)(ws + 2160640);
  int* idx    = (int*)(ws + 2179072);      // 2 MB
  float* y    = (float*)(ws + 4276224);    // 134217728 B (f32, reused L0->L1 in place)
  float* ymax = (float*)(ws + 138493952);  // 8388608
  float* ymin = (float*)(ws + 146882560);  // 8388608
  float* partial = (float*)(ws + 155271168); // 4194304
  float* ab   = (float*)(ws + 159465472);  // 3072
  if (ws_size < 159468544) return;

  prep_kernel<<<592, 256, 0, stream>>>(xyz, w0, w1, w2, sox, soy, soz, pp,
                                       w0h, w0l, w1h, w1l, w2h, w2l);
  fps_kernel<<<16, 1024, 0, stream>>>(sox, soy, soz, out);
  ballq_kernel<<<1024, 1024, 0, stream>>>(sox, soy, soz, pp, out, idx);
  layer0_kernel<<<NBLK_, 256, 0, stream>>>(sox, soy, soz, points, out, idx, w0h, w0l, y, partial);
  stat_kernel<<<64, 64, 0, stream>>>(partial, g0, bt0, ab, 64);
  layer1_kernel<<<NBLK_, 256, 0, stream>>>(y, w1h, w1l, ab, partial);
  stat_kernel<<<64, 64, 0, stream>>>(partial, g1, bt1, ab + 256, 64);
  layer2_kernel<<<NBLK_, 256, 0, stream>>>(y, w2h, w2l, ab + 256, ymax, ymin, partial);
  stat_kernel<<<128, 64, 0, stream>>>(partial, g2, bt2, ab + 512, 128);
  final_kernel<<<8192, 256, 0, stream>>>(ymax, ymin, ab + 512, out + 49152);
}

// Round 4
// 1623.721 us; speedup vs baseline: 1.0164x; 1.0164x over previous
//
#include <hip/hip_runtime.h>

// PointNet++ Set Abstraction for MI355X (gfx950).
// prep -> FPS -> ball-query -> L0(mfma) -> stat -> L1 -> stat -> L2(+pool) -> stat -> final.
// FPS replicates reference f32 elementwise arithmetic exactly (non-FMA, same order).
// Ball-query dot uses an FMA chain replicating BLAS sgemm accumulation.
// Activations stored f32; GEMMs use hi/lo split-bf16 MFMA (near-f32).
// R3: FPS argmax restructured — contiguous per-lane point chunks, f32-only wave
// reduce + ballot/ffs index pick, single barrier + redundant 16-key scan with
// double-buffered LDS keys. Exact first-argmax semantics preserved.

typedef __bf16 bf16x8 __attribute__((ext_vector_type(8)));
typedef float f32x4 __attribute__((ext_vector_type(4)));

#define B_ 16
#define N_ 8192
#define S_ 1024
#define K_ 32
#define M_ 524288   // B*S*K rows
#define NBLK_ 4096  // M/128

__device__ __forceinline__ f32x4 mfma16(bf16x8 a, bf16x8 b, f32x4 c) {
  return __builtin_amdgcn_mfma_f32_16x16x32_bf16(a, b, c, 0, 0, 0);
}

__device__ __forceinline__ void split8(const float* v, bf16x8& hi, bf16x8& lo) {
#pragma unroll
  for (int e = 0; e < 8; ++e) {
    __bf16 h = (__bf16)v[e];
    hi[e] = h;
    lo[e] = (__bf16)(v[e] - (float)h);
  }
}

// ---------------- prep: SoA xyz, |p|^2, hi/lo split weights ----------------
__global__ __launch_bounds__(256) void prep_kernel(
    const float* __restrict__ xyz, const float* __restrict__ w0,
    const float* __restrict__ w1, const float* __restrict__ w2,
    float* __restrict__ sox, float* __restrict__ soy, float* __restrict__ soz,
    float* __restrict__ pp,
    __bf16* __restrict__ w0h, __bf16* __restrict__ w0l,
    __bf16* __restrict__ w1h, __bf16* __restrict__ w1l,
    __bf16* __restrict__ w2h, __bf16* __restrict__ w2l) {
#pragma clang fp contract(off)
  int gid = blockIdx.x * 256 + threadIdx.x;
  if (gid < B_ * N_) {
    float x = xyz[gid * 3 + 0], y = xyz[gid * 3 + 1], z = xyz[gid * 3 + 2];
    sox[gid] = x; soy[gid] = y; soz[gid] = z;
    pp[gid] = (x * x + y * y) + z * z;  // exact reference order
  } else {
    int j = gid - B_ * N_;
    float v; __bf16* ph; __bf16* pl; int jj;
    if (j < 6656) {            // W0: [64][104], real c<67
      int o = j / 104, c = j % 104;
      v = (c < 67) ? w0[o * 67 + c] : 0.f; ph = w0h; pl = w0l; jj = j;
    } else if (j < 6656 + 4608) {  // W1: [64][72], real c<64
      jj = j - 6656;
      int o = jj / 72, c = jj % 72;
      v = (c < 64) ? w1[o * 64 + c] : 0.f; ph = w1h; pl = w1l;
    } else if (j < 6656 + 4608 + 9216) {  // W2: [128][72]
      jj = j - 6656 - 4608;
      int o = jj / 72, c = jj % 72;
      v = (c < 64) ? w2[o * 64 + c] : 0.f; ph = w2h; pl = w2l;
    } else return;
    __bf16 h = (__bf16)v;
    ph[jj] = h;
    pl[jj] = (__bf16)(v - (float)h);
  }
}

// ---------------- FPS: one block per batch ----------------
__global__ __launch_bounds__(1024) void fps_kernel(
    const float* __restrict__ sox, const float* __restrict__ soy,
    const float* __restrict__ soz, float* __restrict__ out /* new_xyz (B,S,3) */) {
#pragma clang fp contract(off)
  const int b = blockIdx.x;
  const int t = threadIdx.x;
  __shared__ float sx[N_], sy[N_], sz[N_];
  __shared__ unsigned long long wkey[2][16];
  const size_t base = (size_t)b * N_;
  {
    const float4* fx = (const float4*)(sox + base);
    const float4* fy = (const float4*)(soy + base);
    const float4* fz = (const float4*)(soz + base);
    for (int i = t; i < N_ / 4; i += 1024) {
      ((float4*)sx)[i] = fx[i]; ((float4*)sy)[i] = fy[i]; ((float4*)sz)[i] = fz[i];
    }
  }
  __syncthreads();
  // contiguous chunk per lane: thread t owns points [8t, 8t+8)
  float px[8], py[8], pz[8], dist[8];
  const int i0 = t * 8;
#pragma unroll
  for (int w = 0; w < 8; ++w) {
    px[w] = sx[i0 + w]; py[w] = sy[i0 + w]; pz[w] = sz[i0 + w];
    dist[w] = 1e10f;
  }
  const int lane = t & 63, wid = t >> 6;
  float* outB = out + (size_t)b * S_ * 3;
  int far = 0;
  for (int s = 0; s < S_; ++s) {
    float cx = sx[far], cy = sy[far], cz = sz[far];
    if (t == 0) { outB[s * 3 + 0] = cx; outB[s * 3 + 1] = cy; outB[s * 3 + 2] = cz; }
    float bv = -1.0f; int bi = 0;
#pragma unroll
    for (int w = 0; w < 8; ++w) {
      float dx = px[w] - cx, dy = py[w] - cy, dz = pz[w] - cz;
      float d = (dx * dx + dy * dy) + dz * dz;   // exact reference order, no fma
      float nd = fminf(dist[w], d);
      dist[w] = nd;
      if (nd > bv) { bv = nd; bi = i0 + w; }  // strict >: first (lowest) local idx
    }
    // wave-wide max on value only (f32 shuffles)
    float m = bv;
#pragma unroll
    for (int off = 32; off >= 1; off >>= 1) m = fmaxf(m, __shfl_xor(m, off, 64));
    // lowest lane holding the max -> lowest global index within this wave
    unsigned long long msk = __ballot(bv == m);
    int src = __ffsll(msk) - 1;
    int wbi = __shfl(bi, src, 64);
    if (lane == 0)
      wkey[s & 1][wid] = ((unsigned long long)__float_as_uint(m) << 32) | (unsigned)wbi;
    __syncthreads();
    // every thread scans the 16 wave keys (broadcast reads); ascending wave
    // order + strict > keeps the first-argmax index. Double buffer makes the
    // single-barrier scheme race-free.
    unsigned long long best = wkey[s & 1][0];
#pragma unroll
    for (int w = 1; w < 16; ++w) {
      unsigned long long k = wkey[s & 1][w];
      if ((k >> 32) > (best >> 32)) best = k;
    }
    far = (int)(best & 0xFFFFFFFFull);
  }
}

// ---------------- ball query: 16 queries per block ----------------
__global__ __launch_bounds__(1024) void ballq_kernel(
    const float* __restrict__ sox, const float* __restrict__ soy,
    const float* __restrict__ soz, const float* __restrict__ pp,
    const float* __restrict__ newxyz, int* __restrict__ idxout) {
#pragma clang fp contract(off)
  __shared__ float sx[N_], sy[N_], sz[N_], sp[N_];
  __shared__ int sel[16][32];
  const int t = threadIdx.x;
  const int g = blockIdx.x;
  const int b = g >> 6;
  const int q0 = (g & 63) << 4;
  const size_t base = (size_t)b * N_;
  {
    const float4* fx = (const float4*)(sox + base);
    const float4* fy = (const float4*)(soy + base);
    const float4* fz = (const float4*)(soz + base);
    const float4* fp = (const float4*)(pp + base);
    for (int i = t; i < N_ / 4; i += 1024) {
      ((float4*)sx)[i] = fx[i]; ((float4*)sy)[i] = fy[i];
      ((float4*)sz)[i] = fz[i]; ((float4*)sp)[i] = fp[i];
    }
  }
  __syncthreads();
  const int wid = t >> 6, lane = t & 63;
  const int q = q0 + wid;
  const float* qp = newxyz + ((size_t)b * S_ + q) * 3;
  const float qx = qp[0], qy = qp[1], qz = qp[2];
  const float qq = (qx * qx + qy * qy) + qz * qz;
  const float rr = (float)(0.4 * 0.4);
  int nsel = 0;
  for (int c0 = 0; c0 < N_ && nsel < 32; c0 += 64) {
    int i = c0 + lane;
    // BLAS-style FMA accumulation chain (matches einsum->matmul lowering):
    float dot = fmaf(qz, sz[i], fmaf(qy, sy[i], qx * sx[i]));
    float d = -2.0f * dot;
    d = d + qq;
    d = d + sp[i];
    unsigned long long m = __ballot(!(d > rr));
    if ((m >> lane) & 1ull) {
      int rank = nsel + __popcll(m & ((1ull << lane) - 1ull));
      if (rank < 32) sel[wid][rank] = i;
    }
    nsel += __popcll(m);
  }
  __syncthreads();
  int nv = nsel < 32 ? nsel : 32;
  int first = sel[wid][0];
  if (lane < 32)
    idxout[(((size_t)b * S_ + q) << 5) + lane] = (lane < nv) ? sel[wid][lane] : first;
}

// ---------------- layer 0: gather+concat -> split GEMM 67->64 (K padded 96) ----------------
__global__ __launch_bounds__(256) void layer0_kernel(
    const float* __restrict__ sox, const float* __restrict__ soy,
    const float* __restrict__ soz, const float* __restrict__ points,
    const float* __restrict__ newxyz, const int* __restrict__ idx,
    const __bf16* __restrict__ wh, const __bf16* __restrict__ wl,
    float* __restrict__ yout, float* __restrict__ partial) {
  __shared__ __align__(16) __bf16 Ah[128 * 104];
  __shared__ __align__(16) __bf16 Al[128 * 104];
  __shared__ __align__(16) __bf16 Bh[64 * 104];
  __shared__ __align__(16) __bf16 Bl[64 * 104];
  __shared__ float swsum[4][64], swsq[4][64];
  const int t = threadIdx.x;
  const int blk = blockIdx.x;
  const size_t row0 = (size_t)blk * 128;
  {
    const int4* sh4 = (const int4*)wh;
    const int4* sl4 = (const int4*)wl;
    int4* dh4 = (int4*)Bh;
    int4* dl4 = (int4*)Bl;
    for (int k = t; k < 832; k += 256) { dh4[k] = sh4[k]; dl4[k] = sl4[k]; }
  }
  {
    const int r = t >> 1, half = t & 1;
    const size_t row = row0 + r;
    const int b = (int)(row >> 15);
    const int s = (int)((row >> 5) & 1023);
    const int i = idx[row];
    const size_t bi = (size_t)b * N_ + i;
    const float* pt = points + bi * 64;
    const float* nx = newxyz + ((size_t)b * S_ + s) * 3;
    const int jb = half ? 6 : 0, je = half ? 13 : 6;
    float gx = 0.f, gy = 0.f, gz = 0.f;
    if (!half) { gx = sox[bi] - nx[0]; gy = soy[bi] - nx[1]; gz = soz[bi] - nx[2]; }
#pragma unroll 13
    for (int j = jb; j < je; ++j) {
      float v[8];
#pragma unroll
      for (int e = 0; e < 8; ++e) {
        const int c = j * 8 + e;
        v[e] = (c == 0) ? gx : (c == 1) ? gy : (c == 2) ? gz
               : (c < 67) ? pt[c - 3] : 0.f;
      }
      bf16x8 hi, lo;
      split8(v, hi, lo);
      *(bf16x8*)(Ah + r * 104 + j * 8) = hi;
      *(bf16x8*)(Al + r * 104 + j * 8) = lo;
    }
  }
  __syncthreads();
  const int wid = t >> 6, lane = t & 63;
  const int wrow = wid * 32;
  const int lrow = lane & 15, lk = (lane >> 4) * 8;
  f32x4 acc[2][4];
#pragma unroll
  for (int a_ = 0; a_ < 2; ++a_)
#pragma unroll
    for (int b_ = 0; b_ < 4; ++b_) acc[a_][b_] = (f32x4){0.f, 0.f, 0.f, 0.f};
#pragma unroll
  for (int ks = 0; ks < 3; ++ks) {
    const int ko = ks * 32 + lk;
    bf16x8 ah0 = *(const bf16x8*)(Ah + (wrow + lrow) * 104 + ko);
    bf16x8 al0 = *(const bf16x8*)(Al + (wrow + lrow) * 104 + ko);
    bf16x8 ah1 = *(const bf16x8*)(Ah + (wrow + 16 + lrow) * 104 + ko);
    bf16x8 al1 = *(const bf16x8*)(Al + (wrow + 16 + lrow) * 104 + ko);
#pragma unroll
    for (int cf = 0; cf < 4; ++cf) {
      bf16x8 bh = *(const bf16x8*)(Bh + (cf * 16 + lrow) * 104 + ko);
      bf16x8 bl = *(const bf16x8*)(Bl + (cf * 16 + lrow) * 104 + ko);
      acc[0][cf] = mfma16(ah0, bh, acc[0][cf]);
      acc[0][cf] = mfma16(al0, bh, acc[0][cf]);
      acc[0][cf] = mfma16(ah0, bl, acc[0][cf]);
      acc[1][cf] = mfma16(ah1, bh, acc[1][cf]);
      acc[1][cf] = mfma16(al1, bh, acc[1][cf]);
      acc[1][cf] = mfma16(ah1, bl, acc[1][cf]);
    }
  }
#pragma unroll
  for (int cf = 0; cf < 4; ++cf) {
    float s = 0.f, s2 = 0.f;
    const int col = cf * 16 + lrow;
#pragma unroll
    for (int rf = 0; rf < 2; ++rf) {
      const int rbase = wrow + rf * 16 + (lane >> 4) * 4;
#pragma unroll
      for (int q = 0; q < 4; ++q) {
        float v = acc[rf][cf][q];
        yout[(row0 + rbase + q) * 64 + col] = v;
        s += v; s2 += v * v;
      }
    }
    s += __shfl_xor(s, 16, 64); s += __shfl_xor(s, 32, 64);
    s2 += __shfl_xor(s2, 16, 64); s2 += __shfl_xor(s2, 32, 64);
    if ((lane >> 4) == 0) { swsum[wid][col] = s; swsq[wid][col] = s2; }
  }
  __syncthreads();
  if (t < 128) {
    const int c = t & 63;
    float v = (t < 64) ? (swsum[0][c] + swsum[1][c] + swsum[2][c] + swsum[3][c])
                       : (swsq[0][c] + swsq[1][c] + swsq[2][c] + swsq[3][c]);
    partial[(size_t)t * NBLK_ + blk] = v;
  }
}

// ---------------- stat: mean/var -> (a, shift) ----------------
__global__ __launch_bounds__(64) void stat_kernel(
    const float* __restrict__ partial, const float* __restrict__ g,
    const float* __restrict__ bt, float* __restrict__ ab, int nch) {
  const int o = blockIdx.x, t = threadIdx.x;
  float s = 0.f, s2 = 0.f;
  for (int i = t; i < NBLK_; i += 64) {
    s += partial[(size_t)o * NBLK_ + i];
    s2 += partial[(size_t)(nch + o) * NBLK_ + i];
  }
#pragma unroll
  for (int off = 32; off >= 1; off >>= 1) {
    s += __shfl_xor(s, off, 64);
    s2 += __shfl_xor(s2, off, 64);
  }
  if (t == 0) {
    const float minv = 1.0f / (float)M_;
    float mean = s * minv;
    float var = s2 * minv - mean * mean;
    float a = g[o] * rsqrtf(var + 1e-5f);
    ab[o] = a;
    ab[128 + o] = bt[o] - mean * a;
  }
}

// ---------------- layer 1: BN0+ReLU on load -> split GEMM 64->64 (in-place y) ----------------
__global__ __launch_bounds__(256) void layer1_kernel(
    float* y /* f32 activations, read rows then overwritten (same block) */,
    const __bf16* __restrict__ wh, const __bf16* __restrict__ wl,
    const float* __restrict__ ab, float* __restrict__ partial) {
  __shared__ __align__(16) __bf16 Ah[128 * 72];
  __shared__ __align__(16) __bf16 Al[128 * 72];
  __shared__ __align__(16) __bf16 Bh[64 * 72];
  __shared__ __align__(16) __bf16 Bl[64 * 72];
  __shared__ float sa[64], sb[64];
  __shared__ float swsum[4][64], swsq[4][64];
  const int t = threadIdx.x;
  const int blk = blockIdx.x;
  const size_t row0 = (size_t)blk * 128;
  if (t < 64) { sa[t] = ab[t]; sb[t] = ab[128 + t]; }
  {
    const int4* sh4 = (const int4*)wh;
    const int4* sl4 = (const int4*)wl;
    int4* dh4 = (int4*)Bh;
    int4* dl4 = (int4*)Bl;
    for (int k = t; k < 576; k += 256) { dh4[k] = sh4[k]; dl4[k] = sl4[k]; }
  }
  __syncthreads();
  {
    const int r = t >> 1, half = t & 1;
    const float4* s4 = (const float4*)(y + (row0 + r) * 64 + half * 32);
#pragma unroll
    for (int j = 0; j < 4; ++j) {
      float4 u = s4[j * 2], w = s4[j * 2 + 1];
      float v[8] = {u.x, u.y, u.z, u.w, w.x, w.y, w.z, w.w};
#pragma unroll
      for (int e = 0; e < 8; ++e) {
        const int c = half * 32 + j * 8 + e;
        v[e] = fmaxf(v[e] * sa[c] + sb[c], 0.f);
      }
      bf16x8 hi, lo;
      split8(v, hi, lo);
      *(bf16x8*)(Ah + r * 72 + half * 32 + j * 8) = hi;
      *(bf16x8*)(Al + r * 72 + half * 32 + j * 8) = lo;
    }
  }
  __syncthreads();
  const int wid = t >> 6, lane = t & 63;
  const int wrow = wid * 32;
  const int lrow = lane & 15, lk = (lane >> 4) * 8;
  f32x4 acc[2][4];
#pragma unroll
  for (int a_ = 0; a_ < 2; ++a_)
#pragma unroll
    for (int b_ = 0; b_ < 4; ++b_) acc[a_][b_] = (f32x4){0.f, 0.f, 0.f, 0.f};
#pragma unroll
  for (int ks = 0; ks < 2; ++ks) {
    const int ko = ks * 32 + lk;
    bf16x8 ah0 = *(const bf16x8*)(Ah + (wrow + lrow) * 72 + ko);
    bf16x8 al0 = *(const bf16x8*)(Al + (wrow + lrow) * 72 + ko);
    bf16x8 ah1 = *(const bf16x8*)(Ah + (wrow + 16 + lrow) * 72 + ko);
    bf16x8 al1 = *(const bf16x8*)(Al + (wrow + 16 + lrow) * 72 + ko);
#pragma unroll
    for (int cf = 0; cf < 4; ++cf) {
      bf16x8 bh = *(const bf16x8*)(Bh + (cf * 16 + lrow) * 72 + ko);
      bf16x8 bl = *(const bf16x8*)(Bl + (cf * 16 + lrow) * 72 + ko);
      acc[0][cf] = mfma16(ah0, bh, acc[0][cf]);
      acc[0][cf] = mfma16(al0, bh, acc[0][cf]);
      acc[0][cf] = mfma16(ah0, bl, acc[0][cf]);
      acc[1][cf] = mfma16(ah1, bh, acc[1][cf]);
      acc[1][cf] = mfma16(al1, bh, acc[1][cf]);
      acc[1][cf] = mfma16(ah1, bl, acc[1][cf]);
    }
  }
#pragma unroll
  for (int cf = 0; cf < 4; ++cf) {
    float s = 0.f, s2 = 0.f;
    const int col = cf * 16 + lrow;
#pragma unroll
    for (int rf = 0; rf < 2; ++rf) {
      const int rbase = wrow + rf * 16 + (lane >> 4) * 4;
#pragma unroll
      for (int q = 0; q < 4; ++q) {
        float v = acc[rf][cf][q];
        y[(row0 + rbase + q) * 64 + col] = v;
        s += v; s2 += v * v;
      }
    }
    s += __shfl_xor(s, 16, 64); s += __shfl_xor(s, 32, 64);
    s2 += __shfl_xor(s2, 16, 64); s2 += __shfl_xor(s2, 32, 64);
    if ((lane >> 4) == 0) { swsum[wid][col] = s; swsq[wid][col] = s2; }
  }
  __syncthreads();
  if (t < 128) {
    const int c = t & 63;
    float v = (t < 64) ? (swsum[0][c] + swsum[1][c] + swsum[2][c] + swsum[3][c])
                       : (swsq[0][c] + swsq[1][c] + swsq[2][c] + swsq[3][c]);
    partial[(size_t)t * NBLK_ + blk] = v;
  }
}

// ---------------- layer 2: BN1+ReLU -> split GEMM 64->128 + fused max/min pool ----------------
__global__ __launch_bounds__(256) void layer2_kernel(
    const float* __restrict__ yin, const __bf16* __restrict__ wh,
    const __bf16* __restrict__ wl, const float* __restrict__ ab,
    float* __restrict__ ymax, float* __restrict__ ymin,
    float* __restrict__ partial) {
  __shared__ __align__(16) __bf16 Ah[128 * 72];
  __shared__ __align__(16) __bf16 Al[128 * 72];
  __shared__ __align__(16) __bf16 Bh[128 * 72];
  __shared__ __align__(16) __bf16 Bl[128 * 72];
  __shared__ float sa[64], sb[64];
  __shared__ float swsum[4][128], swsq[4][128];
  const int t = threadIdx.x;
  const int blk = blockIdx.x;
  const size_t row0 = (size_t)blk * 128;
  if (t < 64) { sa[t] = ab[t]; sb[t] = ab[128 + t]; }
  {
    const int4* sh4 = (const int4*)wh;
    const int4* sl4 = (const int4*)wl;
    int4* dh4 = (int4*)Bh;
    int4* dl4 = (int4*)Bl;
    for (int k = t; k < 1152; k += 256) { dh4[k] = sh4[k]; dl4[k] = sl4[k]; }
  }
  __syncthreads();
  {
    const int r = t >> 1, half = t & 1;
    const float4* s4 = (const float4*)(yin + (row0 + r) * 64 + half * 32);
#pragma unroll
    for (int j = 0; j < 4; ++j) {
      float4 u = s4[j * 2], w = s4[j * 2 + 1];
      float v[8] = {u.x, u.y, u.z, u.w, w.x, w.y, w.z, w.w};
#pragma unroll
      for (int e = 0; e < 8; ++e) {
        const int c = half * 32 + j * 8 + e;
        v[e] = fmaxf(v[e] * sa[c] + sb[c], 0.f);
      }
      bf16x8 hi, lo;
      split8(v, hi, lo);
      *(bf16x8*)(Ah + r * 72 + half * 32 + j * 8) = hi;
      *(bf16x8*)(Al + r * 72 + half * 32 + j * 8) = lo;
    }
  }
  __syncthreads();
  const int wid = t >> 6, lane = t & 63;
  const int wrow = wid * 32;
  const int lrow = lane & 15, lk = (lane >> 4) * 8;
  f32x4 acc[2][8];
#pragma unroll
  for (int a_ = 0; a_ < 2; ++a_)
#pragma unroll
    for (int b_ = 0; b_ < 8; ++b_) acc[a_][b_] = (f32x4){0.f, 0.f, 0.f, 0.f};
#pragma unroll
  for (int ks = 0; ks < 2; ++ks) {
    const int ko = ks * 32 + lk;
    bf16x8 ah0 = *(const bf16x8*)(Ah + (wrow + lrow) * 72 + ko);
    bf16x8 al0 = *(const bf16x8*)(Al + (wrow + lrow) * 72 + ko);
    bf16x8 ah1 = *(const bf16x8*)(Ah + (wrow + 16 + lrow) * 72 + ko);
    bf16x8 al1 = *(const bf16x8*)(Al + (wrow + 16 + lrow) * 72 + ko);
#pragma unroll
    for (int cf = 0; cf < 8; ++cf) {
      bf16x8 bh = *(const bf16x8*)(Bh + (cf * 16 + lrow) * 72 + ko);
      bf16x8 bl = *(const bf16x8*)(Bl + (cf * 16 + lrow) * 72 + ko);
      acc[0][cf] = mfma16(ah0, bh, acc[0][cf]);
      acc[0][cf] = mfma16(al0, bh, acc[0][cf]);
      acc[0][cf] = mfma16(ah0, bl, acc[0][cf]);
      acc[1][cf] = mfma16(ah1, bh, acc[1][cf]);
      acc[1][cf] = mfma16(al1, bh, acc[1][cf]);
      acc[1][cf] = mfma16(ah1, bl, acc[1][cf]);
    }
  }
  // each wave's 32 rows form exactly one (b,s) group
  const size_t bs = (size_t)blk * 4 + wid;
#pragma unroll
  for (int cf = 0; cf < 8; ++cf) {
    float s = 0.f, s2 = 0.f, mx = -3.4e38f, mn = 3.4e38f;
    const int col = cf * 16 + lrow;
#pragma unroll
    for (int rf = 0; rf < 2; ++rf)
#pragma unroll
      for (int q = 0; q < 4; ++q) {
        float v = acc[rf][cf][q];
        s += v; s2 += v * v;
        mx = fmaxf(mx, v); mn = fminf(mn, v);
      }
    s += __shfl_xor(s, 16, 64); s += __shfl_xor(s, 32, 64);
    s2 += __shfl_xor(s2, 16, 64); s2 += __shfl_xor(s2, 32, 64);
    mx = fmaxf(mx, __shfl_xor(mx, 16, 64)); mx = fmaxf(mx, __shfl_xor(mx, 32, 64));
    mn = fminf(mn, __shfl_xor(mn, 16, 64)); mn = fminf(mn, __shfl_xor(mn, 32, 64));
    if ((lane >> 4) == 0) {
      ymax[bs * 128 + col] = mx;
      ymin[bs * 128 + col] = mn;
      swsum[wid][col] = s; swsq[wid][col] = s2;
    }
  }
  __syncthreads();
  if (t < 128) {
    float v = swsum[0][t] + swsum[1][t] + swsum[2][t] + swsum[3][t];
    partial[(size_t)t * NBLK_ + blk] = v;
  } else {
    const int c = t - 128;
    float v = swsq[0][c] + swsq[1][c] + swsq[2][c] + swsq[3][c];
    partial[(size_t)t * NBLK_ + blk] = v;
  }
}

// ---------------- final: BN2+ReLU on pooled values ----------------
__global__ __launch_bounds__(256) void final_kernel(
    const float* __restrict__ ymax, const float* __restrict__ ymin,
    const float* __restrict__ ab, float* __restrict__ out) {
  const int gid = blockIdx.x * 256 + threadIdx.x;  // B*S*128
  const int col = gid & 127;
  const float a = ab[col];
  const float v = (a >= 0.f) ? ymax[gid] : ymin[gid];  // monotonicity of BN+ReLU vs sign(a)
  out[gid] = fmaxf(v * a + ab[128 + col], 0.f);
}

extern "C" void kernel_launch(void* const* d_in, const int* in_sizes, int n_in,
                              void* d_out, int out_size, void* d_ws, size_t ws_size,
                              hipStream_t stream) {
  const float* xyz = (const float*)d_in[0];
  const float* points = (const float*)d_in[1];
  const float* w0 = (const float*)d_in[2];
  const float* g0 = (const float*)d_in[4];
  const float* bt0 = (const float*)d_in[5];
  const float* w1 = (const float*)d_in[6];
  const float* g1 = (const float*)d_in[8];
  const float* bt1 = (const float*)d_in[9];
  const float* w2 = (const float*)d_in[10];
  const float* g2 = (const float*)d_in[12];
  const float* bt2 = (const float*)d_in[13];
  float* out = (float*)d_out;
  char* ws = (char*)d_ws;

  float* sox = (float*)(ws + 0);
  float* soy = (float*)(ws + 524288);
  float* soz = (float*)(ws + 1048576);
  float* pp  = (float*)(ws + 1572864);
  __bf16* w0h = (__bf16*)(ws + 2097152);   // 13312 B
  __bf16* w0l = (__bf16*)(ws + 2110464);
  __bf16* w1h = (__bf16*)(ws + 2123776);   // 9216 B
  __bf16* w1l = (__bf16*)(ws + 2132992);
  __bf16* w2h = (__bf16*)(ws + 2142208);   // 18432 B
  __bf16* w2l = (__bf16*)(ws + 2160640);
  int* idx    = (int*)(ws + 2179072);      // 2 MB
  float* y    = (float*)(ws + 4276224);    // 134217728 B (f32, reused L0->L1 in place)
  float* ymax = (float*)(ws + 138493952);  // 8388608
  float* ymin = (float*)(ws + 146882560);  // 8388608
  float* partial = (float*)(ws + 155271168); // 4194304
  float* ab   = (float*)(ws + 159465472);  // 3072
  if (ws_size < 159468544) return;

  prep_kernel<<<592, 256, 0, stream>>>(xyz, w0, w1, w2, sox, soy, soz, pp,
                                       w0h, w0l, w1h, w1l, w2h, w2l);
  fps_kernel<<<16, 1024, 0, stream>>>(sox, soy, soz, out);
  ballq_kernel<<<1024, 1024, 0, stream>>>(sox, soy, soz, pp, out, idx);
  layer0_kernel<<<NBLK_, 256, 0, stream>>>(sox, soy, soz, points, out, idx, w0h, w0l, y, partial);
  stat_kernel<<<64, 64, 0, stream>>>(partial, g0, bt0, ab, 64);
  layer1_kernel<<<NBLK_, 256, 0, stream>>>(y, w1h, w1l, ab, partial);
  stat_kernel<<<64, 64, 0, stream>>>(partial, g1, bt1, ab + 256, 64);
  layer2_kernel<<<NBLK_, 256, 0, stream>>>(y, w2h, w2l, ab + 256, ymax, ymin, partial);
  stat_kernel<<<128, 64, 0, stream>>>(partial, g2, bt2, ab + 512, 128);
  final_kernel<<<8192, 256, 0, stream>>>(ymax, ymin, ab + 512, out + 49152);
}

// Round 5
// 1419.608 us; speedup vs baseline: 1.1626x; 1.1438x over previous
//
#include <hip/hip_runtime.h>

// PointNet++ Set Abstraction for MI355X (gfx950).
// prep -> FPS -> ball-query -> L0(mfma) -> stat -> L1 -> stat -> L2(+pool) -> stat -> final.
// FPS replicates reference f32 elementwise arithmetic exactly (non-FMA, same order).
// Ball-query dot uses an FMA chain replicating BLAS sgemm accumulation.
// Activations stored f32; GEMMs use hi/lo split-bf16 MFMA (near-f32).
// R4: FPS cross-wave argmax via single LDS ds_max_u64 on packed (val<<32|~idx)
// key (exact first-argmax), 4-slot rotation for race-free reset; xyz+|p|^2
// packed as float4 (1 b128 LDS read for centroid / ball candidate).

typedef __bf16 bf16x8 __attribute__((ext_vector_type(8)));
typedef float f32x4 __attribute__((ext_vector_type(4)));

#define B_ 16
#define N_ 8192
#define S_ 1024
#define K_ 32
#define M_ 524288   // B*S*K rows
#define NBLK_ 4096  // M/128

__device__ __forceinline__ f32x4 mfma16(bf16x8 a, bf16x8 b, f32x4 c) {
  return __builtin_amdgcn_mfma_f32_16x16x32_bf16(a, b, c, 0, 0, 0);
}

__device__ __forceinline__ void split8(const float* v, bf16x8& hi, bf16x8& lo) {
#pragma unroll
  for (int e = 0; e < 8; ++e) {
    __bf16 h = (__bf16)v[e];
    hi[e] = h;
    lo[e] = (__bf16)(v[e] - (float)h);
  }
}

// ---------------- prep: packed {x,y,z,|p|^2}, hi/lo split weights ----------------
__global__ __launch_bounds__(256) void prep_kernel(
    const float* __restrict__ xyz, const float* __restrict__ w0,
    const float* __restrict__ w1, const float* __restrict__ w2,
    float4* __restrict__ sxyzp,
    __bf16* __restrict__ w0h, __bf16* __restrict__ w0l,
    __bf16* __restrict__ w1h, __bf16* __restrict__ w1l,
    __bf16* __restrict__ w2h, __bf16* __restrict__ w2l) {
#pragma clang fp contract(off)
  int gid = blockIdx.x * 256 + threadIdx.x;
  if (gid < B_ * N_) {
    float x = xyz[gid * 3 + 0], y = xyz[gid * 3 + 1], z = xyz[gid * 3 + 2];
    float p = (x * x + y * y) + z * z;  // exact reference order
    sxyzp[gid] = make_float4(x, y, z, p);
  } else {
    int j = gid - B_ * N_;
    float v; __bf16* ph; __bf16* pl; int jj;
    if (j < 6656) {            // W0: [64][104], real c<67
      int o = j / 104, c = j % 104;
      v = (c < 67) ? w0[o * 67 + c] : 0.f; ph = w0h; pl = w0l; jj = j;
    } else if (j < 6656 + 4608) {  // W1: [64][72], real c<64
      jj = j - 6656;
      int o = jj / 72, c = jj % 72;
      v = (c < 64) ? w1[o * 64 + c] : 0.f; ph = w1h; pl = w1l;
    } else if (j < 6656 + 4608 + 9216) {  // W2: [128][72]
      jj = j - 6656 - 4608;
      int o = jj / 72, c = jj % 72;
      v = (c < 64) ? w2[o * 64 + c] : 0.f; ph = w2h; pl = w2l;
    } else return;
    __bf16 h = (__bf16)v;
    ph[jj] = h;
    pl[jj] = (__bf16)(v - (float)h);
  }
}

// ---------------- FPS: one block per batch, LDS atomic-max argmax ----------------
__global__ __launch_bounds__(1024) void fps_kernel(
    const float4* __restrict__ sxyzp, float* __restrict__ out /* new_xyz (B,S,3) */) {
#pragma clang fp contract(off)
  const int b = blockIdx.x;
  const int t = threadIdx.x;
  __shared__ float4 sp[N_];                    // 128 KB
  __shared__ unsigned long long slot[4];
  const float4* src = sxyzp + (size_t)b * N_;
  for (int i = t; i < N_; i += 1024) sp[i] = src[i];
  if (t < 4) slot[t] = 0ull;
  __syncthreads();
  // contiguous chunk per lane: thread t owns points [8t, 8t+8)
  float px[8], py[8], pz[8], dist[8];
  const int i0 = t * 8;
#pragma unroll
  for (int w = 0; w < 8; ++w) {
    float4 v = sp[i0 + w];
    px[w] = v.x; py[w] = v.y; pz[w] = v.z;
    dist[w] = 1e10f;
  }
  const int lane = t & 63;
  float* outB = out + (size_t)b * S_ * 3;
  int far = 0;
  for (int s = 0; s < S_; ++s) {
    float4 c = sp[far];
    if (t == 0) { outB[s * 3 + 0] = c.x; outB[s * 3 + 1] = c.y; outB[s * 3 + 2] = c.z; }
    float bv = -1.0f; int bi = 0;
#pragma unroll
    for (int w = 0; w < 8; ++w) {
      float dx = px[w] - c.x, dy = py[w] - c.y, dz = pz[w] - c.z;
      float d = (dx * dx + dy * dy) + dz * dz;   // exact reference order, no fma
      float nd = fminf(dist[w], d);
      dist[w] = nd;
      bv = fmaxf(bv, nd);
    }
    // first (lowest) local index equal to bv: descending select keeps lowest w
#pragma unroll
    for (int w = 7; w >= 0; --w) if (dist[w] == bv) bi = i0 + w;
    // wave-wide max on value (f32 shuffles), then first-lane index pick
    float m = bv;
#pragma unroll
    for (int off = 32; off >= 1; off >>= 1) m = fmaxf(m, __shfl_xor(m, off, 64));
    unsigned long long msk = __ballot(bv == m);
    int srcl = __ffsll(msk) - 1;
    int wbi = __shfl(bi, srcl, 64);
    if (lane == 0)
      atomicMax(&slot[(s + 1) & 3],
                ((unsigned long long)__float_as_uint(m) << 32) |
                    (unsigned long long)(0xFFFFFFFFu - (unsigned)wbi));
    __syncthreads();
    unsigned long long best = slot[(s + 1) & 3];
    far = (int)(0xFFFFFFFFu - (unsigned)(best & 0xFFFFFFFFull));
    if (t == 0) slot[(s + 3) & 3] = 0ull;  // safe: atomics into it start after next barrier
  }
}

// ---------------- ball query: 16 queries per block ----------------
__global__ __launch_bounds__(1024) void ballq_kernel(
    const float4* __restrict__ sxyzp, const float* __restrict__ newxyz,
    int* __restrict__ idxout) {
#pragma clang fp contract(off)
  __shared__ float4 sp[N_];                    // 128 KB
  __shared__ int sel[16][32];
  const int t = threadIdx.x;
  const int g = blockIdx.x;
  const int b = g >> 6;
  const int q0 = (g & 63) << 4;
  const float4* srcp = sxyzp + (size_t)b * N_;
  for (int i = t; i < N_; i += 1024) sp[i] = srcp[i];
  __syncthreads();
  const int wid = t >> 6, lane = t & 63;
  const int q = q0 + wid;
  const float* qp = newxyz + ((size_t)b * S_ + q) * 3;
  const float qx = qp[0], qy = qp[1], qz = qp[2];
  const float qq = (qx * qx + qy * qy) + qz * qz;
  const float rr = (float)(0.4 * 0.4);
  int nsel = 0;
  for (int c0 = 0; c0 < N_ && nsel < 32; c0 += 64) {
    int i = c0 + lane;
    float4 v = sp[i];
    // BLAS-style FMA accumulation chain (matches einsum->matmul lowering):
    float dot = fmaf(qz, v.z, fmaf(qy, v.y, qx * v.x));
    float d = -2.0f * dot;
    d = d + qq;
    d = d + v.w;
    unsigned long long m = __ballot(!(d > rr));
    if ((m >> lane) & 1ull) {
      int rank = nsel + __popcll(m & ((1ull << lane) - 1ull));
      if (rank < 32) sel[wid][rank] = i;
    }
    nsel += __popcll(m);
  }
  __syncthreads();
  int nv = nsel < 32 ? nsel : 32;
  int first = sel[wid][0];
  if (lane < 32)
    idxout[(((size_t)b * S_ + q) << 5) + lane] = (lane < nv) ? sel[wid][lane] : first;
}

// ---------------- layer 0: gather+concat -> split GEMM 67->64 (K padded 96) ----------------
__global__ __launch_bounds__(256) void layer0_kernel(
    const float4* __restrict__ sxyzp, const float* __restrict__ points,
    const float* __restrict__ newxyz, const int* __restrict__ idx,
    const __bf16* __restrict__ wh, const __bf16* __restrict__ wl,
    float* __restrict__ yout, float* __restrict__ partial) {
  __shared__ __align__(16) __bf16 Ah[128 * 104];
  __shared__ __align__(16) __bf16 Al[128 * 104];
  __shared__ __align__(16) __bf16 Bh[64 * 104];
  __shared__ __align__(16) __bf16 Bl[64 * 104];
  __shared__ float swsum[4][64], swsq[4][64];
  const int t = threadIdx.x;
  const int blk = blockIdx.x;
  const size_t row0 = (size_t)blk * 128;
  {
    const int4* sh4 = (const int4*)wh;
    const int4* sl4 = (const int4*)wl;
    int4* dh4 = (int4*)Bh;
    int4* dl4 = (int4*)Bl;
    for (int k = t; k < 832; k += 256) { dh4[k] = sh4[k]; dl4[k] = sl4[k]; }
  }
  {
    const int r = t >> 1, half = t & 1;
    const size_t row = row0 + r;
    const int b = (int)(row >> 15);
    const int s = (int)((row >> 5) & 1023);
    const int i = idx[row];
    const size_t bi = (size_t)b * N_ + i;
    const float* pt = points + bi * 64;
    const float* nx = newxyz + ((size_t)b * S_ + s) * 3;
    const int jb = half ? 6 : 0, je = half ? 13 : 6;
    float gx = 0.f, gy = 0.f, gz = 0.f;
    if (!half) {
      float4 xv = sxyzp[bi];
      gx = xv.x - nx[0]; gy = xv.y - nx[1]; gz = xv.z - nx[2];
    }
#pragma unroll 13
    for (int j = jb; j < je; ++j) {
      float v[8];
#pragma unroll
      for (int e = 0; e < 8; ++e) {
        const int c = j * 8 + e;
        v[e] = (c == 0) ? gx : (c == 1) ? gy : (c == 2) ? gz
               : (c < 67) ? pt[c - 3] : 0.f;
      }
      bf16x8 hi, lo;
      split8(v, hi, lo);
      *(bf16x8*)(Ah + r * 104 + j * 8) = hi;
      *(bf16x8*)(Al + r * 104 + j * 8) = lo;
    }
  }
  __syncthreads();
  const int wid = t >> 6, lane = t & 63;
  const int wrow = wid * 32;
  const int lrow = lane & 15, lk = (lane >> 4) * 8;
  f32x4 acc[2][4];
#pragma unroll
  for (int a_ = 0; a_ < 2; ++a_)
#pragma unroll
    for (int b_ = 0; b_ < 4; ++b_) acc[a_][b_] = (f32x4){0.f, 0.f, 0.f, 0.f};
#pragma unroll
  for (int ks = 0; ks < 3; ++ks) {
    const int ko = ks * 32 + lk;
    bf16x8 ah0 = *(const bf16x8*)(Ah + (wrow + lrow) * 104 + ko);
    bf16x8 al0 = *(const bf16x8*)(Al + (wrow + lrow) * 104 + ko);
    bf16x8 ah1 = *(const bf16x8*)(Ah + (wrow + 16 + lrow) * 104 + ko);
    bf16x8 al1 = *(const bf16x8*)(Al + (wrow + 16 + lrow) * 104 + ko);
#pragma unroll
    for (int cf = 0; cf < 4; ++cf) {
      bf16x8 bh = *(const bf16x8*)(Bh + (cf * 16 + lrow) * 104 + ko);
      bf16x8 bl = *(const bf16x8*)(Bl + (cf * 16 + lrow) * 104 + ko);
      acc[0][cf] = mfma16(ah0, bh, acc[0][cf]);
      acc[0][cf] = mfma16(al0, bh, acc[0][cf]);
      acc[0][cf] = mfma16(ah0, bl, acc[0][cf]);
      acc[1][cf] = mfma16(ah1, bh, acc[1][cf]);
      acc[1][cf] = mfma16(al1, bh, acc[1][cf]);
      acc[1][cf] = mfma16(ah1, bl, acc[1][cf]);
    }
  }
#pragma unroll
  for (int cf = 0; cf < 4; ++cf) {
    float s = 0.f, s2 = 0.f;
    const int col = cf * 16 + lrow;
#pragma unroll
    for (int rf = 0; rf < 2; ++rf) {
      const int rbase = wrow + rf * 16 + (lane >> 4) * 4;
#pragma unroll
      for (int q = 0; q < 4; ++q) {
        float v = acc[rf][cf][q];
        yout[(row0 + rbase + q) * 64 + col] = v;
        s += v; s2 += v * v;
      }
    }
    s += __shfl_xor(s, 16, 64); s += __shfl_xor(s, 32, 64);
    s2 += __shfl_xor(s2, 16, 64); s2 += __shfl_xor(s2, 32, 64);
    if ((lane >> 4) == 0) { swsum[wid][col] = s; swsq[wid][col] = s2; }
  }
  __syncthreads();
  if (t < 128) {
    const int c = t & 63;
    float v = (t < 64) ? (swsum[0][c] + swsum[1][c] + swsum[2][c] + swsum[3][c])
                       : (swsq[0][c] + swsq[1][c] + swsq[2][c] + swsq[3][c]);
    partial[(size_t)t * NBLK_ + blk] = v;
  }
}

// ---------------- stat: mean/var -> (a, shift) ----------------
__global__ __launch_bounds__(64) void stat_kernel(
    const float* __restrict__ partial, const float* __restrict__ g,
    const float* __restrict__ bt, float* __restrict__ ab, int nch) {
  const int o = blockIdx.x, t = threadIdx.x;
  float s = 0.f, s2 = 0.f;
  for (int i = t; i < NBLK_; i += 64) {
    s += partial[(size_t)o * NBLK_ + i];
    s2 += partial[(size_t)(nch + o) * NBLK_ + i];
  }
#pragma unroll
  for (int off = 32; off >= 1; off >>= 1) {
    s += __shfl_xor(s, off, 64);
    s2 += __shfl_xor(s2, off, 64);
  }
  if (t == 0) {
    const float minv = 1.0f / (float)M_;
    float mean = s * minv;
    float var = s2 * minv - mean * mean;
    float a = g[o] * rsqrtf(var + 1e-5f);
    ab[o] = a;
    ab[128 + o] = bt[o] - mean * a;
  }
}

// ---------------- layer 1: BN0+ReLU on load -> split GEMM 64->64 (in-place y) ----------------
__global__ __launch_bounds__(256) void layer1_kernel(
    float* y /* f32 activations, read rows then overwritten (same block) */,
    const __bf16* __restrict__ wh, const __bf16* __restrict__ wl,
    const float* __restrict__ ab, float* __restrict__ partial) {
  __shared__ __align__(16) __bf16 Ah[128 * 72];
  __shared__ __align__(16) __bf16 Al[128 * 72];
  __shared__ __align__(16) __bf16 Bh[64 * 72];
  __shared__ __align__(16) __bf16 Bl[64 * 72];
  __shared__ float sa[64], sb[64];
  __shared__ float swsum[4][64], swsq[4][64];
  const int t = threadIdx.x;
  const int blk = blockIdx.x;
  const size_t row0 = (size_t)blk * 128;
  if (t < 64) { sa[t] = ab[t]; sb[t] = ab[128 + t]; }
  {
    const int4* sh4 = (const int4*)wh;
    const int4* sl4 = (const int4*)wl;
    int4* dh4 = (int4*)Bh;
    int4* dl4 = (int4*)Bl;
    for (int k = t; k < 576; k += 256) { dh4[k] = sh4[k]; dl4[k] = sl4[k]; }
  }
  __syncthreads();
  {
    const int r = t >> 1, half = t & 1;
    const float4* s4 = (const float4*)(y + (row0 + r) * 64 + half * 32);
#pragma unroll
    for (int j = 0; j < 4; ++j) {
      float4 u = s4[j * 2], w = s4[j * 2 + 1];
      float v[8] = {u.x, u.y, u.z, u.w, w.x, w.y, w.z, w.w};
#pragma unroll
      for (int e = 0; e < 8; ++e) {
        const int c = half * 32 + j * 8 + e;
        v[e] = fmaxf(v[e] * sa[c] + sb[c], 0.f);
      }
      bf16x8 hi, lo;
      split8(v, hi, lo);
      *(bf16x8*)(Ah + r * 72 + half * 32 + j * 8) = hi;
      *(bf16x8*)(Al + r * 72 + half * 32 + j * 8) = lo;
    }
  }
  __syncthreads();
  const int wid = t >> 6, lane = t & 63;
  const int wrow = wid * 32;
  const int lrow = lane & 15, lk = (lane >> 4) * 8;
  f32x4 acc[2][4];
#pragma unroll
  for (int a_ = 0; a_ < 2; ++a_)
#pragma unroll
    for (int b_ = 0; b_ < 4; ++b_) acc[a_][b_] = (f32x4){0.f, 0.f, 0.f, 0.f};
#pragma unroll
  for (int ks = 0; ks < 2; ++ks) {
    const int ko = ks * 32 + lk;
    bf16x8 ah0 = *(const bf16x8*)(Ah + (wrow + lrow) * 72 + ko);
    bf16x8 al0 = *(const bf16x8*)(Al + (wrow + lrow) * 72 + ko);
    bf16x8 ah1 = *(const bf16x8*)(Ah + (wrow + 16 + lrow) * 72 + ko);
    bf16x8 al1 = *(const bf16x8*)(Al + (wrow + 16 + lrow) * 72 + ko);
#pragma unroll
    for (int cf = 0; cf < 4; ++cf) {
      bf16x8 bh = *(const bf16x8*)(Bh + (cf * 16 + lrow) * 72 + ko);
      bf16x8 bl = *(const bf16x8*)(Bl + (cf * 16 + lrow) * 72 + ko);
      acc[0][cf] = mfma16(ah0, bh, acc[0][cf]);
      acc[0][cf] = mfma16(al0, bh, acc[0][cf]);
      acc[0][cf] = mfma16(ah0, bl, acc[0][cf]);
      acc[1][cf] = mfma16(ah1, bh, acc[1][cf]);
      acc[1][cf] = mfma16(al1, bh, acc[1][cf]);
      acc[1][cf] = mfma16(ah1, bl, acc[1][cf]);
    }
  }
#pragma unroll
  for (int cf = 0; cf < 4; ++cf) {
    float s = 0.f, s2 = 0.f;
    const int col = cf * 16 + lrow;
#pragma unroll
    for (int rf = 0; rf < 2; ++rf) {
      const int rbase = wrow + rf * 16 + (lane >> 4) * 4;
#pragma unroll
      for (int q = 0; q < 4; ++q) {
        float v = acc[rf][cf][q];
        y[(row0 + rbase + q) * 64 + col] = v;
        s += v; s2 += v * v;
      }
    }
    s += __shfl_xor(s, 16, 64); s += __shfl_xor(s, 32, 64);
    s2 += __shfl_xor(s2, 16, 64); s2 += __shfl_xor(s2, 32, 64);
    if ((lane >> 4) == 0) { swsum[wid][col] = s; swsq[wid][col] = s2; }
  }
  __syncthreads();
  if (t < 128) {
    const int c = t & 63;
    float v = (t < 64) ? (swsum[0][c] + swsum[1][c] + swsum[2][c] + swsum[3][c])
                       : (swsq[0][c] + swsq[1][c] + swsq[2][c] + swsq[3][c]);
    partial[(size_t)t * NBLK_ + blk] = v;
  }
}

// ---------------- layer 2: BN1+ReLU -> split GEMM 64->128 + fused max/min pool ----------------
__global__ __launch_bounds__(256) void layer2_kernel(
    const float* __restrict__ yin, const __bf16* __restrict__ wh,
    const __bf16* __restrict__ wl, const float* __restrict__ ab,
    float* __restrict__ ymax, float* __restrict__ ymin,
    float* __restrict__ partial) {
  __shared__ __align__(16) __bf16 Ah[128 * 72];
  __shared__ __align__(16) __bf16 Al[128 * 72];
  __shared__ __align__(16) __bf16 Bh[128 * 72];
  __shared__ __align__(16) __bf16 Bl[128 * 72];
  __shared__ float sa[64], sb[64];
  __shared__ float swsum[4][128], swsq[4][128];
  const int t = threadIdx.x;
  const int blk = blockIdx.x;
  const size_t row0 = (size_t)blk * 128;
  if (t < 64) { sa[t] = ab[t]; sb[t] = ab[128 + t]; }
  {
    const int4* sh4 = (const int4*)wh;
    const int4* sl4 = (const int4*)wl;
    int4* dh4 = (int4*)Bh;
    int4* dl4 = (int4*)Bl;
    for (int k = t; k < 1152; k += 256) { dh4[k] = sh4[k]; dl4[k] = sl4[k]; }
  }
  __syncthreads();
  {
    const int r = t >> 1, half = t & 1;
    const float4* s4 = (const float4*)(yin + (row0 + r) * 64 + half * 32);
#pragma unroll
    for (int j = 0; j < 4; ++j) {
      float4 u = s4[j * 2], w = s4[j * 2 + 1];
      float v[8] = {u.x, u.y, u.z, u.w, w.x, w.y, w.z, w.w};
#pragma unroll
      for (int e = 0; e < 8; ++e) {
        const int c = half * 32 + j * 8 + e;
        v[e] = fmaxf(v[e] * sa[c] + sb[c], 0.f);
      }
      bf16x8 hi, lo;
      split8(v, hi, lo);
      *(bf16x8*)(Ah + r * 72 + half * 32 + j * 8) = hi;
      *(bf16x8*)(Al + r * 72 + half * 32 + j * 8) = lo;
    }
  }
  __syncthreads();
  const int wid = t >> 6, lane = t & 63;
  const int wrow = wid * 32;
  const int lrow = lane & 15, lk = (lane >> 4) * 8;
  f32x4 acc[2][8];
#pragma unroll
  for (int a_ = 0; a_ < 2; ++a_)
#pragma unroll
    for (int b_ = 0; b_ < 8; ++b_) acc[a_][b_] = (f32x4){0.f, 0.f, 0.f, 0.f};
#pragma unroll
  for (int ks = 0; ks < 2; ++ks) {
    const int ko = ks * 32 + lk;
    bf16x8 ah0 = *(const bf16x8*)(Ah + (wrow + lrow) * 72 + ko);
    bf16x8 al0 = *(const bf16x8*)(Al + (wrow + lrow) * 72 + ko);
    bf16x8 ah1 = *(const bf16x8*)(Ah + (wrow + 16 + lrow) * 72 + ko);
    bf16x8 al1 = *(const bf16x8*)(Al + (wrow + 16 + lrow) * 72 + ko);
#pragma unroll
    for (int cf = 0; cf < 8; ++cf) {
      bf16x8 bh = *(const bf16x8*)(Bh + (cf * 16 + lrow) * 72 + ko);
      bf16x8 bl = *(const bf16x8*)(Bl + (cf * 16 + lrow) * 72 + ko);
      acc[0][cf] = mfma16(ah0, bh, acc[0][cf]);
      acc[0][cf] = mfma16(al0, bh, acc[0][cf]);
      acc[0][cf] = mfma16(ah0, bl, acc[0][cf]);
      acc[1][cf] = mfma16(ah1, bh, acc[1][cf]);
      acc[1][cf] = mfma16(al1, bh, acc[1][cf]);
      acc[1][cf] = mfma16(ah1, bl, acc[1][cf]);
    }
  }
  // each wave's 32 rows form exactly one (b,s) group
  const size_t bs = (size_t)blk * 4 + wid;
#pragma unroll
  for (int cf = 0; cf < 8; ++cf) {
    float s = 0.f, s2 = 0.f, mx = -3.4e38f, mn = 3.4e38f;
    const int col = cf * 16 + lrow;
#pragma unroll
    for (int rf = 0; rf < 2; ++rf)
#pragma unroll
      for (int q = 0; q < 4; ++q) {
        float v = acc[rf][cf][q];
        s += v; s2 += v * v;
        mx = fmaxf(mx, v); mn = fminf(mn, v);
      }
    s += __shfl_xor(s, 16, 64); s += __shfl_xor(s, 32, 64);
    s2 += __shfl_xor(s2, 16, 64); s2 += __shfl_xor(s2, 32, 64);
    mx = fmaxf(mx, __shfl_xor(mx, 16, 64)); mx = fmaxf(mx, __shfl_xor(mx, 32, 64));
    mn = fminf(mn, __shfl_xor(mn, 16, 64)); mn = fminf(mn, __shfl_xor(mn, 32, 64));
    if ((lane >> 4) == 0) {
      ymax[bs * 128 + col] = mx;
      ymin[bs * 128 + col] = mn;
      swsum[wid][col] = s; swsq[wid][col] = s2;
    }
  }
  __syncthreads();
  if (t < 128) {
    float v = swsum[0][t] + swsum[1][t] + swsum[2][t] + swsum[3][t];
    partial[(size_t)t * NBLK_ + blk] = v;
  } else {
    const int c = t - 128;
    float v = swsq[0][c] + swsq[1][c] + swsq[2][c] + swsq[3][c];
    partial[(size_t)t * NBLK_ + blk] = v;
  }
}

// ---------------- final: BN2+ReLU on pooled values ----------------
__global__ __launch_bounds__(256) void final_kernel(
    const float* __restrict__ ymax, const float* __restrict__ ymin,
    const float* __restrict__ ab, float* __restrict__ out) {
  const int gid = blockIdx.x * 256 + threadIdx.x;  // B*S*128
  const int col = gid & 127;
  const float a = ab[col];
  const float v = (a >= 0.f) ? ymax[gid] : ymin[gid];  // monotonicity of BN+ReLU vs sign(a)
  out[gid] = fmaxf(v * a + ab[128 + col], 0.f);
}

extern "C" void kernel_launch(void* const* d_in, const int* in_sizes, int n_in,
                              void* d_out, int out_size, void* d_ws, size_t ws_size,
                              hipStream_t stream) {
  const float* xyz = (const float*)d_in[0];
  const float* points = (const float*)d_in[1];
  const float* w0 = (const float*)d_in[2];
  const float* g0 = (const float*)d_in[4];
  const float* bt0 = (const float*)d_in[5];
  const float* w1 = (const float*)d_in[6];
  const float* g1 = (const float*)d_in[8];
  const float* bt1 = (const float*)d_in[9];
  const float* w2 = (const float*)d_in[10];
  const float* g2 = (const float*)d_in[12];
  const float* bt2 = (const float*)d_in[13];
  float* out = (float*)d_out;
  char* ws = (char*)d_ws;

  float4* sxyzp = (float4*)(ws + 0);       // 2 MB
  __bf16* w0h = (__bf16*)(ws + 2097152);   // 13312 B
  __bf16* w0l = (__bf16*)(ws + 2110464);
  __bf16* w1h = (__bf16*)(ws + 2123776);   // 9216 B
  __bf16* w1l = (__bf16*)(ws + 2132992);
  __bf16* w2h = (__bf16*)(ws + 2142208);   // 18432 B
  __bf16* w2l = (__bf16*)(ws + 2160640);
  int* idx    = (int*)(ws + 2179072);      // 2 MB
  float* y    = (float*)(ws + 4276224);    // 134217728 B (f32, reused L0->L1 in place)
  float* ymax = (float*)(ws + 138493952);  // 8388608
  float* ymin = (float*)(ws + 146882560);  // 8388608
  float* partial = (float*)(ws + 155271168); // 4194304
  float* ab   = (float*)(ws + 159465472);  // 3072
  if (ws_size < 159468544) return;

  prep_kernel<<<592, 256, 0, stream>>>(xyz, w0, w1, w2, sxyzp,
                                       w0h, w0l, w1h, w1l, w2h, w2l);
  fps_kernel<<<16, 1024, 0, stream>>>(sxyzp, out);
  ballq_kernel<<<1024, 1024, 0, stream>>>(sxyzp, out, idx);
  layer0_kernel<<<NBLK_, 256, 0, stream>>>(sxyzp, points, out, idx, w0h, w0l, y, partial);
  stat_kernel<<<64, 64, 0, stream>>>(partial, g0, bt0, ab, 64);
  layer1_kernel<<<NBLK_, 256, 0, stream>>>(y, w1h, w1l, ab, partial);
  stat_kernel<<<64, 64, 0, stream>>>(partial, g1, bt1, ab + 256, 64);
  layer2_kernel<<<NBLK_, 256, 0, stream>>>(y, w2h, w2l, ab + 256, ymax, ymin, partial);
  stat_kernel<<<128, 64, 0, stream>>>(partial, g2, bt2, ab + 512, 128);
  final_kernel<<<8192, 256, 0, stream>>>(ymax, ymin, ab + 512, out + 49152);
}

// Round 6
// 1358.948 us; speedup vs baseline: 1.2145x; 1.0446x over previous
//
#include <hip/hip_runtime.h>

// PointNet++ Set Abstraction for MI355X (gfx950).
// prep -> FPS -> ball-query -> L0(mfma) -> stat -> L1 -> stat -> L2(+pool) -> stat -> final.
// FPS replicates reference f32 elementwise arithmetic exactly (non-FMA, same order).
// Ball-query dot uses an FMA chain replicating BLAS sgemm accumulation.
// Activations stored f32; GEMMs use hi/lo split-bf16 MFMA (near-f32).
// R5: FPS distance update packed as f32x2 -> v_pk_add/mul_f32 (full-rate packed
// FP32, IEEE-identical per lane; contract off keeps exact reference op order).

typedef __bf16 bf16x8 __attribute__((ext_vector_type(8)));
typedef float f32x4 __attribute__((ext_vector_type(4)));
typedef float f32x2 __attribute__((ext_vector_type(2)));

#define B_ 16
#define N_ 8192
#define S_ 1024
#define K_ 32
#define M_ 524288   // B*S*K rows
#define NBLK_ 4096  // M/128

__device__ __forceinline__ f32x4 mfma16(bf16x8 a, bf16x8 b, f32x4 c) {
  return __builtin_amdgcn_mfma_f32_16x16x32_bf16(a, b, c, 0, 0, 0);
}

__device__ __forceinline__ void split8(const float* v, bf16x8& hi, bf16x8& lo) {
#pragma unroll
  for (int e = 0; e < 8; ++e) {
    __bf16 h = (__bf16)v[e];
    hi[e] = h;
    lo[e] = (__bf16)(v[e] - (float)h);
  }
}

// ---------------- prep: packed {x,y,z,|p|^2}, hi/lo split weights ----------------
__global__ __launch_bounds__(256) void prep_kernel(
    const float* __restrict__ xyz, const float* __restrict__ w0,
    const float* __restrict__ w1, const float* __restrict__ w2,
    float4* __restrict__ sxyzp,
    __bf16* __restrict__ w0h, __bf16* __restrict__ w0l,
    __bf16* __restrict__ w1h, __bf16* __restrict__ w1l,
    __bf16* __restrict__ w2h, __bf16* __restrict__ w2l) {
#pragma clang fp contract(off)
  int gid = blockIdx.x * 256 + threadIdx.x;
  if (gid < B_ * N_) {
    float x = xyz[gid * 3 + 0], y = xyz[gid * 3 + 1], z = xyz[gid * 3 + 2];
    float p = (x * x + y * y) + z * z;  // exact reference order
    sxyzp[gid] = make_float4(x, y, z, p);
  } else {
    int j = gid - B_ * N_;
    float v; __bf16* ph; __bf16* pl; int jj;
    if (j < 6656) {            // W0: [64][104], real c<67
      int o = j / 104, c = j % 104;
      v = (c < 67) ? w0[o * 67 + c] : 0.f; ph = w0h; pl = w0l; jj = j;
    } else if (j < 6656 + 4608) {  // W1: [64][72], real c<64
      jj = j - 6656;
      int o = jj / 72, c = jj % 72;
      v = (c < 64) ? w1[o * 64 + c] : 0.f; ph = w1h; pl = w1l;
    } else if (j < 6656 + 4608 + 9216) {  // W2: [128][72]
      jj = j - 6656 - 4608;
      int o = jj / 72, c = jj % 72;
      v = (c < 64) ? w2[o * 64 + c] : 0.f; ph = w2h; pl = w2l;
    } else return;
    __bf16 h = (__bf16)v;
    ph[jj] = h;
    pl[jj] = (__bf16)(v - (float)h);
  }
}

// ---------------- FPS: one block per batch, pk-f32 distance, LDS atomic argmax ----------------
__global__ __launch_bounds__(1024) void fps_kernel(
    const float4* __restrict__ sxyzp, float* __restrict__ out /* new_xyz (B,S,3) */) {
#pragma clang fp contract(off)
  const int b = blockIdx.x;
  const int t = threadIdx.x;
  __shared__ float4 sp[N_];                    // 128 KB
  __shared__ unsigned long long slot[4];
  const float4* src = sxyzp + (size_t)b * N_;
  for (int i = t; i < N_; i += 1024) sp[i] = src[i];
  if (t < 4) slot[t] = 0ull;
  __syncthreads();
  // contiguous chunk per lane: thread t owns points [8t, 8t+8), packed in pairs
  f32x2 px[4], py[4], pz[4], dd[4];
  const int i0 = t * 8;
#pragma unroll
  for (int w = 0; w < 8; ++w) {
    float4 v = sp[i0 + w];
    px[w >> 1][w & 1] = v.x; py[w >> 1][w & 1] = v.y; pz[w >> 1][w & 1] = v.z;
  }
#pragma unroll
  for (int j = 0; j < 4; ++j) dd[j] = (f32x2){1e10f, 1e10f};
  const int lane = t & 63;
  float* outB = out + (size_t)b * S_ * 3;
  int far = 0;
  for (int s = 0; s < S_; ++s) {
    float4 c = sp[far];
    if (t == 0) { outB[s * 3 + 0] = c.x; outB[s * 3 + 1] = c.y; outB[s * 3 + 2] = c.z; }
    const f32x2 cx = {c.x, c.x}, cy = {c.y, c.y}, cz = {c.z, c.z};
    f32x2 bv2 = {-1.0f, -1.0f};
#pragma unroll
    for (int j = 0; j < 4; ++j) {
      f32x2 dx = px[j] - cx, dy = py[j] - cy, dz = pz[j] - cz;   // v_pk_add (neg)
      f32x2 d = (dx * dx + dy * dy) + dz * dz;  // exact reference order, pk mul/add
      f32x2 nd = __builtin_elementwise_min(dd[j], d);
      dd[j] = nd;
      bv2 = __builtin_elementwise_max(bv2, nd);
    }
    float bv = fmaxf(bv2[0], bv2[1]);
    // first (lowest) local index equal to bv: descending select keeps lowest w
    int bi = 0;
#pragma unroll
    for (int w = 7; w >= 0; --w) if (dd[w >> 1][w & 1] == bv) bi = i0 + w;
    // wave-wide max on value (f32 shuffles), then first-lane index pick
    float m = bv;
#pragma unroll
    for (int off = 32; off >= 1; off >>= 1) m = fmaxf(m, __shfl_xor(m, off, 64));
    unsigned long long msk = __ballot(bv == m);
    int srcl = __ffsll(msk) - 1;
    int wbi = __shfl(bi, srcl, 64);
    if (lane == 0)
      atomicMax(&slot[(s + 1) & 3],
                ((unsigned long long)__float_as_uint(m) << 32) |
                    (unsigned long long)(0xFFFFFFFFu - (unsigned)wbi));
    __syncthreads();
    unsigned long long best = slot[(s + 1) & 3];
    far = (int)(0xFFFFFFFFu - (unsigned)(best & 0xFFFFFFFFull));
    if (t == 0) slot[(s + 3) & 3] = 0ull;  // safe: atomics into it start after next barrier
  }
}

// ---------------- ball query: 16 queries per block ----------------
__global__ __launch_bounds__(1024) void ballq_kernel(
    const float4* __restrict__ sxyzp, const float* __restrict__ newxyz,
    int* __restrict__ idxout) {
#pragma clang fp contract(off)
  __shared__ float4 sp[N_];                    // 128 KB
  __shared__ int sel[16][32];
  const int t = threadIdx.x;
  const int g = blockIdx.x;
  const int b = g >> 6;
  const int q0 = (g & 63) << 4;
  const float4* srcp = sxyzp + (size_t)b * N_;
  for (int i = t; i < N_; i += 1024) sp[i] = srcp[i];
  __syncthreads();
  const int wid = t >> 6, lane = t & 63;
  const int q = q0 + wid;
  const float* qp = newxyz + ((size_t)b * S_ + q) * 3;
  const float qx = qp[0], qy = qp[1], qz = qp[2];
  const float qq = (qx * qx + qy * qy) + qz * qz;
  const float rr = (float)(0.4 * 0.4);
  int nsel = 0;
  for (int c0 = 0; c0 < N_ && nsel < 32; c0 += 64) {
    int i = c0 + lane;
    float4 v = sp[i];
    // BLAS-style FMA accumulation chain (matches einsum->matmul lowering):
    float dot = fmaf(qz, v.z, fmaf(qy, v.y, qx * v.x));
    float d = -2.0f * dot;
    d = d + qq;
    d = d + v.w;
    unsigned long long m = __ballot(!(d > rr));
    if ((m >> lane) & 1ull) {
      int rank = nsel + __popcll(m & ((1ull << lane) - 1ull));
      if (rank < 32) sel[wid][rank] = i;
    }
    nsel += __popcll(m);
  }
  __syncthreads();
  int nv = nsel < 32 ? nsel : 32;
  int first = sel[wid][0];
  if (lane < 32)
    idxout[(((size_t)b * S_ + q) << 5) + lane] = (lane < nv) ? sel[wid][lane] : first;
}

// ---------------- layer 0: gather+concat -> split GEMM 67->64 (K padded 96) ----------------
__global__ __launch_bounds__(256) void layer0_kernel(
    const float4* __restrict__ sxyzp, const float* __restrict__ points,
    const float* __restrict__ newxyz, const int* __restrict__ idx,
    const __bf16* __restrict__ wh, const __bf16* __restrict__ wl,
    float* __restrict__ yout, float* __restrict__ partial) {
  __shared__ __align__(16) __bf16 Ah[128 * 104];
  __shared__ __align__(16) __bf16 Al[128 * 104];
  __shared__ __align__(16) __bf16 Bh[64 * 104];
  __shared__ __align__(16) __bf16 Bl[64 * 104];
  __shared__ float swsum[4][64], swsq[4][64];
  const int t = threadIdx.x;
  const int blk = blockIdx.x;
  const size_t row0 = (size_t)blk * 128;
  {
    const int4* sh4 = (const int4*)wh;
    const int4* sl4 = (const int4*)wl;
    int4* dh4 = (int4*)Bh;
    int4* dl4 = (int4*)Bl;
    for (int k = t; k < 832; k += 256) { dh4[k] = sh4[k]; dl4[k] = sl4[k]; }
  }
  {
    const int r = t >> 1, half = t & 1;
    const size_t row = row0 + r;
    const int b = (int)(row >> 15);
    const int s = (int)((row >> 5) & 1023);
    const int i = idx[row];
    const size_t bi = (size_t)b * N_ + i;
    const float* pt = points + bi * 64;
    const float* nx = newxyz + ((size_t)b * S_ + s) * 3;
    const int jb = half ? 6 : 0, je = half ? 13 : 6;
    float gx = 0.f, gy = 0.f, gz = 0.f;
    if (!half) {
      float4 xv = sxyzp[bi];
      gx = xv.x - nx[0]; gy = xv.y - nx[1]; gz = xv.z - nx[2];
    }
#pragma unroll 13
    for (int j = jb; j < je; ++j) {
      float v[8];
#pragma unroll
      for (int e = 0; e < 8; ++e) {
        const int c = j * 8 + e;
        v[e] = (c == 0) ? gx : (c == 1) ? gy : (c == 2) ? gz
               : (c < 67) ? pt[c - 3] : 0.f;
      }
      bf16x8 hi, lo;
      split8(v, hi, lo);
      *(bf16x8*)(Ah + r * 104 + j * 8) = hi;
      *(bf16x8*)(Al + r * 104 + j * 8) = lo;
    }
  }
  __syncthreads();
  const int wid = t >> 6, lane = t & 63;
  const int wrow = wid * 32;
  const int lrow = lane & 15, lk = (lane >> 4) * 8;
  f32x4 acc[2][4];
#pragma unroll
  for (int a_ = 0; a_ < 2; ++a_)
#pragma unroll
    for (int b_ = 0; b_ < 4; ++b_) acc[a_][b_] = (f32x4){0.f, 0.f, 0.f, 0.f};
#pragma unroll
  for (int ks = 0; ks < 3; ++ks) {
    const int ko = ks * 32 + lk;
    bf16x8 ah0 = *(const bf16x8*)(Ah + (wrow + lrow) * 104 + ko);
    bf16x8 al0 = *(const bf16x8*)(Al + (wrow + lrow) * 104 + ko);
    bf16x8 ah1 = *(const bf16x8*)(Ah + (wrow + 16 + lrow) * 104 + ko);
    bf16x8 al1 = *(const bf16x8*)(Al + (wrow + 16 + lrow) * 104 + ko);
#pragma unroll
    for (int cf = 0; cf < 4; ++cf) {
      bf16x8 bh = *(const bf16x8*)(Bh + (cf * 16 + lrow) * 104 + ko);
      bf16x8 bl = *(const bf16x8*)(Bl + (cf * 16 + lrow) * 104 + ko);
      acc[0][cf] = mfma16(ah0, bh, acc[0][cf]);
      acc[0][cf] = mfma16(al0, bh, acc[0][cf]);
      acc[0][cf] = mfma16(ah0, bl, acc[0][cf]);
      acc[1][cf] = mfma16(ah1, bh, acc[1][cf]);
      acc[1][cf] = mfma16(al1, bh, acc[1][cf]);
      acc[1][cf] = mfma16(ah1, bl, acc[1][cf]);
    }
  }
#pragma unroll
  for (int cf = 0; cf < 4; ++cf) {
    float s = 0.f, s2 = 0.f;
    const int col = cf * 16 + lrow;
#pragma unroll
    for (int rf = 0; rf < 2; ++rf) {
      const int rbase = wrow + rf * 16 + (lane >> 4) * 4;
#pragma unroll
      for (int q = 0; q < 4; ++q) {
        float v = acc[rf][cf][q];
        yout[(row0 + rbase + q) * 64 + col] = v;
        s += v; s2 += v * v;
      }
    }
    s += __shfl_xor(s, 16, 64); s += __shfl_xor(s, 32, 64);
    s2 += __shfl_xor(s2, 16, 64); s2 += __shfl_xor(s2, 32, 64);
    if ((lane >> 4) == 0) { swsum[wid][col] = s; swsq[wid][col] = s2; }
  }
  __syncthreads();
  if (t < 128) {
    const int c = t & 63;
    float v = (t < 64) ? (swsum[0][c] + swsum[1][c] + swsum[2][c] + swsum[3][c])
                       : (swsq[0][c] + swsq[1][c] + swsq[2][c] + swsq[3][c]);
    partial[(size_t)t * NBLK_ + blk] = v;
  }
}

// ---------------- stat: mean/var -> (a, shift) ----------------
__global__ __launch_bounds__(64) void stat_kernel(
    const float* __restrict__ partial, const float* __restrict__ g,
    const float* __restrict__ bt, float* __restrict__ ab, int nch) {
  const int o = blockIdx.x, t = threadIdx.x;
  float s = 0.f, s2 = 0.f;
  for (int i = t; i < NBLK_; i += 64) {
    s += partial[(size_t)o * NBLK_ + i];
    s2 += partial[(size_t)(nch + o) * NBLK_ + i];
  }
#pragma unroll
  for (int off = 32; off >= 1; off >>= 1) {
    s += __shfl_xor(s, off, 64);
    s2 += __shfl_xor(s2, off, 64);
  }
  if (t == 0) {
    const float minv = 1.0f / (float)M_;
    float mean = s * minv;
    float var = s2 * minv - mean * mean;
    float a = g[o] * rsqrtf(var + 1e-5f);
    ab[o] = a;
    ab[128 + o] = bt[o] - mean * a;
  }
}

// ---------------- layer 1: BN0+ReLU on load -> split GEMM 64->64 (in-place y) ----------------
__global__ __launch_bounds__(256) void layer1_kernel(
    float* y /* f32 activations, read rows then overwritten (same block) */,
    const __bf16* __restrict__ wh, const __bf16* __restrict__ wl,
    const float* __restrict__ ab, float* __restrict__ partial) {
  __shared__ __align__(16) __bf16 Ah[128 * 72];
  __shared__ __align__(16) __bf16 Al[128 * 72];
  __shared__ __align__(16) __bf16 Bh[64 * 72];
  __shared__ __align__(16) __bf16 Bl[64 * 72];
  __shared__ float sa[64], sb[64];
  __shared__ float swsum[4][64], swsq[4][64];
  const int t = threadIdx.x;
  const int blk = blockIdx.x;
  const size_t row0 = (size_t)blk * 128;
  if (t < 64) { sa[t] = ab[t]; sb[t] = ab[128 + t]; }
  {
    const int4* sh4 = (const int4*)wh;
    const int4* sl4 = (const int4*)wl;
    int4* dh4 = (int4*)Bh;
    int4* dl4 = (int4*)Bl;
    for (int k = t; k < 576; k += 256) { dh4[k] = sh4[k]; dl4[k] = sl4[k]; }
  }
  __syncthreads();
  {
    const int r = t >> 1, half = t & 1;
    const float4* s4 = (const float4*)(y + (row0 + r) * 64 + half * 32);
#pragma unroll
    for (int j = 0; j < 4; ++j) {
      float4 u = s4[j * 2], w = s4[j * 2 + 1];
      float v[8] = {u.x, u.y, u.z, u.w, w.x, w.y, w.z, w.w};
#pragma unroll
      for (int e = 0; e < 8; ++e) {
        const int c = half * 32 + j * 8 + e;
        v[e] = fmaxf(v[e] * sa[c] + sb[c], 0.f);
      }
      bf16x8 hi, lo;
      split8(v, hi, lo);
      *(bf16x8*)(Ah + r * 72 + half * 32 + j * 8) = hi;
      *(bf16x8*)(Al + r * 72 + half * 32 + j * 8) = lo;
    }
  }
  __syncthreads();
  const int wid = t >> 6, lane = t & 63;
  const int wrow = wid * 32;
  const int lrow = lane & 15, lk = (lane >> 4) * 8;
  f32x4 acc[2][4];
#pragma unroll
  for (int a_ = 0; a_ < 2; ++a_)
#pragma unroll
    for (int b_ = 0; b_ < 4; ++b_) acc[a_][b_] = (f32x4){0.f, 0.f, 0.f, 0.f};
#pragma unroll
  for (int ks = 0; ks < 2; ++ks) {
    const int ko = ks * 32 + lk;
    bf16x8 ah0 = *(const bf16x8*)(Ah + (wrow + lrow) * 72 + ko);
    bf16x8 al0 = *(const bf16x8*)(Al + (wrow + lrow) * 72 + ko);
    bf16x8 ah1 = *(const bf16x8*)(Ah + (wrow + 16 + lrow) * 72 + ko);
    bf16x8 al1 = *(const bf16x8*)(Al + (wrow + 16 + lrow) * 72 + ko);
#pragma unroll
    for (int cf = 0; cf < 4; ++cf) {
      bf16x8 bh = *(const bf16x8*)(Bh + (cf * 16 + lrow) * 72 + ko);
      bf16x8 bl = *(const bf16x8*)(Bl + (cf * 16 + lrow) * 72 + ko);
      acc[0][cf] = mfma16(ah0, bh, acc[0][cf]);
      acc[0][cf] = mfma16(al0, bh, acc[0][cf]);
      acc[0][cf] = mfma16(ah0, bl, acc[0][cf]);
      acc[1][cf] = mfma16(ah1, bh, acc[1][cf]);
      acc[1][cf] = mfma16(al1, bh, acc[1][cf]);
      acc[1][cf] = mfma16(ah1, bl, acc[1][cf]);
    }
  }
#pragma unroll
  for (int cf = 0; cf < 4; ++cf) {
    float s = 0.f, s2 = 0.f;
    const int col = cf * 16 + lrow;
#pragma unroll
    for (int rf = 0; rf < 2; ++rf) {
      const int rbase = wrow + rf * 16 + (lane >> 4) * 4;
#pragma unroll
      for (int q = 0; q < 4; ++q) {
        float v = acc[rf][cf][q];
        y[(row0 + rbase + q) * 64 + col] = v;
        s += v; s2 += v * v;
      }
    }
    s += __shfl_xor(s, 16, 64); s += __shfl_xor(s, 32, 64);
    s2 += __shfl_xor(s2, 16, 64); s2 += __shfl_xor(s2, 32, 64);
    if ((lane >> 4) == 0) { swsum[wid][col] = s; swsq[wid][col] = s2; }
  }
  __syncthreads();
  if (t < 128) {
    const int c = t & 63;
    float v = (t < 64) ? (swsum[0][c] + swsum[1][c] + swsum[2][c] + swsum[3][c])
                       : (swsq[0][c] + swsq[1][c] + swsq[2][c] + swsq[3][c]);
    partial[(size_t)t * NBLK_ + blk] = v;
  }
}

// ---------------- layer 2: BN1+ReLU -> split GEMM 64->128 + fused max/min pool ----------------
__global__ __launch_bounds__(256) void layer2_kernel(
    const float* __restrict__ yin, const __bf16* __restrict__ wh,
    const __bf16* __restrict__ wl, const float* __restrict__ ab,
    float* __restrict__ ymax, float* __restrict__ ymin,
    float* __restrict__ partial) {
  __shared__ __align__(16) __bf16 Ah[128 * 72];
  __shared__ __align__(16) __bf16 Al[128 * 72];
  __shared__ __align__(16) __bf16 Bh[128 * 72];
  __shared__ __align__(16) __bf16 Bl[128 * 72];
  __shared__ float sa[64], sb[64];
  __shared__ float swsum[4][128], swsq[4][128];
  const int t = threadIdx.x;
  const int blk = blockIdx.x;
  const size_t row0 = (size_t)blk * 128;
  if (t < 64) { sa[t] = ab[t]; sb[t] = ab[128 + t]; }
  {
    const int4* sh4 = (const int4*)wh;
    const int4* sl4 = (const int4*)wl;
    int4* dh4 = (int4*)Bh;
    int4* dl4 = (int4*)Bl;
    for (int k = t; k < 1152; k += 256) { dh4[k] = sh4[k]; dl4[k] = sl4[k]; }
  }
  __syncthreads();
  {
    const int r = t >> 1, half = t & 1;
    const float4* s4 = (const float4*)(yin + (row0 + r) * 64 + half * 32);
#pragma unroll
    for (int j = 0; j < 4; ++j) {
      float4 u = s4[j * 2], w = s4[j * 2 + 1];
      float v[8] = {u.x, u.y, u.z, u.w, w.x, w.y, w.z, w.w};
#pragma unroll
      for (int e = 0; e < 8; ++e) {
        const int c = half * 32 + j * 8 + e;
        v[e] = fmaxf(v[e] * sa[c] + sb[c], 0.f);
      }
      bf16x8 hi, lo;
      split8(v, hi, lo);
      *(bf16x8*)(Ah + r * 72 + half * 32 + j * 8) = hi;
      *(bf16x8*)(Al + r * 72 + half * 32 + j * 8) = lo;
    }
  }
  __syncthreads();
  const int wid = t >> 6, lane = t & 63;
  const int wrow = wid * 32;
  const int lrow = lane & 15, lk = (lane >> 4) * 8;
  f32x4 acc[2][8];
#pragma unroll
  for (int a_ = 0; a_ < 2; ++a_)
#pragma unroll
    for (int b_ = 0; b_ < 8; ++b_) acc[a_][b_] = (f32x4){0.f, 0.f, 0.f, 0.f};
#pragma unroll
  for (int ks = 0; ks < 2; ++ks) {
    const int ko = ks * 32 + lk;
    bf16x8 ah0 = *(const bf16x8*)(Ah + (wrow + lrow) * 72 + ko);
    bf16x8 al0 = *(const bf16x8*)(Al + (wrow + lrow) * 72 + ko);
    bf16x8 ah1 = *(const bf16x8*)(Ah + (wrow + 16 + lrow) * 72 + ko);
    bf16x8 al1 = *(const bf16x8*)(Al + (wrow + 16 + lrow) * 72 + ko);
#pragma unroll
    for (int cf = 0; cf < 8; ++cf) {
      bf16x8 bh = *(const bf16x8*)(Bh + (cf * 16 + lrow) * 72 + ko);
      bf16x8 bl = *(const bf16x8*)(Bl + (cf * 16 + lrow) * 72 + ko);
      acc[0][cf] = mfma16(ah0, bh, acc[0][cf]);
      acc[0][cf] = mfma16(al0, bh, acc[0][cf]);
      acc[0][cf] = mfma16(ah0, bl, acc[0][cf]);
      acc[1][cf] = mfma16(ah1, bh, acc[1][cf]);
      acc[1][cf] = mfma16(al1, bh, acc[1][cf]);
      acc[1][cf] = mfma16(ah1, bl, acc[1][cf]);
    }
  }
  // each wave's 32 rows form exactly one (b,s) group
  const size_t bs = (size_t)blk * 4 + wid;
#pragma unroll
  for (int cf = 0; cf < 8; ++cf) {
    float s = 0.f, s2 = 0.f, mx = -3.4e38f, mn = 3.4e38f;
    const int col = cf * 16 + lrow;
#pragma unroll
    for (int rf = 0; rf < 2; ++rf)
#pragma unroll
      for (int q = 0; q < 4; ++q) {
        float v = acc[rf][cf][q];
        s += v; s2 += v * v;
        mx = fmaxf(mx, v); mn = fminf(mn, v);
      }
    s += __shfl_xor(s, 16, 64); s += __shfl_xor(s, 32, 64);
    s2 += __shfl_xor(s2, 16, 64); s2 += __shfl_xor(s2, 32, 64);
    mx = fmaxf(mx, __shfl_xor(mx, 16, 64)); mx = fmaxf(mx, __shfl_xor(mx, 32, 64));
    mn = fminf(mn, __shfl_xor(mn, 16, 64)); mn = fminf(mn, __shfl_xor(mn, 32, 64));
    if ((lane >> 4) == 0) {
      ymax[bs * 128 + col] = mx;
      ymin[bs * 128 + col] = mn;
      swsum[wid][col] = s; swsq[wid][col] = s2;
    }
  }
  __syncthreads();
  if (t < 128) {
    float v = swsum[0][t] + swsum[1][t] + swsum[2][t] + swsum[3][t];
    partial[(size_t)t * NBLK_ + blk] = v;
  } else {
    const int c = t - 128;
    float v = swsq[0][c] + swsq[1][c] + swsq[2][c] + swsq[3][c];
    partial[(size_t)t * NBLK_ + blk] = v;
  }
}

// ---------------- final: BN2+ReLU on pooled values ----------------
__global__ __launch_bounds__(256) void final_kernel(
    const float* __restrict__ ymax, const float* __restrict__ ymin,
    const float* __restrict__ ab, float* __restrict__ out) {
  const int gid = blockIdx.x * 256 + threadIdx.x;  // B*S*128
  const int col = gid & 127;
  const float a = ab[col];
  const float v = (a >= 0.f) ? ymax[gid] : ymin[gid];  // monotonicity of BN+ReLU vs sign(a)
  out[gid] = fmaxf(v * a + ab[128 + col], 0.f);
}

extern "C" void kernel_launch(void* const* d_in, const int* in_sizes, int n_in,
                              void* d_out, int out_size, void* d_ws, size_t ws_size,
                              hipStream_t stream) {
  const float* xyz = (const float*)d_in[0];
  const float* points = (const float*)d_in[1];
  const float* w0 = (const float*)d_in[2];
  const float* g0 = (const float*)d_in[4];
  const float* bt0 = (const float*)d_in[5];
  const float* w1 = (const float*)d_in[6];
  const float* g1 = (const float*)d_in[8];
  const float* bt1 = (const float*)d_in[9];
  const float* w2 = (const float*)d_in[10];
  const float* g2 = (const float*)d_in[12];
  const float* bt2 = (const float*)d_in[13];
  float* out = (float*)d_out;
  char* ws = (char*)d_ws;

  float4* sxyzp = (float4*)(ws + 0);       // 2 MB
  __bf16* w0h = (__bf16*)(ws + 2097152);   // 13312 B
  __bf16* w0l = (__bf16*)(ws + 2110464);
  __bf16* w1h = (__bf16*)(ws + 2123776);   // 9216 B
  __bf16* w1l = (__bf16*)(ws + 2132992);
  __bf16* w2h = (__bf16*)(ws + 2142208);   // 18432 B
  __bf16* w2l = (__bf16*)(ws + 2160640);
  int* idx    = (int*)(ws + 2179072);      // 2 MB
  float* y    = (float*)(ws + 4276224);    // 134217728 B (f32, reused L0->L1 in place)
  float* ymax = (float*)(ws + 138493952);  // 8388608
  float* ymin = (float*)(ws + 146882560);  // 8388608
  float* partial = (float*)(ws + 155271168); // 4194304
  float* ab   = (float*)(ws + 159465472);  // 3072
  if (ws_size < 159468544) return;

  prep_kernel<<<592, 256, 0, stream>>>(xyz, w0, w1, w2, sxyzp,
                                       w0h, w0l, w1h, w1l, w2h, w2l);
  fps_kernel<<<16, 1024, 0, stream>>>(sxyzp, out);
  ballq_kernel<<<1024, 1024, 0, stream>>>(sxyzp, out, idx);
  layer0_kernel<<<NBLK_, 256, 0, stream>>>(sxyzp, points, out, idx, w0h, w0l, y, partial);
  stat_kernel<<<64, 64, 0, stream>>>(partial, g0, bt0, ab, 64);
  layer1_kernel<<<NBLK_, 256, 0, stream>>>(y, w1h, w1l, ab, partial);
  stat_kernel<<<64, 64, 0, stream>>>(partial, g1, bt1, ab + 256, 64);
  layer2_kernel<<<NBLK_, 256, 0, stream>>>(y, w2h, w2l, ab + 256, ymax, ymin, partial);
  stat_kernel<<<128, 64, 0, stream>>>(partial, g2, bt2, ab + 512, 128);
  final_kernel<<<8192, 256, 0, stream>>>(ymax, ymin, ab + 512, out + 49152);
}

// Round 7
// 1350.509 us; speedup vs baseline: 1.2221x; 1.0062x over previous
//
#include <hip/hip_runtime.h>

// PointNet++ Set Abstraction for MI355X (gfx950).
// prep -> FPS -> ball-query -> L0(mfma) -> stat -> L1 -> stat -> L2(+pool) -> stat -> final.
// FPS replicates reference f32 elementwise arithmetic exactly (non-FMA, same order).
// Ball-query dot uses an FMA chain replicating BLAS sgemm accumulation.
// Activations stored f32; GEMMs use hi/lo split-bf16 MFMA (near-f32).
// R6: FPS reshaped to 256 threads x 32 pts/thread: 1 wave/SIMD (no intra-SIMD
// issue serialization), 4 LDS atomics/step (was 16), 4-wave barrier.

typedef __bf16 bf16x8 __attribute__((ext_vector_type(8)));
typedef float f32x4 __attribute__((ext_vector_type(4)));
typedef float f32x2 __attribute__((ext_vector_type(2)));

#define B_ 16
#define N_ 8192
#define S_ 1024
#define K_ 32
#define M_ 524288   // B*S*K rows
#define NBLK_ 4096  // M/128

__device__ __forceinline__ f32x4 mfma16(bf16x8 a, bf16x8 b, f32x4 c) {
  return __builtin_amdgcn_mfma_f32_16x16x32_bf16(a, b, c, 0, 0, 0);
}

__device__ __forceinline__ void split8(const float* v, bf16x8& hi, bf16x8& lo) {
#pragma unroll
  for (int e = 0; e < 8; ++e) {
    __bf16 h = (__bf16)v[e];
    hi[e] = h;
    lo[e] = (__bf16)(v[e] - (float)h);
  }
}

// ---------------- prep: packed {x,y,z,|p|^2}, hi/lo split weights ----------------
__global__ __launch_bounds__(256) void prep_kernel(
    const float* __restrict__ xyz, const float* __restrict__ w0,
    const float* __restrict__ w1, const float* __restrict__ w2,
    float4* __restrict__ sxyzp,
    __bf16* __restrict__ w0h, __bf16* __restrict__ w0l,
    __bf16* __restrict__ w1h, __bf16* __restrict__ w1l,
    __bf16* __restrict__ w2h, __bf16* __restrict__ w2l) {
#pragma clang fp contract(off)
  int gid = blockIdx.x * 256 + threadIdx.x;
  if (gid < B_ * N_) {
    float x = xyz[gid * 3 + 0], y = xyz[gid * 3 + 1], z = xyz[gid * 3 + 2];
    float p = (x * x + y * y) + z * z;  // exact reference order
    sxyzp[gid] = make_float4(x, y, z, p);
  } else {
    int j = gid - B_ * N_;
    float v; __bf16* ph; __bf16* pl; int jj;
    if (j < 6656) {            // W0: [64][104], real c<67
      int o = j / 104, c = j % 104;
      v = (c < 67) ? w0[o * 67 + c] : 0.f; ph = w0h; pl = w0l; jj = j;
    } else if (j < 6656 + 4608) {  // W1: [64][72], real c<64
      jj = j - 6656;
      int o = jj / 72, c = jj % 72;
      v = (c < 64) ? w1[o * 64 + c] : 0.f; ph = w1h; pl = w1l;
    } else if (j < 6656 + 4608 + 9216) {  // W2: [128][72]
      jj = j - 6656 - 4608;
      int o = jj / 72, c = jj % 72;
      v = (c < 64) ? w2[o * 64 + c] : 0.f; ph = w2h; pl = w2l;
    } else return;
    __bf16 h = (__bf16)v;
    ph[jj] = h;
    pl[jj] = (__bf16)(v - (float)h);
  }
}

// ---------------- FPS: one block per batch, 256 thr x 32 pts, LDS atomic argmax ----------------
__global__ __launch_bounds__(256, 1) void fps_kernel(
    const float4* __restrict__ sxyzp, float* __restrict__ out /* new_xyz (B,S,3) */) {
#pragma clang fp contract(off)
  const int b = blockIdx.x;
  const int t = threadIdx.x;
  __shared__ float4 sp[N_];                    // 128 KB
  __shared__ unsigned long long slot[4];
  const float4* src = sxyzp + (size_t)b * N_;
  for (int i = t; i < N_; i += 256) sp[i] = src[i];
  if (t < 4) slot[t] = 0ull;
  __syncthreads();
  // contiguous chunk per lane: thread t owns points [32t, 32t+32), packed in pairs
  f32x2 px[16], py[16], pz[16], dd[16];
  const int i0 = t * 32;
#pragma unroll
  for (int w = 0; w < 32; ++w) {
    float4 v = sp[i0 + w];
    px[w >> 1][w & 1] = v.x; py[w >> 1][w & 1] = v.y; pz[w >> 1][w & 1] = v.z;
  }
#pragma unroll
  for (int j = 0; j < 16; ++j) dd[j] = (f32x2){1e10f, 1e10f};
  const int lane = t & 63;
  float* outB = out + (size_t)b * S_ * 3;
  int far = 0;
  for (int s = 0; s < S_; ++s) {
    float4 c = sp[far];
    if (t == 0) { outB[s * 3 + 0] = c.x; outB[s * 3 + 1] = c.y; outB[s * 3 + 2] = c.z; }
    const f32x2 cx = {c.x, c.x}, cy = {c.y, c.y}, cz = {c.z, c.z};
    f32x2 bv2 = {-1.0f, -1.0f};
#pragma unroll
    for (int j = 0; j < 16; ++j) {
      f32x2 dx = px[j] - cx, dy = py[j] - cy, dz = pz[j] - cz;   // v_pk_add (neg)
      f32x2 d = (dx * dx + dy * dy) + dz * dz;  // exact reference order, pk mul/add
      f32x2 nd = __builtin_elementwise_min(dd[j], d);
      dd[j] = nd;
      bv2 = __builtin_elementwise_max(bv2, nd);
    }
    float bv = fmaxf(bv2[0], bv2[1]);
    // first (lowest) local index equal to bv: descending select keeps lowest w
    int bi = 0;
#pragma unroll
    for (int w = 31; w >= 0; --w) if (dd[w >> 1][w & 1] == bv) bi = i0 + w;
    // wave-wide max on value (f32 shuffles), then first-lane index pick
    float m = bv;
#pragma unroll
    for (int off = 32; off >= 1; off >>= 1) m = fmaxf(m, __shfl_xor(m, off, 64));
    unsigned long long msk = __ballot(bv == m);
    int srcl = __ffsll(msk) - 1;
    int wbi = __shfl(bi, srcl, 64);
    if (lane == 0)
      atomicMax(&slot[(s + 1) & 3],
                ((unsigned long long)__float_as_uint(m) << 32) |
                    (unsigned long long)(0xFFFFFFFFu - (unsigned)wbi));
    __syncthreads();
    unsigned long long best = slot[(s + 1) & 3];
    far = (int)(0xFFFFFFFFu - (unsigned)(best & 0xFFFFFFFFull));
    if (t == 0) slot[(s + 3) & 3] = 0ull;  // safe: atomics into it start after next barrier
  }
}

// ---------------- ball query: 16 queries per block ----------------
__global__ __launch_bounds__(1024) void ballq_kernel(
    const float4* __restrict__ sxyzp, const float* __restrict__ newxyz,
    int* __restrict__ idxout) {
#pragma clang fp contract(off)
  __shared__ float4 sp[N_];                    // 128 KB
  __shared__ int sel[16][32];
  const int t = threadIdx.x;
  const int g = blockIdx.x;
  const int b = g >> 6;
  const int q0 = (g & 63) << 4;
  const float4* srcp = sxyzp + (size_t)b * N_;
  for (int i = t; i < N_; i += 1024) sp[i] = srcp[i];
  __syncthreads();
  const int wid = t >> 6, lane = t & 63;
  const int q = q0 + wid;
  const float* qp = newxyz + ((size_t)b * S_ + q) * 3;
  const float qx = qp[0], qy = qp[1], qz = qp[2];
  const float qq = (qx * qx + qy * qy) + qz * qz;
  const float rr = (float)(0.4 * 0.4);
  int nsel = 0;
  for (int c0 = 0; c0 < N_ && nsel < 32; c0 += 64) {
    int i = c0 + lane;
    float4 v = sp[i];
    // BLAS-style FMA accumulation chain (matches einsum->matmul lowering):
    float dot = fmaf(qz, v.z, fmaf(qy, v.y, qx * v.x));
    float d = -2.0f * dot;
    d = d + qq;
    d = d + v.w;
    unsigned long long m = __ballot(!(d > rr));
    if ((m >> lane) & 1ull) {
      int rank = nsel + __popcll(m & ((1ull << lane) - 1ull));
      if (rank < 32) sel[wid][rank] = i;
    }
    nsel += __popcll(m);
  }
  __syncthreads();
  int nv = nsel < 32 ? nsel : 32;
  int first = sel[wid][0];
  if (lane < 32)
    idxout[(((size_t)b * S_ + q) << 5) + lane] = (lane < nv) ? sel[wid][lane] : first;
}

// ---------------- layer 0: gather+concat -> split GEMM 67->64 (K padded 96) ----------------
__global__ __launch_bounds__(256) void layer0_kernel(
    const float4* __restrict__ sxyzp, const float* __restrict__ points,
    const float* __restrict__ newxyz, const int* __restrict__ idx,
    const __bf16* __restrict__ wh, const __bf16* __restrict__ wl,
    float* __restrict__ yout, float* __restrict__ partial) {
  __shared__ __align__(16) __bf16 Ah[128 * 104];
  __shared__ __align__(16) __bf16 Al[128 * 104];
  __shared__ __align__(16) __bf16 Bh[64 * 104];
  __shared__ __align__(16) __bf16 Bl[64 * 104];
  __shared__ float swsum[4][64], swsq[4][64];
  const int t = threadIdx.x;
  const int blk = blockIdx.x;
  const size_t row0 = (size_t)blk * 128;
  {
    const int4* sh4 = (const int4*)wh;
    const int4* sl4 = (const int4*)wl;
    int4* dh4 = (int4*)Bh;
    int4* dl4 = (int4*)Bl;
    for (int k = t; k < 832; k += 256) { dh4[k] = sh4[k]; dl4[k] = sl4[k]; }
  }
  {
    const int r = t >> 1, half = t & 1;
    const size_t row = row0 + r;
    const int b = (int)(row >> 15);
    const int s = (int)((row >> 5) & 1023);
    const int i = idx[row];
    const size_t bi = (size_t)b * N_ + i;
    const float* pt = points + bi * 64;
    const float* nx = newxyz + ((size_t)b * S_ + s) * 3;
    const int jb = half ? 6 : 0, je = half ? 13 : 6;
    float gx = 0.f, gy = 0.f, gz = 0.f;
    if (!half) {
      float4 xv = sxyzp[bi];
      gx = xv.x - nx[0]; gy = xv.y - nx[1]; gz = xv.z - nx[2];
    }
#pragma unroll 13
    for (int j = jb; j < je; ++j) {
      float v[8];
#pragma unroll
      for (int e = 0; e < 8; ++e) {
        const int c = j * 8 + e;
        v[e] = (c == 0) ? gx : (c == 1) ? gy : (c == 2) ? gz
               : (c < 67) ? pt[c - 3] : 0.f;
      }
      bf16x8 hi, lo;
      split8(v, hi, lo);
      *(bf16x8*)(Ah + r * 104 + j * 8) = hi;
      *(bf16x8*)(Al + r * 104 + j * 8) = lo;
    }
  }
  __syncthreads();
  const int wid = t >> 6, lane = t & 63;
  const int wrow = wid * 32;
  const int lrow = lane & 15, lk = (lane >> 4) * 8;
  f32x4 acc[2][4];
#pragma unroll
  for (int a_ = 0; a_ < 2; ++a_)
#pragma unroll
    for (int b_ = 0; b_ < 4; ++b_) acc[a_][b_] = (f32x4){0.f, 0.f, 0.f, 0.f};
#pragma unroll
  for (int ks = 0; ks < 3; ++ks) {
    const int ko = ks * 32 + lk;
    bf16x8 ah0 = *(const bf16x8*)(Ah + (wrow + lrow) * 104 + ko);
    bf16x8 al0 = *(const bf16x8*)(Al + (wrow + lrow) * 104 + ko);
    bf16x8 ah1 = *(const bf16x8*)(Ah + (wrow + 16 + lrow) * 104 + ko);
    bf16x8 al1 = *(const bf16x8*)(Al + (wrow + 16 + lrow) * 104 + ko);
#pragma unroll
    for (int cf = 0; cf < 4; ++cf) {
      bf16x8 bh = *(const bf16x8*)(Bh + (cf * 16 + lrow) * 104 + ko);
      bf16x8 bl = *(const bf16x8*)(Bl + (cf * 16 + lrow) * 104 + ko);
      acc[0][cf] = mfma16(ah0, bh, acc[0][cf]);
      acc[0][cf] = mfma16(al0, bh, acc[0][cf]);
      acc[0][cf] = mfma16(ah0, bl, acc[0][cf]);
      acc[1][cf] = mfma16(ah1, bh, acc[1][cf]);
      acc[1][cf] = mfma16(al1, bh, acc[1][cf]);
      acc[1][cf] = mfma16(ah1, bl, acc[1][cf]);
    }
  }
#pragma unroll
  for (int cf = 0; cf < 4; ++cf) {
    float s = 0.f, s2 = 0.f;
    const int col = cf * 16 + lrow;
#pragma unroll
    for (int rf = 0; rf < 2; ++rf) {
      const int rbase = wrow + rf * 16 + (lane >> 4) * 4;
#pragma unroll
      for (int q = 0; q < 4; ++q) {
        float v = acc[rf][cf][q];
        yout[(row0 + rbase + q) * 64 + col] = v;
        s += v; s2 += v * v;
      }
    }
    s += __shfl_xor(s, 16, 64); s += __shfl_xor(s, 32, 64);
    s2 += __shfl_xor(s2, 16, 64); s2 += __shfl_xor(s2, 32, 64);
    if ((lane >> 4) == 0) { swsum[wid][col] = s; swsq[wid][col] = s2; }
  }
  __syncthreads();
  if (t < 128) {
    const int c = t & 63;
    float v = (t < 64) ? (swsum[0][c] + swsum[1][c] + swsum[2][c] + swsum[3][c])
                       : (swsq[0][c] + swsq[1][c] + swsq[2][c] + swsq[3][c]);
    partial[(size_t)t * NBLK_ + blk] = v;
  }
}

// ---------------- stat: mean/var -> (a, shift) ----------------
__global__ __launch_bounds__(64) void stat_kernel(
    const float* __restrict__ partial, const float* __restrict__ g,
    const float* __restrict__ bt, float* __restrict__ ab, int nch) {
  const int o = blockIdx.x, t = threadIdx.x;
  float s = 0.f, s2 = 0.f;
  for (int i = t; i < NBLK_; i += 64) {
    s += partial[(size_t)o * NBLK_ + i];
    s2 += partial[(size_t)(nch + o) * NBLK_ + i];
  }
#pragma unroll
  for (int off = 32; off >= 1; off >>= 1) {
    s += __shfl_xor(s, off, 64);
    s2 += __shfl_xor(s2, off, 64);
  }
  if (t == 0) {
    const float minv = 1.0f / (float)M_;
    float mean = s * minv;
    float var = s2 * minv - mean * mean;
    float a = g[o] * rsqrtf(var + 1e-5f);
    ab[o] = a;
    ab[128 + o] = bt[o] - mean * a;
  }
}

// ---------------- layer 1: BN0+ReLU on load -> split GEMM 64->64 (in-place y) ----------------
__global__ __launch_bounds__(256) void layer1_kernel(
    float* y /* f32 activations, read rows then overwritten (same block) */,
    const __bf16* __restrict__ wh, const __bf16* __restrict__ wl,
    const float* __restrict__ ab, float* __restrict__ partial) {
  __shared__ __align__(16) __bf16 Ah[128 * 72];
  __shared__ __align__(16) __bf16 Al[128 * 72];
  __shared__ __align__(16) __bf16 Bh[64 * 72];
  __shared__ __align__(16) __bf16 Bl[64 * 72];
  __shared__ float sa[64], sb[64];
  __shared__ float swsum[4][64], swsq[4][64];
  const int t = threadIdx.x;
  const int blk = blockIdx.x;
  const size_t row0 = (size_t)blk * 128;
  if (t < 64) { sa[t] = ab[t]; sb[t] = ab[128 + t]; }
  {
    const int4* sh4 = (const int4*)wh;
    const int4* sl4 = (const int4*)wl;
    int4* dh4 = (int4*)Bh;
    int4* dl4 = (int4*)Bl;
    for (int k = t; k < 576; k += 256) { dh4[k] = sh4[k]; dl4[k] = sl4[k]; }
  }
  __syncthreads();
  {
    const int r = t >> 1, half = t & 1;
    const float4* s4 = (const float4*)(y + (row0 + r) * 64 + half * 32);
#pragma unroll
    for (int j = 0; j < 4; ++j) {
      float4 u = s4[j * 2], w = s4[j * 2 + 1];
      float v[8] = {u.x, u.y, u.z, u.w, w.x, w.y, w.z, w.w};
#pragma unroll
      for (int e = 0; e < 8; ++e) {
        const int c = half * 32 + j * 8 + e;
        v[e] = fmaxf(v[e] * sa[c] + sb[c], 0.f);
      }
      bf16x8 hi, lo;
      split8(v, hi, lo);
      *(bf16x8*)(Ah + r * 72 + half * 32 + j * 8) = hi;
      *(bf16x8*)(Al + r * 72 + half * 32 + j * 8) = lo;
    }
  }
  __syncthreads();
  const int wid = t >> 6, lane = t & 63;
  const int wrow = wid * 32;
  const int lrow = lane & 15, lk = (lane >> 4) * 8;
  f32x4 acc[2][4];
#pragma unroll
  for (int a_ = 0; a_ < 2; ++a_)
#pragma unroll
    for (int b_ = 0; b_ < 4; ++b_) acc[a_][b_] = (f32x4){0.f, 0.f, 0.f, 0.f};
#pragma unroll
  for (int ks = 0; ks < 2; ++ks) {
    const int ko = ks * 32 + lk;
    bf16x8 ah0 = *(const bf16x8*)(Ah + (wrow + lrow) * 72 + ko);
    bf16x8 al0 = *(const bf16x8*)(Al + (wrow + lrow) * 72 + ko);
    bf16x8 ah1 = *(const bf16x8*)(Ah + (wrow + 16 + lrow) * 72 + ko);
    bf16x8 al1 = *(const bf16x8*)(Al + (wrow + 16 + lrow) * 72 + ko);
#pragma unroll
    for (int cf = 0; cf < 4; ++cf) {
      bf16x8 bh = *(const bf16x8*)(Bh + (cf * 16 + lrow) * 72 + ko);
      bf16x8 bl = *(const bf16x8*)(Bl + (cf * 16 + lrow) * 72 + ko);
      acc[0][cf] = mfma16(ah0, bh, acc[0][cf]);
      acc[0][cf] = mfma16(al0, bh, acc[0][cf]);
      acc[0][cf] = mfma16(ah0, bl, acc[0][cf]);
      acc[1][cf] = mfma16(ah1, bh, acc[1][cf]);
      acc[1][cf] = mfma16(al1, bh, acc[1][cf]);
      acc[1][cf] = mfma16(ah1, bl, acc[1][cf]);
    }
  }
#pragma unroll
  for (int cf = 0; cf < 4; ++cf) {
    float s = 0.f, s2 = 0.f;
    const int col = cf * 16 + lrow;
#pragma unroll
    for (int rf = 0; rf < 2; ++rf) {
      const int rbase = wrow + rf * 16 + (lane >> 4) * 4;
#pragma unroll
      for (int q = 0; q < 4; ++q) {
        float v = acc[rf][cf][q];
        y[(row0 + rbase + q) * 64 + col] = v;
        s += v; s2 += v * v;
      }
    }
    s += __shfl_xor(s, 16, 64); s += __shfl_xor(s, 32, 64);
    s2 += __shfl_xor(s2, 16, 64); s2 += __shfl_xor(s2, 32, 64);
    if ((lane >> 4) == 0) { swsum[wid][col] = s; swsq[wid][col] = s2; }
  }
  __syncthreads();
  if (t < 128) {
    const int c = t & 63;
    float v = (t < 64) ? (swsum[0][c] + swsum[1][c] + swsum[2][c] + swsum[3][c])
                       : (swsq[0][c] + swsq[1][c] + swsq[2][c] + swsq[3][c]);
    partial[(size_t)t * NBLK_ + blk] = v;
  }
}

// ---------------- layer 2: BN1+ReLU -> split GEMM 64->128 + fused max/min pool ----------------
__global__ __launch_bounds__(256) void layer2_kernel(
    const float* __restrict__ yin, const __bf16* __restrict__ wh,
    const __bf16* __restrict__ wl, const float* __restrict__ ab,
    float* __restrict__ ymax, float* __restrict__ ymin,
    float* __restrict__ partial) {
  __shared__ __align__(16) __bf16 Ah[128 * 72];
  __shared__ __align__(16) __bf16 Al[128 * 72];
  __shared__ __align__(16) __bf16 Bh[128 * 72];
  __shared__ __align__(16) __bf16 Bl[128 * 72];
  __shared__ float sa[64], sb[64];
  __shared__ float swsum[4][128], swsq[4][128];
  const int t = threadIdx.x;
  const int blk = blockIdx.x;
  const size_t row0 = (size_t)blk * 128;
  if (t < 64) { sa[t] = ab[t]; sb[t] = ab[128 + t]; }
  {
    const int4* sh4 = (const int4*)wh;
    const int4* sl4 = (const int4*)wl;
    int4* dh4 = (int4*)Bh;
    int4* dl4 = (int4*)Bl;
    for (int k = t; k < 1152; k += 256) { dh4[k] = sh4[k]; dl4[k] = sl4[k]; }
  }
  __syncthreads();
  {
    const int r = t >> 1, half = t & 1;
    const float4* s4 = (const float4*)(yin + (row0 + r) * 64 + half * 32);
#pragma unroll
    for (int j = 0; j < 4; ++j) {
      float4 u = s4[j * 2], w = s4[j * 2 + 1];
      float v[8] = {u.x, u.y, u.z, u.w, w.x, w.y, w.z, w.w};
#pragma unroll
      for (int e = 0; e < 8; ++e) {
        const int c = half * 32 + j * 8 + e;
        v[e] = fmaxf(v[e] * sa[c] + sb[c], 0.f);
      }
      bf16x8 hi, lo;
      split8(v, hi, lo);
      *(bf16x8*)(Ah + r * 72 + half * 32 + j * 8) = hi;
      *(bf16x8*)(Al + r * 72 + half * 32 + j * 8) = lo;
    }
  }
  __syncthreads();
  const int wid = t >> 6, lane = t & 63;
  const int wrow = wid * 32;
  const int lrow = lane & 15, lk = (lane >> 4) * 8;
  f32x4 acc[2][8];
#pragma unroll
  for (int a_ = 0; a_ < 2; ++a_)
#pragma unroll
    for (int b_ = 0; b_ < 8; ++b_) acc[a_][b_] = (f32x4){0.f, 0.f, 0.f, 0.f};
#pragma unroll
  for (int ks = 0; ks < 2; ++ks) {
    const int ko = ks * 32 + lk;
    bf16x8 ah0 = *(const bf16x8*)(Ah + (wrow + lrow) * 72 + ko);
    bf16x8 al0 = *(const bf16x8*)(Al + (wrow + lrow) * 72 + ko);
    bf16x8 ah1 = *(const bf16x8*)(Ah + (wrow + 16 + lrow) * 72 + ko);
    bf16x8 al1 = *(const bf16x8*)(Al + (wrow + 16 + lrow) * 72 + ko);
#pragma unroll
    for (int cf = 0; cf < 8; ++cf) {
      bf16x8 bh = *(const bf16x8*)(Bh + (cf * 16 + lrow) * 72 + ko);
      bf16x8 bl = *(const bf16x8*)(Bl + (cf * 16 + lrow) * 72 + ko);
      acc[0][cf] = mfma16(ah0, bh, acc[0][cf]);
      acc[0][cf] = mfma16(al0, bh, acc[0][cf]);
      acc[0][cf] = mfma16(ah0, bl, acc[0][cf]);
      acc[1][cf] = mfma16(ah1, bh, acc[1][cf]);
      acc[1][cf] = mfma16(al1, bh, acc[1][cf]);
      acc[1][cf] = mfma16(ah1, bl, acc[1][cf]);
    }
  }
  // each wave's 32 rows form exactly one (b,s) group
  const size_t bs = (size_t)blk * 4 + wid;
#pragma unroll
  for (int cf = 0; cf < 8; ++cf) {
    float s = 0.f, s2 = 0.f, mx = -3.4e38f, mn = 3.4e38f;
    const int col = cf * 16 + lrow;
#pragma unroll
    for (int rf = 0; rf < 2; ++rf)
#pragma unroll
      for (int q = 0; q < 4; ++q) {
        float v = acc[rf][cf][q];
        s += v; s2 += v * v;
        mx = fmaxf(mx, v); mn = fminf(mn, v);
      }
    s += __shfl_xor(s, 16, 64); s += __shfl_xor(s, 32, 64);
    s2 += __shfl_xor(s2, 16, 64); s2 += __shfl_xor(s2, 32, 64);
    mx = fmaxf(mx, __shfl_xor(mx, 16, 64)); mx = fmaxf(mx, __shfl_xor(mx, 32, 64));
    mn = fminf(mn, __shfl_xor(mn, 16, 64)); mn = fminf(mn, __shfl_xor(mn, 32, 64));
    if ((lane >> 4) == 0) {
      ymax[bs * 128 + col] = mx;
      ymin[bs * 128 + col] = mn;
      swsum[wid][col] = s; swsq[wid][col] = s2;
    }
  }
  __syncthreads();
  if (t < 128) {
    float v = swsum[0][t] + swsum[1][t] + swsum[2][t] + swsum[3][t];
    partial[(size_t)t * NBLK_ + blk] = v;
  } else {
    const int c = t - 128;
    float v = swsq[0][c] + swsq[1][c] + swsq[2][c] + swsq[3][c];
    partial[(size_t)t * NBLK_ + blk] = v;
  }
}

// ---------------- final: BN2+ReLU on pooled values ----------------
__global__ __launch_bounds__(256) void final_kernel(
    const float* __restrict__ ymax, const float* __restrict__ ymin,
    const float* __restrict__ ab, float* __restrict__ out) {
  const int gid = blockIdx.x * 256 + threadIdx.x;  // B*S*128
  const int col = gid & 127;
  const float a = ab[col];
  const float v = (a >= 0.f) ? ymax[gid] : ymin[gid];  // monotonicity of BN+ReLU vs sign(a)
  out[gid] = fmaxf(v * a + ab[128 + col], 0.f);
}

extern "C" void kernel_launch(void* const* d_in, const int* in_sizes, int n_in,
                              void* d_out, int out_size, void* d_ws, size_t ws_size,
                              hipStream_t stream) {
  const float* xyz = (const float*)d_in[0];
  const float* points = (const float*)d_in[1];
  const float* w0 = (const float*)d_in[2];
  const float* g0 = (const float*)d_in[4];
  const float* bt0 = (const float*)d_in[5];
  const float* w1 = (const float*)d_in[6];
  const float* g1 = (const float*)d_in[8];
  const float* bt1 = (const float*)d_in[9];
  const float* w2 = (const float*)d_in[10];
  const float* g2 = (const float*)d_in[12];
  const float* bt2 = (const float*)d_in[13];
  float* out = (float*)d_out;
  char* ws = (char*)d_ws;

  float4* sxyzp = (float4*)(ws + 0);       // 2 MB
  __bf16* w0h = (__bf16*)(ws + 2097152);   // 13312 B
  __bf16* w0l = (__bf16*)(ws + 2110464);
  __bf16* w1h = (__bf16*)(ws + 2123776);   // 9216 B
  __bf16* w1l = (__bf16*)(ws + 2132992);
  __bf16* w2h = (__bf16*)(ws + 2142208);   // 18432 B
  __bf16* w2l = (__bf16*)(ws + 2160640);
  int* idx    = (int*)(ws + 2179072);      // 2 MB
  float* y    = (float*)(ws + 4276224);    // 134217728 B (f32, reused L0->L1 in place)
  float* ymax = (float*)(ws + 138493952);  // 8388608
  float* ymin = (float*)(ws + 146882560);  // 8388608
  float* partial = (float*)(ws + 155271168); // 4194304
  float* ab   = (float*)(ws + 159465472);  // 3072
  if (ws_size < 159468544) return;

  prep_kernel<<<592, 256, 0, stream>>>(xyz, w0, w1, w2, sxyzp,
                                       w0h, w0l, w1h, w1l, w2h, w2l);
  fps_kernel<<<16, 256, 0, stream>>>(sxyzp, out);
  ballq_kernel<<<1024, 1024, 0, stream>>>(sxyzp, out, idx);
  layer0_kernel<<<NBLK_, 256, 0, stream>>>(sxyzp, points, out, idx, w0h, w0l, y, partial);
  stat_kernel<<<64, 64, 0, stream>>>(partial, g0, bt0, ab, 64);
  layer1_kernel<<<NBLK_, 256, 0, stream>>>(y, w1h, w1l, ab, partial);
  stat_kernel<<<64, 64, 0, stream>>>(partial, g1, bt1, ab + 256, 64);
  layer2_kernel<<<NBLK_, 256, 0, stream>>>(y, w2h, w2l, ab + 256, ymax, ymin, partial);
  stat_kernel<<<128, 64, 0, stream>>>(partial, g2, bt2, ab + 512, 128);
  final_kernel<<<8192, 256, 0, stream>>>(ymax, ymin, ab + 512, out + 49152);
}

// Round 8
// 1337.259 us; speedup vs baseline: 1.2342x; 1.0099x over previous
//
#include <hip/hip_runtime.h>

// PointNet++ Set Abstraction for MI355X (gfx950).
// prep -> FPS -> ball-query -> L0(mfma) -> stat -> L1 -> stat -> L2(+pool) -> stat -> final.
// FPS replicates reference f32 elementwise arithmetic exactly (non-FMA, same order).
// Ball-query dot uses an FMA chain replicating BLAS sgemm accumulation.
// Activations stored f32; GEMMs use hi/lo split-bf16 MFMA (near-f32).
// R7: FPS cross-wave argmax via double-buffered 4-entry LDS winner exchange
// (uint2 {val_bits, idx}; f32 order == u32 order for non-negative distances).
// Removes LDS atomicMax + dependent slot read from the per-step serial chain.

typedef __bf16 bf16x8 __attribute__((ext_vector_type(8)));
typedef float f32x4 __attribute__((ext_vector_type(4)));
typedef float f32x2 __attribute__((ext_vector_type(2)));

#define B_ 16
#define N_ 8192
#define S_ 1024
#define K_ 32
#define M_ 524288   // B*S*K rows
#define NBLK_ 4096  // M/128

__device__ __forceinline__ f32x4 mfma16(bf16x8 a, bf16x8 b, f32x4 c) {
  return __builtin_amdgcn_mfma_f32_16x16x32_bf16(a, b, c, 0, 0, 0);
}

__device__ __forceinline__ void split8(const float* v, bf16x8& hi, bf16x8& lo) {
#pragma unroll
  for (int e = 0; e < 8; ++e) {
    __bf16 h = (__bf16)v[e];
    hi[e] = h;
    lo[e] = (__bf16)(v[e] - (float)h);
  }
}

// ---------------- prep: packed {x,y,z,|p|^2}, hi/lo split weights ----------------
__global__ __launch_bounds__(256) void prep_kernel(
    const float* __restrict__ xyz, const float* __restrict__ w0,
    const float* __restrict__ w1, const float* __restrict__ w2,
    float4* __restrict__ sxyzp,
    __bf16* __restrict__ w0h, __bf16* __restrict__ w0l,
    __bf16* __restrict__ w1h, __bf16* __restrict__ w1l,
    __bf16* __restrict__ w2h, __bf16* __restrict__ w2l) {
#pragma clang fp contract(off)
  int gid = blockIdx.x * 256 + threadIdx.x;
  if (gid < B_ * N_) {
    float x = xyz[gid * 3 + 0], y = xyz[gid * 3 + 1], z = xyz[gid * 3 + 2];
    float p = (x * x + y * y) + z * z;  // exact reference order
    sxyzp[gid] = make_float4(x, y, z, p);
  } else {
    int j = gid - B_ * N_;
    float v; __bf16* ph; __bf16* pl; int jj;
    if (j < 6656) {            // W0: [64][104], real c<67
      int o = j / 104, c = j % 104;
      v = (c < 67) ? w0[o * 67 + c] : 0.f; ph = w0h; pl = w0l; jj = j;
    } else if (j < 6656 + 4608) {  // W1: [64][72], real c<64
      jj = j - 6656;
      int o = jj / 72, c = jj % 72;
      v = (c < 64) ? w1[o * 64 + c] : 0.f; ph = w1h; pl = w1l;
    } else if (j < 6656 + 4608 + 9216) {  // W2: [128][72]
      jj = j - 6656 - 4608;
      int o = jj / 72, c = jj % 72;
      v = (c < 64) ? w2[o * 64 + c] : 0.f; ph = w2h; pl = w2l;
    } else return;
    __bf16 h = (__bf16)v;
    ph[jj] = h;
    pl[jj] = (__bf16)(v - (float)h);
  }
}

// ---------------- FPS: one block per batch, 256 thr x 32 pts, LDS winner exchange ----------------
__global__ __launch_bounds__(256, 1) void fps_kernel(
    const float4* __restrict__ sxyzp, float* __restrict__ out /* new_xyz (B,S,3) */) {
#pragma clang fp contract(off)
  const int b = blockIdx.x;
  const int t = threadIdx.x;
  __shared__ float4 sp[N_];                    // 128 KB (centroid lookup)
  __shared__ uint2 went[2][4];                 // {val_bits, idx} per wave, double-buffered
  const float4* src = sxyzp + (size_t)b * N_;
  for (int i = t; i < N_; i += 256) sp[i] = src[i];
  __syncthreads();
  // contiguous chunk per lane: thread t owns points [32t, 32t+32), packed in pairs
  f32x2 px[16], py[16], pz[16], dd[16];
  const int i0 = t * 32;
#pragma unroll
  for (int w = 0; w < 32; ++w) {
    float4 v = sp[i0 + w];
    px[w >> 1][w & 1] = v.x; py[w >> 1][w & 1] = v.y; pz[w >> 1][w & 1] = v.z;
  }
#pragma unroll
  for (int j = 0; j < 16; ++j) dd[j] = (f32x2){1e10f, 1e10f};
  const int lane = t & 63, wid = t >> 6;
  float* outB = out + (size_t)b * S_ * 3;
  int far = 0;
  for (int s = 0; s < S_; ++s) {
    float4 c = sp[far];
    if (t == 0) { outB[s * 3 + 0] = c.x; outB[s * 3 + 1] = c.y; outB[s * 3 + 2] = c.z; }
    const f32x2 cx = {c.x, c.x}, cy = {c.y, c.y}, cz = {c.z, c.z};
    f32x2 bv2 = {-1.0f, -1.0f};
#pragma unroll
    for (int j = 0; j < 16; ++j) {
      f32x2 dx = px[j] - cx, dy = py[j] - cy, dz = pz[j] - cz;
      f32x2 d = (dx * dx + dy * dy) + dz * dz;  // exact reference order, no fma
      f32x2 nd = __builtin_elementwise_min(dd[j], d);
      dd[j] = nd;
      bv2 = __builtin_elementwise_max(bv2, nd);
    }
    float bv = fmaxf(bv2[0], bv2[1]);
    // first (lowest) local index equal to bv: descending select keeps lowest w
    int bi = 0;
#pragma unroll
    for (int w = 31; w >= 0; --w) if (dd[w >> 1][w & 1] == bv) bi = i0 + w;
    // wave-wide max on value (f32 shuffles), then first-lane index pick
    float m = bv;
#pragma unroll
    for (int off = 32; off >= 1; off >>= 1) m = fmaxf(m, __shfl_xor(m, off, 64));
    unsigned long long msk = __ballot(bv == m);
    int srcl = __ffsll(msk) - 1;
    int wbi = __shfl(bi, srcl, 64);
    if (lane == 0) went[s & 1][wid] = make_uint2(__float_as_uint(m), (unsigned)wbi);
    __syncthreads();
    // ascending wave scan, strict >: lowest wave (= lowest index) wins ties.
    // f32 order == u32 order for non-negative distances.
    uint2 bestE = went[s & 1][0];
#pragma unroll
    for (int w = 1; w < 4; ++w) {
      uint2 e = went[s & 1][w];
      if (e.x > bestE.x) bestE = e;
    }
    far = (int)bestE.y;
  }
}

// ---------------- ball query: 16 queries per block ----------------
__global__ __launch_bounds__(1024) void ballq_kernel(
    const float4* __restrict__ sxyzp, const float* __restrict__ newxyz,
    int* __restrict__ idxout) {
#pragma clang fp contract(off)
  __shared__ float4 sp[N_];                    // 128 KB
  __shared__ int sel[16][32];
  const int t = threadIdx.x;
  const int g = blockIdx.x;
  const int b = g >> 6;
  const int q0 = (g & 63) << 4;
  const float4* srcp = sxyzp + (size_t)b * N_;
  for (int i = t; i < N_; i += 1024) sp[i] = srcp[i];
  __syncthreads();
  const int wid = t >> 6, lane = t & 63;
  const int q = q0 + wid;
  const float* qp = newxyz + ((size_t)b * S_ + q) * 3;
  const float qx = qp[0], qy = qp[1], qz = qp[2];
  const float qq = (qx * qx + qy * qy) + qz * qz;
  const float rr = (float)(0.4 * 0.4);
  int nsel = 0;
  for (int c0 = 0; c0 < N_ && nsel < 32; c0 += 64) {
    int i = c0 + lane;
    float4 v = sp[i];
    // BLAS-style FMA accumulation chain (matches einsum->matmul lowering):
    float dot = fmaf(qz, v.z, fmaf(qy, v.y, qx * v.x));
    float d = -2.0f * dot;
    d = d + qq;
    d = d + v.w;
    unsigned long long m = __ballot(!(d > rr));
    if ((m >> lane) & 1ull) {
      int rank = nsel + __popcll(m & ((1ull << lane) - 1ull));
      if (rank < 32) sel[wid][rank] = i;
    }
    nsel += __popcll(m);
  }
  __syncthreads();
  int nv = nsel < 32 ? nsel : 32;
  int first = sel[wid][0];
  if (lane < 32)
    idxout[(((size_t)b * S_ + q) << 5) + lane] = (lane < nv) ? sel[wid][lane] : first;
}

// ---------------- layer 0: gather+concat -> split GEMM 67->64 (K padded 96) ----------------
__global__ __launch_bounds__(256) void layer0_kernel(
    const float4* __restrict__ sxyzp, const float* __restrict__ points,
    const float* __restrict__ newxyz, const int* __restrict__ idx,
    const __bf16* __restrict__ wh, const __bf16* __restrict__ wl,
    float* __restrict__ yout, float* __restrict__ partial) {
  __shared__ __align__(16) __bf16 Ah[128 * 104];
  __shared__ __align__(16) __bf16 Al[128 * 104];
  __shared__ __align__(16) __bf16 Bh[64 * 104];
  __shared__ __align__(16) __bf16 Bl[64 * 104];
  __shared__ float swsum[4][64], swsq[4][64];
  const int t = threadIdx.x;
  const int blk = blockIdx.x;
  const size_t row0 = (size_t)blk * 128;
  {
    const int4* sh4 = (const int4*)wh;
    const int4* sl4 = (const int4*)wl;
    int4* dh4 = (int4*)Bh;
    int4* dl4 = (int4*)Bl;
    for (int k = t; k < 832; k += 256) { dh4[k] = sh4[k]; dl4[k] = sl4[k]; }
  }
  {
    const int r = t >> 1, half = t & 1;
    const size_t row = row0 + r;
    const int b = (int)(row >> 15);
    const int s = (int)((row >> 5) & 1023);
    const int i = idx[row];
    const size_t bi = (size_t)b * N_ + i;
    const float* pt = points + bi * 64;
    const float* nx = newxyz + ((size_t)b * S_ + s) * 3;
    const int jb = half ? 6 : 0, je = half ? 13 : 6;
    float gx = 0.f, gy = 0.f, gz = 0.f;
    if (!half) {
      float4 xv = sxyzp[bi];
      gx = xv.x - nx[0]; gy = xv.y - nx[1]; gz = xv.z - nx[2];
    }
#pragma unroll 13
    for (int j = jb; j < je; ++j) {
      float v[8];
#pragma unroll
      for (int e = 0; e < 8; ++e) {
        const int c = j * 8 + e;
        v[e] = (c == 0) ? gx : (c == 1) ? gy : (c == 2) ? gz
               : (c < 67) ? pt[c - 3] : 0.f;
      }
      bf16x8 hi, lo;
      split8(v, hi, lo);
      *(bf16x8*)(Ah + r * 104 + j * 8) = hi;
      *(bf16x8*)(Al + r * 104 + j * 8) = lo;
    }
  }
  __syncthreads();
  const int wid = t >> 6, lane = t & 63;
  const int wrow = wid * 32;
  const int lrow = lane & 15, lk = (lane >> 4) * 8;
  f32x4 acc[2][4];
#pragma unroll
  for (int a_ = 0; a_ < 2; ++a_)
#pragma unroll
    for (int b_ = 0; b_ < 4; ++b_) acc[a_][b_] = (f32x4){0.f, 0.f, 0.f, 0.f};
#pragma unroll
  for (int ks = 0; ks < 3; ++ks) {
    const int ko = ks * 32 + lk;
    bf16x8 ah0 = *(const bf16x8*)(Ah + (wrow + lrow) * 104 + ko);
    bf16x8 al0 = *(const bf16x8*)(Al + (wrow + lrow) * 104 + ko);
    bf16x8 ah1 = *(const bf16x8*)(Ah + (wrow + 16 + lrow) * 104 + ko);
    bf16x8 al1 = *(const bf16x8*)(Al + (wrow + 16 + lrow) * 104 + ko);
#pragma unroll
    for (int cf = 0; cf < 4; ++cf) {
      bf16x8 bh = *(const bf16x8*)(Bh + (cf * 16 + lrow) * 104 + ko);
      bf16x8 bl = *(const bf16x8*)(Bl + (cf * 16 + lrow) * 104 + ko);
      acc[0][cf] = mfma16(ah0, bh, acc[0][cf]);
      acc[0][cf] = mfma16(al0, bh, acc[0][cf]);
      acc[0][cf] = mfma16(ah0, bl, acc[0][cf]);
      acc[1][cf] = mfma16(ah1, bh, acc[1][cf]);
      acc[1][cf] = mfma16(al1, bh, acc[1][cf]);
      acc[1][cf] = mfma16(ah1, bl, acc[1][cf]);
    }
  }
#pragma unroll
  for (int cf = 0; cf < 4; ++cf) {
    float s = 0.f, s2 = 0.f;
    const int col = cf * 16 + lrow;
#pragma unroll
    for (int rf = 0; rf < 2; ++rf) {
      const int rbase = wrow + rf * 16 + (lane >> 4) * 4;
#pragma unroll
      for (int q = 0; q < 4; ++q) {
        float v = acc[rf][cf][q];
        yout[(row0 + rbase + q) * 64 + col] = v;
        s += v; s2 += v * v;
      }
    }
    s += __shfl_xor(s, 16, 64); s += __shfl_xor(s, 32, 64);
    s2 += __shfl_xor(s2, 16, 64); s2 += __shfl_xor(s2, 32, 64);
    if ((lane >> 4) == 0) { swsum[wid][col] = s; swsq[wid][col] = s2; }
  }
  __syncthreads();
  if (t < 128) {
    const int c = t & 63;
    float v = (t < 64) ? (swsum[0][c] + swsum[1][c] + swsum[2][c] + swsum[3][c])
                       : (swsq[0][c] + swsq[1][c] + swsq[2][c] + swsq[3][c]);
    partial[(size_t)t * NBLK_ + blk] = v;
  }
}

// ---------------- stat: mean/var -> (a, shift) ----------------
__global__ __launch_bounds__(64) void stat_kernel(
    const float* __restrict__ partial, const float* __restrict__ g,
    const float* __restrict__ bt, float* __restrict__ ab, int nch) {
  const int o = blockIdx.x, t = threadIdx.x;
  float s = 0.f, s2 = 0.f;
  for (int i = t; i < NBLK_; i += 64) {
    s += partial[(size_t)o * NBLK_ + i];
    s2 += partial[(size_t)(nch + o) * NBLK_ + i];
  }
#pragma unroll
  for (int off = 32; off >= 1; off >>= 1) {
    s += __shfl_xor(s, off, 64);
    s2 += __shfl_xor(s2, off, 64);
  }
  if (t == 0) {
    const float minv = 1.0f / (float)M_;
    float mean = s * minv;
    float var = s2 * minv - mean * mean;
    float a = g[o] * rsqrtf(var + 1e-5f);
    ab[o] = a;
    ab[128 + o] = bt[o] - mean * a;
  }
}

// ---------------- layer 1: BN0+ReLU on load -> split GEMM 64->64 (in-place y) ----------------
__global__ __launch_bounds__(256) void layer1_kernel(
    float* y /* f32 activations, read rows then overwritten (same block) */,
    const __bf16* __restrict__ wh, const __bf16* __restrict__ wl,
    const float* __restrict__ ab, float* __restrict__ partial) {
  __shared__ __align__(16) __bf16 Ah[128 * 72];
  __shared__ __align__(16) __bf16 Al[128 * 72];
  __shared__ __align__(16) __bf16 Bh[64 * 72];
  __shared__ __align__(16) __bf16 Bl[64 * 72];
  __shared__ float sa[64], sb[64];
  __shared__ float swsum[4][64], swsq[4][64];
  const int t = threadIdx.x;
  const int blk = blockIdx.x;
  const size_t row0 = (size_t)blk * 128;
  if (t < 64) { sa[t] = ab[t]; sb[t] = ab[128 + t]; }
  {
    const int4* sh4 = (const int4*)wh;
    const int4* sl4 = (const int4*)wl;
    int4* dh4 = (int4*)Bh;
    int4* dl4 = (int4*)Bl;
    for (int k = t; k < 576; k += 256) { dh4[k] = sh4[k]; dl4[k] = sl4[k]; }
  }
  __syncthreads();
  {
    const int r = t >> 1, half = t & 1;
    const float4* s4 = (const float4*)(y + (row0 + r) * 64 + half * 32);
#pragma unroll
    for (int j = 0; j < 4; ++j) {
      float4 u = s4[j * 2], w = s4[j * 2 + 1];
      float v[8] = {u.x, u.y, u.z, u.w, w.x, w.y, w.z, w.w};
#pragma unroll
      for (int e = 0; e < 8; ++e) {
        const int c = half * 32 + j * 8 + e;
        v[e] = fmaxf(v[e] * sa[c] + sb[c], 0.f);
      }
      bf16x8 hi, lo;
      split8(v, hi, lo);
      *(bf16x8*)(Ah + r * 72 + half * 32 + j * 8) = hi;
      *(bf16x8*)(Al + r * 72 + half * 32 + j * 8) = lo;
    }
  }
  __syncthreads();
  const int wid = t >> 6, lane = t & 63;
  const int wrow = wid * 32;
  const int lrow = lane & 15, lk = (lane >> 4) * 8;
  f32x4 acc[2][4];
#pragma unroll
  for (int a_ = 0; a_ < 2; ++a_)
#pragma unroll
    for (int b_ = 0; b_ < 4; ++b_) acc[a_][b_] = (f32x4){0.f, 0.f, 0.f, 0.f};
#pragma unroll
  for (int ks = 0; ks < 2; ++ks) {
    const int ko = ks * 32 + lk;
    bf16x8 ah0 = *(const bf16x8*)(Ah + (wrow + lrow) * 72 + ko);
    bf16x8 al0 = *(const bf16x8*)(Al + (wrow + lrow) * 72 + ko);
    bf16x8 ah1 = *(const bf16x8*)(Ah + (wrow + 16 + lrow) * 72 + ko);
    bf16x8 al1 = *(const bf16x8*)(Al + (wrow + 16 + lrow) * 72 + ko);
#pragma unroll
    for (int cf = 0; cf < 4; ++cf) {
      bf16x8 bh = *(const bf16x8*)(Bh + (cf * 16 + lrow) * 72 + ko);
      bf16x8 bl = *(const bf16x8*)(Bl + (cf * 16 + lrow) * 72 + ko);
      acc[0][cf] = mfma16(ah0, bh, acc[0][cf]);
      acc[0][cf] = mfma16(al0, bh, acc[0][cf]);
      acc[0][cf] = mfma16(ah0, bl, acc[0][cf]);
      acc[1][cf] = mfma16(ah1, bh, acc[1][cf]);
      acc[1][cf] = mfma16(al1, bh, acc[1][cf]);
      acc[1][cf] = mfma16(ah1, bl, acc[1][cf]);
    }
  }
#pragma unroll
  for (int cf = 0; cf < 4; ++cf) {
    float s = 0.f, s2 = 0.f;
    const int col = cf * 16 + lrow;
#pragma unroll
    for (int rf = 0; rf < 2; ++rf) {
      const int rbase = wrow + rf * 16 + (lane >> 4) * 4;
#pragma unroll
      for (int q = 0; q < 4; ++q) {
        float v = acc[rf][cf][q];
        y[(row0 + rbase + q) * 64 + col] = v;
        s += v; s2 += v * v;
      }
    }
    s += __shfl_xor(s, 16, 64); s += __shfl_xor(s, 32, 64);
    s2 += __shfl_xor(s2, 16, 64); s2 += __shfl_xor(s2, 32, 64);
    if ((lane >> 4) == 0) { swsum[wid][col] = s; swsq[wid][col] = s2; }
  }
  __syncthreads();
  if (t < 128) {
    const int c = t & 63;
    float v = (t < 64) ? (swsum[0][c] + swsum[1][c] + swsum[2][c] + swsum[3][c])
                       : (swsq[0][c] + swsq[1][c] + swsq[2][c] + swsq[3][c]);
    partial[(size_t)t * NBLK_ + blk] = v;
  }
}

// ---------------- layer 2: BN1+ReLU -> split GEMM 64->128 + fused max/min pool ----------------
__global__ __launch_bounds__(256) void layer2_kernel(
    const float* __restrict__ yin, const __bf16* __restrict__ wh,
    const __bf16* __restrict__ wl, const float* __restrict__ ab,
    float* __restrict__ ymax, float* __restrict__ ymin,
    float* __restrict__ partial) {
  __shared__ __align__(16) __bf16 Ah[128 * 72];
  __shared__ __align__(16) __bf16 Al[128 * 72];
  __shared__ __align__(16) __bf16 Bh[128 * 72];
  __shared__ __align__(16) __bf16 Bl[128 * 72];
  __shared__ float sa[64], sb[64];
  __shared__ float swsum[4][128], swsq[4][128];
  const int t = threadIdx.x;
  const int blk = blockIdx.x;
  const size_t row0 = (size_t)blk * 128;
  if (t < 64) { sa[t] = ab[t]; sb[t] = ab[128 + t]; }
  {
    const int4* sh4 = (const int4*)wh;
    const int4* sl4 = (const int4*)wl;
    int4* dh4 = (int4*)Bh;
    int4* dl4 = (int4*)Bl;
    for (int k = t; k < 1152; k += 256) { dh4[k] = sh4[k]; dl4[k] = sl4[k]; }
  }
  __syncthreads();
  {
    const int r = t >> 1, half = t & 1;
    const float4* s4 = (const float4*)(yin + (row0 + r) * 64 + half * 32);
#pragma unroll
    for (int j = 0; j < 4; ++j) {
      float4 u = s4[j * 2], w = s4[j * 2 + 1];
      float v[8] = {u.x, u.y, u.z, u.w, w.x, w.y, w.z, w.w};
#pragma unroll
      for (int e = 0; e < 8; ++e) {
        const int c = half * 32 + j * 8 + e;
        v[e] = fmaxf(v[e] * sa[c] + sb[c], 0.f);
      }
      bf16x8 hi, lo;
      split8(v, hi, lo);
      *(bf16x8*)(Ah + r * 72 + half * 32 + j * 8) = hi;
      *(bf16x8*)(Al + r * 72 + half * 32 + j * 8) = lo;
    }
  }
  __syncthreads();
  const int wid = t >> 6, lane = t & 63;
  const int wrow = wid * 32;
  const int lrow = lane & 15, lk = (lane >> 4) * 8;
  f32x4 acc[2][8];
#pragma unroll
  for (int a_ = 0; a_ < 2; ++a_)
#pragma unroll
    for (int b_ = 0; b_ < 8; ++b_) acc[a_][b_] = (f32x4){0.f, 0.f, 0.f, 0.f};
#pragma unroll
  for (int ks = 0; ks < 2; ++ks) {
    const int ko = ks * 32 + lk;
    bf16x8 ah0 = *(const bf16x8*)(Ah + (wrow + lrow) * 72 + ko);
    bf16x8 al0 = *(const bf16x8*)(Al + (wrow + lrow) * 72 + ko);
    bf16x8 ah1 = *(const bf16x8*)(Ah + (wrow + 16 + lrow) * 72 + ko);
    bf16x8 al1 = *(const bf16x8*)(Al + (wrow + 16 + lrow) * 72 + ko);
#pragma unroll
    for (int cf = 0; cf < 8; ++cf) {
      bf16x8 bh = *(const bf16x8*)(Bh + (cf * 16 + lrow) * 72 + ko);
      bf16x8 bl = *(const bf16x8*)(Bl + (cf * 16 + lrow) * 72 + ko);
      acc[0][cf] = mfma16(ah0, bh, acc[0][cf]);
      acc[0][cf] = mfma16(al0, bh, acc[0][cf]);
      acc[0][cf] = mfma16(ah0, bl, acc[0][cf]);
      acc[1][cf] = mfma16(ah1, bh, acc[1][cf]);
      acc[1][cf] = mfma16(al1, bh, acc[1][cf]);
      acc[1][cf] = mfma16(ah1, bl, acc[1][cf]);
    }
  }
  // each wave's 32 rows form exactly one (b,s) group
  const size_t bs = (size_t)blk * 4 + wid;
#pragma unroll
  for (int cf = 0; cf < 8; ++cf) {
    float s = 0.f, s2 = 0.f, mx = -3.4e38f, mn = 3.4e38f;
    const int col = cf * 16 + lrow;
#pragma unroll
    for (int rf = 0; rf < 2; ++rf)
#pragma unroll
      for (int q = 0; q < 4; ++q) {
        float v = acc[rf][cf][q];
        s += v; s2 += v * v;
        mx = fmaxf(mx, v); mn = fminf(mn, v);
      }
    s += __shfl_xor(s, 16, 64); s += __shfl_xor(s, 32, 64);
    s2 += __shfl_xor(s2, 16, 64); s2 += __shfl_xor(s2, 32, 64);
    mx = fmaxf(mx, __shfl_xor(mx, 16, 64)); mx = fmaxf(mx, __shfl_xor(mx, 32, 64));
    mn = fminf(mn, __shfl_xor(mn, 16, 64)); mn = fminf(mn, __shfl_xor(mn, 32, 64));
    if ((lane >> 4) == 0) {
      ymax[bs * 128 + col] = mx;
      ymin[bs * 128 + col] = mn;
      swsum[wid][col] = s; swsq[wid][col] = s2;
    }
  }
  __syncthreads();
  if (t < 128) {
    float v = swsum[0][t] + swsum[1][t] + swsum[2][t] + swsum[3][t];
    partial[(size_t)t * NBLK_ + blk] = v;
  } else {
    const int c = t - 128;
    float v = swsq[0][c] + swsq[1][c] + swsq[2][c] + swsq[3][c];
    partial[(size_t)t * NBLK_ + blk] = v;
  }
}

// ---------------- final: BN2+ReLU on pooled values ----------------
__global__ __launch_bounds__(256) void final_kernel(
    const float* __restrict__ ymax, const float* __restrict__ ymin,
    const float* __restrict__ ab, float* __restrict__ out) {
  const int gid = blockIdx.x * 256 + threadIdx.x;  // B*S*128
  const int col = gid & 127;
  const float a = ab[col];
  const float v = (a >= 0.f) ? ymax[gid] : ymin[gid];  // monotonicity of BN+ReLU vs sign(a)
  out[gid] = fmaxf(v * a + ab[128 + col], 0.f);
}

extern "C" void kernel_launch(void* const* d_in, const int* in_sizes, int n_in,
                              void* d_out, int out_size, void* d_ws, size_t ws_size,
                              hipStream_t stream) {
  const float* xyz = (const float*)d_in[0];
  const float* points = (const float*)d_in[1];
  const float* w0 = (const float*)d_in[2];
  const float* g0 = (const float*)d_in[4];
  const float* bt0 = (const float*)d_in[5];
  const float* w1 = (const float*)d_in[6];
  const float* g1 = (const float*)d_in[8];
  const float* bt1 = (const float*)d_in[9];
  const float* w2 = (const float*)d_in[10];
  const float* g2 = (const float*)d_in[12];
  const float* bt2 = (const float*)d_in[13];
  float* out = (float*)d_out;
  char* ws = (char*)d_ws;

  float4* sxyzp = (float4*)(ws + 0);       // 2 MB
  __bf16* w0h = (__bf16*)(ws + 2097152);   // 13312 B
  __bf16* w0l = (__bf16*)(ws + 2110464);
  __bf16* w1h = (__bf16*)(ws + 2123776);   // 9216 B
  __bf16* w1l = (__bf16*)(ws + 2132992);
  __bf16* w2h = (__bf16*)(ws + 2142208);   // 18432 B
  __bf16* w2l = (__bf16*)(ws + 2160640);
  int* idx    = (int*)(ws + 2179072);      // 2 MB
  float* y    = (float*)(ws + 4276224);    // 134217728 B (f32, reused L0->L1 in place)
  float* ymax = (float*)(ws + 138493952);  // 8388608
  float* ymin = (float*)(ws + 146882560);  // 8388608
  float* partial = (float*)(ws + 155271168); // 4194304
  float* ab   = (float*)(ws + 159465472);  // 3072
  if (ws_size < 159468544) return;

  prep_kernel<<<592, 256, 0, stream>>>(xyz, w0, w1, w2, sxyzp,
                                       w0h, w0l, w1h, w1l, w2h, w2l);
  fps_kernel<<<16, 256, 0, stream>>>(sxyzp, out);
  ballq_kernel<<<1024, 1024, 0, stream>>>(sxyzp, out, idx);
  layer0_kernel<<<NBLK_, 256, 0, stream>>>(sxyzp, points, out, idx, w0h, w0l, y, partial);
  stat_kernel<<<64, 64, 0, stream>>>(partial, g0, bt0, ab, 64);
  layer1_kernel<<<NBLK_, 256, 0, stream>>>(y, w1h, w1l, ab, partial);
  stat_kernel<<<64, 64, 0, stream>>>(partial, g1, bt1, ab + 256, 64);
  layer2_kernel<<<NBLK_, 256, 0, stream>>>(y, w2h, w2l, ab + 256, ymax, ymin, partial);
  stat_kernel<<<128, 64, 0, stream>>>(partial, g2, bt2, ab + 512, 128);
  final_kernel<<<8192, 256, 0, stream>>>(ymax, ymin, ab + 512, out + 49152);
}

// Round 9
// 1260.881 us; speedup vs baseline: 1.3089x; 1.0606x over previous
//
#include <hip/hip_runtime.h>

// PointNet++ Set Abstraction for MI355X (gfx950).
// prep -> FPS -> ball-query -> L0(mfma) -> stat -> L1 -> stat -> L2(+pool) -> stat -> final.
// FPS replicates reference f32 elementwise arithmetic exactly (non-FMA, same order).
// Ball-query dot uses an FMA chain replicating BLAS sgemm accumulation.
// Activations stored f32; GEMMs use hi/lo split-bf16 MFMA (near-f32).
// R8: FPS wave-max via DPP (row_shr 1/2/4/8 + row_bcast 15/31 + readlane63,
// ~30cy vs ~300cy of ds_bpermute shuffles); winner index via SGPR readlane;
// 512 threads x 16 pts (2 waves/SIMD hides VALU dep latency).

typedef __bf16 bf16x8 __attribute__((ext_vector_type(8)));
typedef float f32x4 __attribute__((ext_vector_type(4)));
typedef float f32x2 __attribute__((ext_vector_type(2)));

#define B_ 16
#define N_ 8192
#define S_ 1024
#define K_ 32
#define M_ 524288   // B*S*K rows
#define NBLK_ 4096  // M/128

__device__ __forceinline__ f32x4 mfma16(bf16x8 a, bf16x8 b, f32x4 c) {
  return __builtin_amdgcn_mfma_f32_16x16x32_bf16(a, b, c, 0, 0, 0);
}

__device__ __forceinline__ void split8(const float* v, bf16x8& hi, bf16x8& lo) {
#pragma unroll
  for (int e = 0; e < 8; ++e) {
    __bf16 h = (__bf16)v[e];
    hi[e] = h;
    lo[e] = (__bf16)(v[e] - (float)h);
  }
}

// Wave64 max of non-negative f32 via DPP; returns uniform max (all lanes).
// bound_ctrl=true fills invalid lanes with 0 (max-neutral for x >= 0).
__device__ __forceinline__ float wave_max_nonneg(float x) {
  int v = __float_as_int(x);
#define DPP_MAX(ctrl)                                                          \
  v = __float_as_int(fmaxf(__int_as_float(v),                                  \
        __int_as_float(__builtin_amdgcn_update_dpp(0, v, (ctrl), 0xf, 0xf, true))))
  DPP_MAX(0x111);  // row_shr:1
  DPP_MAX(0x112);  // row_shr:2
  DPP_MAX(0x114);  // row_shr:4
  DPP_MAX(0x118);  // row_shr:8
  DPP_MAX(0x142);  // row_bcast:15
  DPP_MAX(0x143);  // row_bcast:31
#undef DPP_MAX
  return __int_as_float(__builtin_amdgcn_readlane(v, 63));
}

// ---------------- prep: packed {x,y,z,|p|^2}, hi/lo split weights ----------------
__global__ __launch_bounds__(256) void prep_kernel(
    const float* __restrict__ xyz, const float* __restrict__ w0,
    const float* __restrict__ w1, const float* __restrict__ w2,
    float4* __restrict__ sxyzp,
    __bf16* __restrict__ w0h, __bf16* __restrict__ w0l,
    __bf16* __restrict__ w1h, __bf16* __restrict__ w1l,
    __bf16* __restrict__ w2h, __bf16* __restrict__ w2l) {
#pragma clang fp contract(off)
  int gid = blockIdx.x * 256 + threadIdx.x;
  if (gid < B_ * N_) {
    float x = xyz[gid * 3 + 0], y = xyz[gid * 3 + 1], z = xyz[gid * 3 + 2];
    float p = (x * x + y * y) + z * z;  // exact reference order
    sxyzp[gid] = make_float4(x, y, z, p);
  } else {
    int j = gid - B_ * N_;
    float v; __bf16* ph; __bf16* pl; int jj;
    if (j < 6656) {            // W0: [64][104], real c<67
      int o = j / 104, c = j % 104;
      v = (c < 67) ? w0[o * 67 + c] : 0.f; ph = w0h; pl = w0l; jj = j;
    } else if (j < 6656 + 4608) {  // W1: [64][72], real c<64
      jj = j - 6656;
      int o = jj / 72, c = jj % 72;
      v = (c < 64) ? w1[o * 64 + c] : 0.f; ph = w1h; pl = w1l;
    } else if (j < 6656 + 4608 + 9216) {  // W2: [128][72]
      jj = j - 6656 - 4608;
      int o = jj / 72, c = jj % 72;
      v = (c < 64) ? w2[o * 64 + c] : 0.f; ph = w2h; pl = w2l;
    } else return;
    __bf16 h = (__bf16)v;
    ph[jj] = h;
    pl[jj] = (__bf16)(v - (float)h);
  }
}

// ---------------- FPS: one block per batch, 512 thr x 16 pts, DPP argmax ----------------
__global__ __launch_bounds__(512, 1) void fps_kernel(
    const float4* __restrict__ sxyzp, float* __restrict__ out /* new_xyz (B,S,3) */) {
#pragma clang fp contract(off)
  const int b = blockIdx.x;
  const int t = threadIdx.x;
  __shared__ float4 sp[N_];                    // 128 KB (centroid lookup)
  __shared__ uint2 went[2][8];                 // {val_bits, idx} per wave, double-buffered
  const float4* src = sxyzp + (size_t)b * N_;
  for (int i = t; i < N_; i += 512) sp[i] = src[i];
  __syncthreads();
  // contiguous chunk per lane: thread t owns points [16t, 16t+16), packed in pairs
  f32x2 px[8], py[8], pz[8], dd[8];
  const int i0 = t * 16;
#pragma unroll
  for (int w = 0; w < 16; ++w) {
    float4 v = sp[i0 + w];
    px[w >> 1][w & 1] = v.x; py[w >> 1][w & 1] = v.y; pz[w >> 1][w & 1] = v.z;
  }
#pragma unroll
  for (int j = 0; j < 8; ++j) dd[j] = (f32x2){1e10f, 1e10f};
  const int lane = t & 63, wid = t >> 6;
  float* outB = out + (size_t)b * S_ * 3;
  int far = 0;
  for (int s = 0; s < S_; ++s) {
    float4 c = sp[far];
    if (t == 0) { outB[s * 3 + 0] = c.x; outB[s * 3 + 1] = c.y; outB[s * 3 + 2] = c.z; }
    const f32x2 cx = {c.x, c.x}, cy = {c.y, c.y}, cz = {c.z, c.z};
    f32x2 bv2 = {-1.0f, -1.0f};
#pragma unroll
    for (int j = 0; j < 8; ++j) {
      f32x2 dx = px[j] - cx, dy = py[j] - cy, dz = pz[j] - cz;
      f32x2 d = (dx * dx + dy * dy) + dz * dz;  // exact reference order, no fma
      f32x2 nd = __builtin_elementwise_min(dd[j], d);
      dd[j] = nd;
      bv2 = __builtin_elementwise_max(bv2, nd);
    }
    float bv = fmaxf(bv2[0], bv2[1]);
    // first (lowest) local index equal to bv: descending select keeps lowest w
    int bi = 0;
#pragma unroll
    for (int w = 15; w >= 0; --w) if (dd[w >> 1][w & 1] == bv) bi = i0 + w;
    // wave-wide max via DPP (uniform), then lowest-lane index via SGPR readlane
    float m = wave_max_nonneg(bv);
    unsigned long long msk = __ballot(bv == m);
    int srcl = __ffsll((long long)msk) - 1;          // uniform (SGPR)
    int wbi = __builtin_amdgcn_readlane(bi, srcl);   // uniform
    if (lane == 0) went[s & 1][wid] = make_uint2(__float_as_uint(m), (unsigned)wbi);
    __syncthreads();
    // ascending wave scan, strict >: lowest wave (= lowest index) wins ties.
    // f32 order == u32 order for non-negative distances.
    uint2 bestE = went[s & 1][0];
#pragma unroll
    for (int w = 1; w < 8; ++w) {
      uint2 e = went[s & 1][w];
      if (e.x > bestE.x) bestE = e;
    }
    far = (int)bestE.y;
  }
}

// ---------------- ball query: 16 queries per block ----------------
__global__ __launch_bounds__(1024) void ballq_kernel(
    const float4* __restrict__ sxyzp, const float* __restrict__ newxyz,
    int* __restrict__ idxout) {
#pragma clang fp contract(off)
  __shared__ float4 sp[N_];                    // 128 KB
  __shared__ int sel[16][32];
  const int t = threadIdx.x;
  const int g = blockIdx.x;
  const int b = g >> 6;
  const int q0 = (g & 63) << 4;
  const float4* srcp = sxyzp + (size_t)b * N_;
  for (int i = t; i < N_; i += 1024) sp[i] = srcp[i];
  __syncthreads();
  const int wid = t >> 6, lane = t & 63;
  const int q = q0 + wid;
  const float* qp = newxyz + ((size_t)b * S_ + q) * 3;
  const float qx = qp[0], qy = qp[1], qz = qp[2];
  const float qq = (qx * qx + qy * qy) + qz * qz;
  const float rr = (float)(0.4 * 0.4);
  int nsel = 0;
  for (int c0 = 0; c0 < N_ && nsel < 32; c0 += 64) {
    int i = c0 + lane;
    float4 v = sp[i];
    // BLAS-style FMA accumulation chain (matches einsum->matmul lowering):
    float dot = fmaf(qz, v.z, fmaf(qy, v.y, qx * v.x));
    float d = -2.0f * dot;
    d = d + qq;
    d = d + v.w;
    unsigned long long m = __ballot(!(d > rr));
    if ((m >> lane) & 1ull) {
      int rank = nsel + __popcll(m & ((1ull << lane) - 1ull));
      if (rank < 32) sel[wid][rank] = i;
    }
    nsel += __popcll(m);
  }
  __syncthreads();
  int nv = nsel < 32 ? nsel : 32;
  int first = sel[wid][0];
  if (lane < 32)
    idxout[(((size_t)b * S_ + q) << 5) + lane] = (lane < nv) ? sel[wid][lane] : first;
}

// ---------------- layer 0: gather+concat -> split GEMM 67->64 (K padded 96) ----------------
__global__ __launch_bounds__(256) void layer0_kernel(
    const float4* __restrict__ sxyzp, const float* __restrict__ points,
    const float* __restrict__ newxyz, const int* __restrict__ idx,
    const __bf16* __restrict__ wh, const __bf16* __restrict__ wl,
    float* __restrict__ yout, float* __restrict__ partial) {
  __shared__ __align__(16) __bf16 Ah[128 * 104];
  __shared__ __align__(16) __bf16 Al[128 * 104];
  __shared__ __align__(16) __bf16 Bh[64 * 104];
  __shared__ __align__(16) __bf16 Bl[64 * 104];
  __shared__ float swsum[4][64], swsq[4][64];
  const int t = threadIdx.x;
  const int blk = blockIdx.x;
  const size_t row0 = (size_t)blk * 128;
  {
    const int4* sh4 = (const int4*)wh;
    const int4* sl4 = (const int4*)wl;
    int4* dh4 = (int4*)Bh;
    int4* dl4 = (int4*)Bl;
    for (int k = t; k < 832; k += 256) { dh4[k] = sh4[k]; dl4[k] = sl4[k]; }
  }
  {
    const int r = t >> 1, half = t & 1;
    const size_t row = row0 + r;
    const int b = (int)(row >> 15);
    const int s = (int)((row >> 5) & 1023);
    const int i = idx[row];
    const size_t bi = (size_t)b * N_ + i;
    const float* pt = points + bi * 64;
    const float* nx = newxyz + ((size_t)b * S_ + s) * 3;
    const int jb = half ? 6 : 0, je = half ? 13 : 6;
    float gx = 0.f, gy = 0.f, gz = 0.f;
    if (!half) {
      float4 xv = sxyzp[bi];
      gx = xv.x - nx[0]; gy = xv.y - nx[1]; gz = xv.z - nx[2];
    }
#pragma unroll 13
    for (int j = jb; j < je; ++j) {
      float v[8];
#pragma unroll
      for (int e = 0; e < 8; ++e) {
        const int c = j * 8 + e;
        v[e] = (c == 0) ? gx : (c == 1) ? gy : (c == 2) ? gz
               : (c < 67) ? pt[c - 3] : 0.f;
      }
      bf16x8 hi, lo;
      split8(v, hi, lo);
      *(bf16x8*)(Ah + r * 104 + j * 8) = hi;
      *(bf16x8*)(Al + r * 104 + j * 8) = lo;
    }
  }
  __syncthreads();
  const int wid = t >> 6, lane = t & 63;
  const int wrow = wid * 32;
  const int lrow = lane & 15, lk = (lane >> 4) * 8;
  f32x4 acc[2][4];
#pragma unroll
  for (int a_ = 0; a_ < 2; ++a_)
#pragma unroll
    for (int b_ = 0; b_ < 4; ++b_) acc[a_][b_] = (f32x4){0.f, 0.f, 0.f, 0.f};
#pragma unroll
  for (int ks = 0; ks < 3; ++ks) {
    const int ko = ks * 32 + lk;
    bf16x8 ah0 = *(const bf16x8*)(Ah + (wrow + lrow) * 104 + ko);
    bf16x8 al0 = *(const bf16x8*)(Al + (wrow + lrow) * 104 + ko);
    bf16x8 ah1 = *(const bf16x8*)(Ah + (wrow + 16 + lrow) * 104 + ko);
    bf16x8 al1 = *(const bf16x8*)(Al + (wrow + 16 + lrow) * 104 + ko);
#pragma unroll
    for (int cf = 0; cf < 4; ++cf) {
      bf16x8 bh = *(const bf16x8*)(Bh + (cf * 16 + lrow) * 104 + ko);
      bf16x8 bl = *(const bf16x8*)(Bl + (cf * 16 + lrow) * 104 + ko);
      acc[0][cf] = mfma16(ah0, bh, acc[0][cf]);
      acc[0][cf] = mfma16(al0, bh, acc[0][cf]);
      acc[0][cf] = mfma16(ah0, bl, acc[0][cf]);
      acc[1][cf] = mfma16(ah1, bh, acc[1][cf]);
      acc[1][cf] = mfma16(al1, bh, acc[1][cf]);
      acc[1][cf] = mfma16(ah1, bl, acc[1][cf]);
    }
  }
#pragma unroll
  for (int cf = 0; cf < 4; ++cf) {
    float s = 0.f, s2 = 0.f;
    const int col = cf * 16 + lrow;
#pragma unroll
    for (int rf = 0; rf < 2; ++rf) {
      const int rbase = wrow + rf * 16 + (lane >> 4) * 4;
#pragma unroll
      for (int q = 0; q < 4; ++q) {
        float v = acc[rf][cf][q];
        yout[(row0 + rbase + q) * 64 + col] = v;
        s += v; s2 += v * v;
      }
    }
    s += __shfl_xor(s, 16, 64); s += __shfl_xor(s, 32, 64);
    s2 += __shfl_xor(s2, 16, 64); s2 += __shfl_xor(s2, 32, 64);
    if ((lane >> 4) == 0) { swsum[wid][col] = s; swsq[wid][col] = s2; }
  }
  __syncthreads();
  if (t < 128) {
    const int c = t & 63;
    float v = (t < 64) ? (swsum[0][c] + swsum[1][c] + swsum[2][c] + swsum[3][c])
                       : (swsq[0][c] + swsq[1][c] + swsq[2][c] + swsq[3][c]);
    partial[(size_t)t * NBLK_ + blk] = v;
  }
}

// ---------------- stat: mean/var -> (a, shift) ----------------
__global__ __launch_bounds__(64) void stat_kernel(
    const float* __restrict__ partial, const float* __restrict__ g,
    const float* __restrict__ bt, float* __restrict__ ab, int nch) {
  const int o = blockIdx.x, t = threadIdx.x;
  float s = 0.f, s2 = 0.f;
  for (int i = t; i < NBLK_; i += 64) {
    s += partial[(size_t)o * NBLK_ + i];
    s2 += partial[(size_t)(nch + o) * NBLK_ + i];
  }
#pragma unroll
  for (int off = 32; off >= 1; off >>= 1) {
    s += __shfl_xor(s, off, 64);
    s2 += __shfl_xor(s2, off, 64);
  }
  if (t == 0) {
    const float minv = 1.0f / (float)M_;
    float mean = s * minv;
    float var = s2 * minv - mean * mean;
    float a = g[o] * rsqrtf(var + 1e-5f);
    ab[o] = a;
    ab[128 + o] = bt[o] - mean * a;
  }
}

// ---------------- layer 1: BN0+ReLU on load -> split GEMM 64->64 (in-place y) ----------------
__global__ __launch_bounds__(256) void layer1_kernel(
    float* y /* f32 activations, read rows then overwritten (same block) */,
    const __bf16* __restrict__ wh, const __bf16* __restrict__ wl,
    const float* __restrict__ ab, float* __restrict__ partial) {
  __shared__ __align__(16) __bf16 Ah[128 * 72];
  __shared__ __align__(16) __bf16 Al[128 * 72];
  __shared__ __align__(16) __bf16 Bh[64 * 72];
  __shared__ __align__(16) __bf16 Bl[64 * 72];
  __shared__ float sa[64], sb[64];
  __shared__ float swsum[4][64], swsq[4][64];
  const int t = threadIdx.x;
  const int blk = blockIdx.x;
  const size_t row0 = (size_t)blk * 128;
  if (t < 64) { sa[t] = ab[t]; sb[t] = ab[128 + t]; }
  {
    const int4* sh4 = (const int4*)wh;
    const int4* sl4 = (const int4*)wl;
    int4* dh4 = (int4*)Bh;
    int4* dl4 = (int4*)Bl;
    for (int k = t; k < 576; k += 256) { dh4[k] = sh4[k]; dl4[k] = sl4[k]; }
  }
  __syncthreads();
  {
    const int r = t >> 1, half = t & 1;
    const float4* s4 = (const float4*)(y + (row0 + r) * 64 + half * 32);
#pragma unroll
    for (int j = 0; j < 4; ++j) {
      float4 u = s4[j * 2], w = s4[j * 2 + 1];
      float v[8] = {u.x, u.y, u.z, u.w, w.x, w.y, w.z, w.w};
#pragma unroll
      for (int e = 0; e < 8; ++e) {
        const int c = half * 32 + j * 8 + e;
        v[e] = fmaxf(v[e] * sa[c] + sb[c], 0.f);
      }
      bf16x8 hi, lo;
      split8(v, hi, lo);
      *(bf16x8*)(Ah + r * 72 + half * 32 + j * 8) = hi;
      *(bf16x8*)(Al + r * 72 + half * 32 + j * 8) = lo;
    }
  }
  __syncthreads();
  const int wid = t >> 6, lane = t & 63;
  const int wrow = wid * 32;
  const int lrow = lane & 15, lk = (lane >> 4) * 8;
  f32x4 acc[2][4];
#pragma unroll
  for (int a_ = 0; a_ < 2; ++a_)
#pragma unroll
    for (int b_ = 0; b_ < 4; ++b_) acc[a_][b_] = (f32x4){0.f, 0.f, 0.f, 0.f};
#pragma unroll
  for (int ks = 0; ks < 2; ++ks) {
    const int ko = ks * 32 + lk;
    bf16x8 ah0 = *(const bf16x8*)(Ah + (wrow + lrow) * 72 + ko);
    bf16x8 al0 = *(const bf16x8*)(Al + (wrow + lrow) * 72 + ko);
    bf16x8 ah1 = *(const bf16x8*)(Ah + (wrow + 16 + lrow) * 72 + ko);
    bf16x8 al1 = *(const bf16x8*)(Al + (wrow + 16 + lrow) * 72 + ko);
#pragma unroll
    for (int cf = 0; cf < 4; ++cf) {
      bf16x8 bh = *(const bf16x8*)(Bh + (cf * 16 + lrow) * 72 + ko);
      bf16x8 bl = *(const bf16x8*)(Bl + (cf * 16 + lrow) * 72 + ko);
      acc[0][cf] = mfma16(ah0, bh, acc[0][cf]);
      acc[0][cf] = mfma16(al0, bh, acc[0][cf]);
      acc[0][cf] = mfma16(ah0, bl, acc[0][cf]);
      acc[1][cf] = mfma16(ah1, bh, acc[1][cf]);
      acc[1][cf] = mfma16(al1, bh, acc[1][cf]);
      acc[1][cf] = mfma16(ah1, bl, acc[1][cf]);
    }
  }
#pragma unroll
  for (int cf = 0; cf < 4; ++cf) {
    float s = 0.f, s2 = 0.f;
    const int col = cf * 16 + lrow;
#pragma unroll
    for (int rf = 0; rf < 2; ++rf) {
      const int rbase = wrow + rf * 16 + (lane >> 4) * 4;
#pragma unroll
      for (int q = 0; q < 4; ++q) {
        float v = acc[rf][cf][q];
        y[(row0 + rbase + q) * 64 + col] = v;
        s += v; s2 += v * v;
      }
    }
    s += __shfl_xor(s, 16, 64); s += __shfl_xor(s, 32, 64);
    s2 += __shfl_xor(s2, 16, 64); s2 += __shfl_xor(s2, 32, 64);
    if ((lane >> 4) == 0) { swsum[wid][col] = s; swsq[wid][col] = s2; }
  }
  __syncthreads();
  if (t < 128) {
    const int c = t & 63;
    float v = (t < 64) ? (swsum[0][c] + swsum[1][c] + swsum[2][c] + swsum[3][c])
                       : (swsq[0][c] + swsq[1][c] + swsq[2][c] + swsq[3][c]);
    partial[(size_t)t * NBLK_ + blk] = v;
  }
}

// ---------------- layer 2: BN1+ReLU -> split GEMM 64->128 + fused max/min pool ----------------
__global__ __launch_bounds__(256) void layer2_kernel(
    const float* __restrict__ yin, const __bf16* __restrict__ wh,
    const __bf16* __restrict__ wl, const float* __restrict__ ab,
    float* __restrict__ ymax, float* __restrict__ ymin,
    float* __restrict__ partial) {
  __shared__ __align__(16) __bf16 Ah[128 * 72];
  __shared__ __align__(16) __bf16 Al[128 * 72];
  __shared__ __align__(16) __bf16 Bh[128 * 72];
  __shared__ __align__(16) __bf16 Bl[128 * 72];
  __shared__ float sa[64], sb[64];
  __shared__ float swsum[4][128], swsq[4][128];
  const int t = threadIdx.x;
  const int blk = blockIdx.x;
  const size_t row0 = (size_t)blk * 128;
  if (t < 64) { sa[t] = ab[t]; sb[t] = ab[128 + t]; }
  {
    const int4* sh4 = (const int4*)wh;
    const int4* sl4 = (const int4*)wl;
    int4* dh4 = (int4*)Bh;
    int4* dl4 = (int4*)Bl;
    for (int k = t; k < 1152; k += 256) { dh4[k] = sh4[k]; dl4[k] = sl4[k]; }
  }
  __syncthreads();
  {
    const int r = t >> 1, half = t & 1;
    const float4* s4 = (const float4*)(yin + (row0 + r) * 64 + half * 32);
#pragma unroll
    for (int j = 0; j < 4; ++j) {
      float4 u = s4[j * 2], w = s4[j * 2 + 1];
      float v[8] = {u.x, u.y, u.z, u.w, w.x, w.y, w.z, w.w};
#pragma unroll
      for (int e = 0; e < 8; ++e) {
        const int c = half * 32 + j * 8 + e;
        v[e] = fmaxf(v[e] * sa[c] + sb[c], 0.f);
      }
      bf16x8 hi, lo;
      split8(v, hi, lo);
      *(bf16x8*)(Ah + r * 72 + half * 32 + j * 8) = hi;
      *(bf16x8*)(Al + r * 72 + half * 32 + j * 8) = lo;
    }
  }
  __syncthreads();
  const int wid = t >> 6, lane = t & 63;
  const int wrow = wid * 32;
  const int lrow = lane & 15, lk = (lane >> 4) * 8;
  f32x4 acc[2][8];
#pragma unroll
  for (int a_ = 0; a_ < 2; ++a_)
#pragma unroll
    for (int b_ = 0; b_ < 8; ++b_) acc[a_][b_] = (f32x4){0.f, 0.f, 0.f, 0.f};
#pragma unroll
  for (int ks = 0; ks < 2; ++ks) {
    const int ko = ks * 32 + lk;
    bf16x8 ah0 = *(const bf16x8*)(Ah + (wrow + lrow) * 72 + ko);
    bf16x8 al0 = *(const bf16x8*)(Al + (wrow + lrow) * 72 + ko);
    bf16x8 ah1 = *(const bf16x8*)(Ah + (wrow + 16 + lrow) * 72 + ko);
    bf16x8 al1 = *(const bf16x8*)(Al + (wrow + 16 + lrow) * 72 + ko);
#pragma unroll
    for (int cf = 0; cf < 8; ++cf) {
      bf16x8 bh = *(const bf16x8*)(Bh + (cf * 16 + lrow) * 72 + ko);
      bf16x8 bl = *(const bf16x8*)(Bl + (cf * 16 + lrow) * 72 + ko);
      acc[0][cf] = mfma16(ah0, bh, acc[0][cf]);
      acc[0][cf] = mfma16(al0, bh, acc[0][cf]);
      acc[0][cf] = mfma16(ah0, bl, acc[0][cf]);
      acc[1][cf] = mfma16(ah1, bh, acc[1][cf]);
      acc[1][cf] = mfma16(al1, bh, acc[1][cf]);
      acc[1][cf] = mfma16(ah1, bl, acc[1][cf]);
    }
  }
  // each wave's 32 rows form exactly one (b,s) group
  const size_t bs = (size_t)blk * 4 + wid;
#pragma unroll
  for (int cf = 0; cf < 8; ++cf) {
    float s = 0.f, s2 = 0.f, mx = -3.4e38f, mn = 3.4e38f;
    const int col = cf * 16 + lrow;
#pragma unroll
    for (int rf = 0; rf < 2; ++rf)
#pragma unroll
      for (int q = 0; q < 4; ++q) {
        float v = acc[rf][cf][q];
        s += v; s2 += v * v;
        mx = fmaxf(mx, v); mn = fminf(mn, v);
      }
    s += __shfl_xor(s, 16, 64); s += __shfl_xor(s, 32, 64);
    s2 += __shfl_xor(s2, 16, 64); s2 += __shfl_xor(s2, 32, 64);
    mx = fmaxf(mx, __shfl_xor(mx, 16, 64)); mx = fmaxf(mx, __shfl_xor(mx, 32, 64));
    mn = fminf(mn, __shfl_xor(mn, 16, 64)); mn = fminf(mn, __shfl_xor(mn, 32, 64));
    if ((lane >> 4) == 0) {
      ymax[bs * 128 + col] = mx;
      ymin[bs * 128 + col] = mn;
      swsum[wid][col] = s; swsq[wid][col] = s2;
    }
  }
  __syncthreads();
  if (t < 128) {
    float v = swsum[0][t] + swsum[1][t] + swsum[2][t] + swsum[3][t];
    partial[(size_t)t * NBLK_ + blk] = v;
  } else {
    const int c = t - 128;
    float v = swsq[0][c] + swsq[1][c] + swsq[2][c] + swsq[3][c];
    partial[(size_t)t * NBLK_ + blk] = v;
  }
}

// ---------------- final: BN2+ReLU on pooled values ----------------
__global__ __launch_bounds__(256) void final_kernel(
    const float* __restrict__ ymax, const float* __restrict__ ymin,
    const float* __restrict__ ab, float* __restrict__ out) {
  const int gid = blockIdx.x * 256 + threadIdx.x;  // B*S*128
  const int col = gid & 127;
  const float a = ab[col];
  const float v = (a >= 0.f) ? ymax[gid] : ymin[gid];  // monotonicity of BN+ReLU vs sign(a)
  out[gid] = fmaxf(v * a + ab[128 + col], 0.f);
}

extern "C" void kernel_launch(void* const* d_in, const int* in_sizes, int n_in,
                              void* d_out, int out_size, void* d_ws, size_t ws_size,
                              hipStream_t stream) {
  const float* xyz = (const float*)d_in[0];
  const float* points = (const float*)d_in[1];
  const float* w0 = (const float*)d_in[2];
  const float* g0 = (const float*)d_in[4];
  const float* bt0 = (const float*)d_in[5];
  const float* w1 = (const float*)d_in[6];
  const float* g1 = (const float*)d_in[8];
  const float* bt1 = (const float*)d_in[9];
  const float* w2 = (const float*)d_in[10];
  const float* g2 = (const float*)d_in[12];
  const float* bt2 = (const float*)d_in[13];
  float* out = (float*)d_out;
  char* ws = (char*)d_ws;

  float4* sxyzp = (float4*)(ws + 0);       // 2 MB
  __bf16* w0h = (__bf16*)(ws + 2097152);   // 13312 B
  __bf16* w0l = (__bf16*)(ws + 2110464);
  __bf16* w1h = (__bf16*)(ws + 2123776);   // 9216 B
  __bf16* w1l = (__bf16*)(ws + 2132992);
  __bf16* w2h = (__bf16*)(ws + 2142208);   // 18432 B
  __bf16* w2l = (__bf16*)(ws + 2160640);
  int* idx    = (int*)(ws + 2179072);      // 2 MB
  float* y    = (float*)(ws + 4276224);    // 134217728 B (f32, reused L0->L1 in place)
  float* ymax = (float*)(ws + 138493952);  // 8388608
  float* ymin = (float*)(ws + 146882560);  // 8388608
  float* partial = (float*)(ws + 155271168); // 4194304
  float* ab   = (float*)(ws + 159465472);  // 3072
  if (ws_size < 159468544) return;

  prep_kernel<<<592, 256, 0, stream>>>(xyz, w0, w1, w2, sxyzp,
                                       w0h, w0l, w1h, w1l, w2h, w2l);
  fps_kernel<<<16, 512, 0, stream>>>(sxyzp, out);
  ballq_kernel<<<1024, 1024, 0, stream>>>(sxyzp, out, idx);
  layer0_kernel<<<NBLK_, 256, 0, stream>>>(sxyzp, points, out, idx, w0h, w0l, y, partial);
  stat_kernel<<<64, 64, 0, stream>>>(partial, g0, bt0, ab, 64);
  layer1_kernel<<<NBLK_, 256, 0, stream>>>(y, w1h, w1l, ab, partial);
  stat_kernel<<<64, 64, 0, stream>>>(partial, g1, bt1, ab + 256, 64);
  layer2_kernel<<<NBLK_, 256, 0, stream>>>(y, w2h, w2l, ab + 256, ymax, ymin, partial);
  stat_kernel<<<128, 64, 0, stream>>>(partial, g2, bt2, ab + 512, 128);
  final_kernel<<<8192, 256, 0, stream>>>(ymax, ymin, ab + 512, out + 49152);
}

// Round 10
// 1221.588 us; speedup vs baseline: 1.3510x; 1.0322x over previous
//
#include <hip/hip_runtime.h>

// PointNet++ Set Abstraction for MI355X (gfx950).
// prep -> FPS -> ball-query -> L0(mfma) -> stat -> L1 -> stat -> L2(+pool) -> stat -> final.
// FPS replicates reference f32 elementwise arithmetic exactly (non-FMA, same order).
// Ball-query dot uses an FMA chain replicating BLAS sgemm accumulation.
// Activations stored f32; GEMMs use hi/lo split-bf16 MFMA (near-f32).
// R9: FPS loop contains NO global stores (they forced a vmcnt(0) drain at every
// __syncthreads -> ~hundreds of cycles/step). Winner indices go to LDS
// farhist[]; new_xyz written once after the loop.

typedef __bf16 bf16x8 __attribute__((ext_vector_type(8)));
typedef float f32x4 __attribute__((ext_vector_type(4)));
typedef float f32x2 __attribute__((ext_vector_type(2)));

#define B_ 16
#define N_ 8192
#define S_ 1024
#define K_ 32
#define M_ 524288   // B*S*K rows
#define NBLK_ 4096  // M/128

__device__ __forceinline__ f32x4 mfma16(bf16x8 a, bf16x8 b, f32x4 c) {
  return __builtin_amdgcn_mfma_f32_16x16x32_bf16(a, b, c, 0, 0, 0);
}

__device__ __forceinline__ void split8(const float* v, bf16x8& hi, bf16x8& lo) {
#pragma unroll
  for (int e = 0; e < 8; ++e) {
    __bf16 h = (__bf16)v[e];
    hi[e] = h;
    lo[e] = (__bf16)(v[e] - (float)h);
  }
}

// Wave64 max of non-negative f32 via DPP; returns uniform max (all lanes).
// bound_ctrl=true fills invalid lanes with 0 (max-neutral for x >= 0).
__device__ __forceinline__ float wave_max_nonneg(float x) {
  int v = __float_as_int(x);
#define DPP_MAX(ctrl)                                                          \
  v = __float_as_int(fmaxf(__int_as_float(v),                                  \
        __int_as_float(__builtin_amdgcn_update_dpp(0, v, (ctrl), 0xf, 0xf, true))))
  DPP_MAX(0x111);  // row_shr:1
  DPP_MAX(0x112);  // row_shr:2
  DPP_MAX(0x114);  // row_shr:4
  DPP_MAX(0x118);  // row_shr:8
  DPP_MAX(0x142);  // row_bcast:15
  DPP_MAX(0x143);  // row_bcast:31
#undef DPP_MAX
  return __int_as_float(__builtin_amdgcn_readlane(v, 63));
}

// ---------------- prep: packed {x,y,z,|p|^2}, hi/lo split weights ----------------
__global__ __launch_bounds__(256) void prep_kernel(
    const float* __restrict__ xyz, const float* __restrict__ w0,
    const float* __restrict__ w1, const float* __restrict__ w2,
    float4* __restrict__ sxyzp,
    __bf16* __restrict__ w0h, __bf16* __restrict__ w0l,
    __bf16* __restrict__ w1h, __bf16* __restrict__ w1l,
    __bf16* __restrict__ w2h, __bf16* __restrict__ w2l) {
#pragma clang fp contract(off)
  int gid = blockIdx.x * 256 + threadIdx.x;
  if (gid < B_ * N_) {
    float x = xyz[gid * 3 + 0], y = xyz[gid * 3 + 1], z = xyz[gid * 3 + 2];
    float p = (x * x + y * y) + z * z;  // exact reference order
    sxyzp[gid] = make_float4(x, y, z, p);
  } else {
    int j = gid - B_ * N_;
    float v; __bf16* ph; __bf16* pl; int jj;
    if (j < 6656) {            // W0: [64][104], real c<67
      int o = j / 104, c = j % 104;
      v = (c < 67) ? w0[o * 67 + c] : 0.f; ph = w0h; pl = w0l; jj = j;
    } else if (j < 6656 + 4608) {  // W1: [64][72], real c<64
      jj = j - 6656;
      int o = jj / 72, c = jj % 72;
      v = (c < 64) ? w1[o * 64 + c] : 0.f; ph = w1h; pl = w1l;
    } else if (j < 6656 + 4608 + 9216) {  // W2: [128][72]
      jj = j - 6656 - 4608;
      int o = jj / 72, c = jj % 72;
      v = (c < 64) ? w2[o * 64 + c] : 0.f; ph = w2h; pl = w2l;
    } else return;
    __bf16 h = (__bf16)v;
    ph[jj] = h;
    pl[jj] = (__bf16)(v - (float)h);
  }
}

// ---------------- FPS: one block per batch, 512 thr x 16 pts, DPP argmax ----------------
__global__ __launch_bounds__(512, 1) void fps_kernel(
    const float4* __restrict__ sxyzp, float* __restrict__ out /* new_xyz (B,S,3) */) {
#pragma clang fp contract(off)
  const int b = blockIdx.x;
  const int t = threadIdx.x;
  __shared__ float4 sp[N_];                    // 128 KB (centroid lookup)
  __shared__ int farhist[S_];                  // 4 KB winner history
  __shared__ uint2 went[2][8];                 // {val_bits, idx} per wave, double-buffered
  const float4* src = sxyzp + (size_t)b * N_;
  for (int i = t; i < N_; i += 512) sp[i] = src[i];
  __syncthreads();
  // contiguous chunk per lane: thread t owns points [16t, 16t+16), packed in pairs
  f32x2 px[8], py[8], pz[8], dd[8];
  const int i0 = t * 16;
#pragma unroll
  for (int w = 0; w < 16; ++w) {
    float4 v = sp[i0 + w];
    px[w >> 1][w & 1] = v.x; py[w >> 1][w & 1] = v.y; pz[w >> 1][w & 1] = v.z;
  }
#pragma unroll
  for (int j = 0; j < 8; ++j) dd[j] = (f32x2){1e10f, 1e10f};
  const int lane = t & 63, wid = t >> 6;
  int far = 0;
  for (int s = 0; s < S_; ++s) {
    if (t == 0) farhist[s] = far;              // LDS only; no global store in loop
    float4 c = sp[far];
    const f32x2 cx = {c.x, c.x}, cy = {c.y, c.y}, cz = {c.z, c.z};
    f32x2 bv2 = {-1.0f, -1.0f};
#pragma unroll
    for (int j = 0; j < 8; ++j) {
      f32x2 dx = px[j] - cx, dy = py[j] - cy, dz = pz[j] - cz;
      f32x2 d = (dx * dx + dy * dy) + dz * dz;  // exact reference order, no fma
      f32x2 nd = __builtin_elementwise_min(dd[j], d);
      dd[j] = nd;
      bv2 = __builtin_elementwise_max(bv2, nd);
    }
    float bv = fmaxf(bv2[0], bv2[1]);
    // first (lowest) local index equal to bv: descending select keeps lowest w
    int bi = 0;
#pragma unroll
    for (int w = 15; w >= 0; --w) if (dd[w >> 1][w & 1] == bv) bi = i0 + w;
    // wave-wide max via DPP (uniform), then lowest-lane index via SGPR readlane
    float m = wave_max_nonneg(bv);
    unsigned long long msk = __ballot(bv == m);
    int srcl = __ffsll((long long)msk) - 1;          // uniform (SGPR)
    int wbi = __builtin_amdgcn_readlane(bi, srcl);   // uniform
    if (lane == 0) went[s & 1][wid] = make_uint2(__float_as_uint(m), (unsigned)wbi);
    __syncthreads();
    // ascending wave scan, strict >: lowest wave (= lowest index) wins ties.
    // f32 order == u32 order for non-negative distances.
    uint2 bestE = went[s & 1][0];
#pragma unroll
    for (int w = 1; w < 8; ++w) {
      uint2 e = went[s & 1][w];
      if (e.x > bestE.x) bestE = e;
    }
    far = (int)bestE.y;
  }
  __syncthreads();
  // one-time output write from history (exact sp values)
  float* outB = out + (size_t)b * S_ * 3;
  for (int k = t; k < S_; k += 512) {
    float4 v = sp[farhist[k]];
    outB[k * 3 + 0] = v.x; outB[k * 3 + 1] = v.y; outB[k * 3 + 2] = v.z;
  }
}

// ---------------- ball query: 16 queries per block ----------------
__global__ __launch_bounds__(1024) void ballq_kernel(
    const float4* __restrict__ sxyzp, const float* __restrict__ newxyz,
    int* __restrict__ idxout) {
#pragma clang fp contract(off)
  __shared__ float4 sp[N_];                    // 128 KB
  __shared__ int sel[16][32];
  const int t = threadIdx.x;
  const int g = blockIdx.x;
  const int b = g >> 6;
  const int q0 = (g & 63) << 4;
  const float4* srcp = sxyzp + (size_t)b * N_;
  for (int i = t; i < N_; i += 1024) sp[i] = srcp[i];
  __syncthreads();
  const int wid = t >> 6, lane = t & 63;
  const int q = q0 + wid;
  const float* qp = newxyz + ((size_t)b * S_ + q) * 3;
  const float qx = qp[0], qy = qp[1], qz = qp[2];
  const float qq = (qx * qx + qy * qy) + qz * qz;
  const float rr = (float)(0.4 * 0.4);
  int nsel = 0;
  for (int c0 = 0; c0 < N_ && nsel < 32; c0 += 64) {
    int i = c0 + lane;
    float4 v = sp[i];
    // BLAS-style FMA accumulation chain (matches einsum->matmul lowering):
    float dot = fmaf(qz, v.z, fmaf(qy, v.y, qx * v.x));
    float d = -2.0f * dot;
    d = d + qq;
    d = d + v.w;
    unsigned long long m = __ballot(!(d > rr));
    if ((m >> lane) & 1ull) {
      int rank = nsel + __popcll(m & ((1ull << lane) - 1ull));
      if (rank < 32) sel[wid][rank] = i;
    }
    nsel += __popcll(m);
  }
  __syncthreads();
  int nv = nsel < 32 ? nsel : 32;
  int first = sel[wid][0];
  if (lane < 32)
    idxout[(((size_t)b * S_ + q) << 5) + lane] = (lane < nv) ? sel[wid][lane] : first;
}

// ---------------- layer 0: gather+concat -> split GEMM 67->64 (K padded 96) ----------------
__global__ __launch_bounds__(256) void layer0_kernel(
    const float4* __restrict__ sxyzp, const float* __restrict__ points,
    const float* __restrict__ newxyz, const int* __restrict__ idx,
    const __bf16* __restrict__ wh, const __bf16* __restrict__ wl,
    float* __restrict__ yout, float* __restrict__ partial) {
  __shared__ __align__(16) __bf16 Ah[128 * 104];
  __shared__ __align__(16) __bf16 Al[128 * 104];
  __shared__ __align__(16) __bf16 Bh[64 * 104];
  __shared__ __align__(16) __bf16 Bl[64 * 104];
  __shared__ float swsum[4][64], swsq[4][64];
  const int t = threadIdx.x;
  const int blk = blockIdx.x;
  const size_t row0 = (size_t)blk * 128;
  {
    const int4* sh4 = (const int4*)wh;
    const int4* sl4 = (const int4*)wl;
    int4* dh4 = (int4*)Bh;
    int4* dl4 = (int4*)Bl;
    for (int k = t; k < 832; k += 256) { dh4[k] = sh4[k]; dl4[k] = sl4[k]; }
  }
  {
    const int r = t >> 1, half = t & 1;
    const size_t row = row0 + r;
    const int b = (int)(row >> 15);
    const int s = (int)((row >> 5) & 1023);
    const int i = idx[row];
    const size_t bi = (size_t)b * N_ + i;
    const float* pt = points + bi * 64;
    const float* nx = newxyz + ((size_t)b * S_ + s) * 3;
    const int jb = half ? 6 : 0, je = half ? 13 : 6;
    float gx = 0.f, gy = 0.f, gz = 0.f;
    if (!half) {
      float4 xv = sxyzp[bi];
      gx = xv.x - nx[0]; gy = xv.y - nx[1]; gz = xv.z - nx[2];
    }
#pragma unroll 13
    for (int j = jb; j < je; ++j) {
      float v[8];
#pragma unroll
      for (int e = 0; e < 8; ++e) {
        const int c = j * 8 + e;
        v[e] = (c == 0) ? gx : (c == 1) ? gy : (c == 2) ? gz
               : (c < 67) ? pt[c - 3] : 0.f;
      }
      bf16x8 hi, lo;
      split8(v, hi, lo);
      *(bf16x8*)(Ah + r * 104 + j * 8) = hi;
      *(bf16x8*)(Al + r * 104 + j * 8) = lo;
    }
  }
  __syncthreads();
  const int wid = t >> 6, lane = t & 63;
  const int wrow = wid * 32;
  const int lrow = lane & 15, lk = (lane >> 4) * 8;
  f32x4 acc[2][4];
#pragma unroll
  for (int a_ = 0; a_ < 2; ++a_)
#pragma unroll
    for (int b_ = 0; b_ < 4; ++b_) acc[a_][b_] = (f32x4){0.f, 0.f, 0.f, 0.f};
#pragma unroll
  for (int ks = 0; ks < 3; ++ks) {
    const int ko = ks * 32 + lk;
    bf16x8 ah0 = *(const bf16x8*)(Ah + (wrow + lrow) * 104 + ko);
    bf16x8 al0 = *(const bf16x8*)(Al + (wrow + lrow) * 104 + ko);
    bf16x8 ah1 = *(const bf16x8*)(Ah + (wrow + 16 + lrow) * 104 + ko);
    bf16x8 al1 = *(const bf16x8*)(Al + (wrow + 16 + lrow) * 104 + ko);
#pragma unroll
    for (int cf = 0; cf < 4; ++cf) {
      bf16x8 bh = *(const bf16x8*)(Bh + (cf * 16 + lrow) * 104 + ko);
      bf16x8 bl = *(const bf16x8*)(Bl + (cf * 16 + lrow) * 104 + ko);
      acc[0][cf] = mfma16(ah0, bh, acc[0][cf]);
      acc[0][cf] = mfma16(al0, bh, acc[0][cf]);
      acc[0][cf] = mfma16(ah0, bl, acc[0][cf]);
      acc[1][cf] = mfma16(ah1, bh, acc[1][cf]);
      acc[1][cf] = mfma16(al1, bh, acc[1][cf]);
      acc[1][cf] = mfma16(ah1, bl, acc[1][cf]);
    }
  }
#pragma unroll
  for (int cf = 0; cf < 4; ++cf) {
    float s = 0.f, s2 = 0.f;
    const int col = cf * 16 + lrow;
#pragma unroll
    for (int rf = 0; rf < 2; ++rf) {
      const int rbase = wrow + rf * 16 + (lane >> 4) * 4;
#pragma unroll
      for (int q = 0; q < 4; ++q) {
        float v = acc[rf][cf][q];
        yout[(row0 + rbase + q) * 64 + col] = v;
        s += v; s2 += v * v;
      }
    }
    s += __shfl_xor(s, 16, 64); s += __shfl_xor(s, 32, 64);
    s2 += __shfl_xor(s2, 16, 64); s2 += __shfl_xor(s2, 32, 64);
    if ((lane >> 4) == 0) { swsum[wid][col] = s; swsq[wid][col] = s2; }
  }
  __syncthreads();
  if (t < 128) {
    const int c = t & 63;
    float v = (t < 64) ? (swsum[0][c] + swsum[1][c] + swsum[2][c] + swsum[3][c])
                       : (swsq[0][c] + swsq[1][c] + swsq[2][c] + swsq[3][c]);
    partial[(size_t)t * NBLK_ + blk] = v;
  }
}

// ---------------- stat: mean/var -> (a, shift) ----------------
__global__ __launch_bounds__(64) void stat_kernel(
    const float* __restrict__ partial, const float* __restrict__ g,
    const float* __restrict__ bt, float* __restrict__ ab, int nch) {
  const int o = blockIdx.x, t = threadIdx.x;
  float s = 0.f, s2 = 0.f;
  for (int i = t; i < NBLK_; i += 64) {
    s += partial[(size_t)o * NBLK_ + i];
    s2 += partial[(size_t)(nch + o) * NBLK_ + i];
  }
#pragma unroll
  for (int off = 32; off >= 1; off >>= 1) {
    s += __shfl_xor(s, off, 64);
    s2 += __shfl_xor(s2, off, 64);
  }
  if (t == 0) {
    const float minv = 1.0f / (float)M_;
    float mean = s * minv;
    float var = s2 * minv - mean * mean;
    float a = g[o] * rsqrtf(var + 1e-5f);
    ab[o] = a;
    ab[128 + o] = bt[o] - mean * a;
  }
}

// ---------------- layer 1: BN0+ReLU on load -> split GEMM 64->64 (in-place y) ----------------
__global__ __launch_bounds__(256) void layer1_kernel(
    float* y /* f32 activations, read rows then overwritten (same block) */,
    const __bf16* __restrict__ wh, const __bf16* __restrict__ wl,
    const float* __restrict__ ab, float* __restrict__ partial) {
  __shared__ __align__(16) __bf16 Ah[128 * 72];
  __shared__ __align__(16) __bf16 Al[128 * 72];
  __shared__ __align__(16) __bf16 Bh[64 * 72];
  __shared__ __align__(16) __bf16 Bl[64 * 72];
  __shared__ float sa[64], sb[64];
  __shared__ float swsum[4][64], swsq[4][64];
  const int t = threadIdx.x;
  const int blk = blockIdx.x;
  const size_t row0 = (size_t)blk * 128;
  if (t < 64) { sa[t] = ab[t]; sb[t] = ab[128 + t]; }
  {
    const int4* sh4 = (const int4*)wh;
    const int4* sl4 = (const int4*)wl;
    int4* dh4 = (int4*)Bh;
    int4* dl4 = (int4*)Bl;
    for (int k = t; k < 576; k += 256) { dh4[k] = sh4[k]; dl4[k] = sl4[k]; }
  }
  __syncthreads();
  {
    const int r = t >> 1, half = t & 1;
    const float4* s4 = (const float4*)(y + (row0 + r) * 64 + half * 32);
#pragma unroll
    for (int j = 0; j < 4; ++j) {
      float4 u = s4[j * 2], w = s4[j * 2 + 1];
      float v[8] = {u.x, u.y, u.z, u.w, w.x, w.y, w.z, w.w};
#pragma unroll
      for (int e = 0; e < 8; ++e) {
        const int c = half * 32 + j * 8 + e;
        v[e] = fmaxf(v[e] * sa[c] + sb[c], 0.f);
      }
      bf16x8 hi, lo;
      split8(v, hi, lo);
      *(bf16x8*)(Ah + r * 72 + half * 32 + j * 8) = hi;
      *(bf16x8*)(Al + r * 72 + half * 32 + j * 8) = lo;
    }
  }
  __syncthreads();
  const int wid = t >> 6, lane = t & 63;
  const int wrow = wid * 32;
  const int lrow = lane & 15, lk = (lane >> 4) * 8;
  f32x4 acc[2][4];
#pragma unroll
  for (int a_ = 0; a_ < 2; ++a_)
#pragma unroll
    for (int b_ = 0; b_ < 4; ++b_) acc[a_][b_] = (f32x4){0.f, 0.f, 0.f, 0.f};
#pragma unroll
  for (int ks = 0; ks < 2; ++ks) {
    const int ko = ks * 32 + lk;
    bf16x8 ah0 = *(const bf16x8*)(Ah + (wrow + lrow) * 72 + ko);
    bf16x8 al0 = *(const bf16x8*)(Al + (wrow + lrow) * 72 + ko);
    bf16x8 ah1 = *(const bf16x8*)(Ah + (wrow + 16 + lrow) * 72 + ko);
    bf16x8 al1 = *(const bf16x8*)(Al + (wrow + 16 + lrow) * 72 + ko);
#pragma unroll
    for (int cf = 0; cf < 4; ++cf) {
      bf16x8 bh = *(const bf16x8*)(Bh + (cf * 16 + lrow) * 72 + ko);
      bf16x8 bl = *(const bf16x8*)(Bl + (cf * 16 + lrow) * 72 + ko);
      acc[0][cf] = mfma16(ah0, bh, acc[0][cf]);
      acc[0][cf] = mfma16(al0, bh, acc[0][cf]);
      acc[0][cf] = mfma16(ah0, bl, acc[0][cf]);
      acc[1][cf] = mfma16(ah1, bh, acc[1][cf]);
      acc[1][cf] = mfma16(al1, bh, acc[1][cf]);
      acc[1][cf] = mfma16(ah1, bl, acc[1][cf]);
    }
  }
#pragma unroll
  for (int cf = 0; cf < 4; ++cf) {
    float s = 0.f, s2 = 0.f;
    const int col = cf * 16 + lrow;
#pragma unroll
    for (int rf = 0; rf < 2; ++rf) {
      const int rbase = wrow + rf * 16 + (lane >> 4) * 4;
#pragma unroll
      for (int q = 0; q < 4; ++q) {
        float v = acc[rf][cf][q];
        y[(row0 + rbase + q) * 64 + col] = v;
        s += v; s2 += v * v;
      }
    }
    s += __shfl_xor(s, 16, 64); s += __shfl_xor(s, 32, 64);
    s2 += __shfl_xor(s2, 16, 64); s2 += __shfl_xor(s2, 32, 64);
    if ((lane >> 4) == 0) { swsum[wid][col] = s; swsq[wid][col] = s2; }
  }
  __syncthreads();
  if (t < 128) {
    const int c = t & 63;
    float v = (t < 64) ? (swsum[0][c] + swsum[1][c] + swsum[2][c] + swsum[3][c])
                       : (swsq[0][c] + swsq[1][c] + swsq[2][c] + swsq[3][c]);
    partial[(size_t)t * NBLK_ + blk] = v;
  }
}

// ---------------- layer 2: BN1+ReLU -> split GEMM 64->128 + fused max/min pool ----------------
__global__ __launch_bounds__(256) void layer2_kernel(
    const float* __restrict__ yin, const __bf16* __restrict__ wh,
    const __bf16* __restrict__ wl, const float* __restrict__ ab,
    float* __restrict__ ymax, float* __restrict__ ymin,
    float* __restrict__ partial) {
  __shared__ __align__(16) __bf16 Ah[128 * 72];
  __shared__ __align__(16) __bf16 Al[128 * 72];
  __shared__ __align__(16) __bf16 Bh[128 * 72];
  __shared__ __align__(16) __bf16 Bl[128 * 72];
  __shared__ float sa[64], sb[64];
  __shared__ float swsum[4][128], swsq[4][128];
  const int t = threadIdx.x;
  const int blk = blockIdx.x;
  const size_t row0 = (size_t)blk * 128;
  if (t < 64) { sa[t] = ab[t]; sb[t] = ab[128 + t]; }
  {
    const int4* sh4 = (const int4*)wh;
    const int4* sl4 = (const int4*)wl;
    int4* dh4 = (int4*)Bh;
    int4* dl4 = (int4*)Bl;
    for (int k = t; k < 1152; k += 256) { dh4[k] = sh4[k]; dl4[k] = sl4[k]; }
  }
  __syncthreads();
  {
    const int r = t >> 1, half = t & 1;
    const float4* s4 = (const float4*)(yin + (row0 + r) * 64 + half * 32);
#pragma unroll
    for (int j = 0; j < 4; ++j) {
      float4 u = s4[j * 2], w = s4[j * 2 + 1];
      float v[8] = {u.x, u.y, u.z, u.w, w.x, w.y, w.z, w.w};
#pragma unroll
      for (int e = 0; e < 8; ++e) {
        const int c = half * 32 + j * 8 + e;
        v[e] = fmaxf(v[e] * sa[c] + sb[c], 0.f);
      }
      bf16x8 hi, lo;
      split8(v, hi, lo);
      *(bf16x8*)(Ah + r * 72 + half * 32 + j * 8) = hi;
      *(bf16x8*)(Al + r * 72 + half * 32 + j * 8) = lo;
    }
  }
  __syncthreads();
  const int wid = t >> 6, lane = t & 63;
  const int wrow = wid * 32;
  const int lrow = lane & 15, lk = (lane >> 4) * 8;
  f32x4 acc[2][8];
#pragma unroll
  for (int a_ = 0; a_ < 2; ++a_)
#pragma unroll
    for (int b_ = 0; b_ < 8; ++b_) acc[a_][b_] = (f32x4){0.f, 0.f, 0.f, 0.f};
#pragma unroll
  for (int ks = 0; ks < 2; ++ks) {
    const int ko = ks * 32 + lk;
    bf16x8 ah0 = *(const bf16x8*)(Ah + (wrow + lrow) * 72 + ko);
    bf16x8 al0 = *(const bf16x8*)(Al + (wrow + lrow) * 72 + ko);
    bf16x8 ah1 = *(const bf16x8*)(Ah + (wrow + 16 + lrow) * 72 + ko);
    bf16x8 al1 = *(const bf16x8*)(Al + (wrow + 16 + lrow) * 72 + ko);
#pragma unroll
    for (int cf = 0; cf < 8; ++cf) {
      bf16x8 bh = *(const bf16x8*)(Bh + (cf * 16 + lrow) * 72 + ko);
      bf16x8 bl = *(const bf16x8*)(Bl + (cf * 16 + lrow) * 72 + ko);
      acc[0][cf] = mfma16(ah0, bh, acc[0][cf]);
      acc[0][cf] = mfma16(al0, bh, acc[0][cf]);
      acc[0][cf] = mfma16(ah0, bl, acc[0][cf]);
      acc[1][cf] = mfma16(ah1, bh, acc[1][cf]);
      acc[1][cf] = mfma16(al1, bh, acc[1][cf]);
      acc[1][cf] = mfma16(ah1, bl, acc[1][cf]);
    }
  }
  // each wave's 32 rows form exactly one (b,s) group
  const size_t bs = (size_t)blk * 4 + wid;
#pragma unroll
  for (int cf = 0; cf < 8; ++cf) {
    float s = 0.f, s2 = 0.f, mx = -3.4e38f, mn = 3.4e38f;
    const int col = cf * 16 + lrow;
#pragma unroll
    for (int rf = 0; rf < 2; ++rf)
#pragma unroll
      for (int q = 0; q < 4; ++q) {
        float v = acc[rf][cf][q];
        s += v; s2 += v * v;
        mx = fmaxf(mx, v); mn = fminf(mn, v);
      }
    s += __shfl_xor(s, 16, 64); s += __shfl_xor(s, 32, 64);
    s2 += __shfl_xor(s2, 16, 64); s2 += __shfl_xor(s2, 32, 64);
    mx = fmaxf(mx, __shfl_xor(mx, 16, 64)); mx = fmaxf(mx, __shfl_xor(mx, 32, 64));
    mn = fminf(mn, __shfl_xor(mn, 16, 64)); mn = fminf(mn, __shfl_xor(mn, 32, 64));
    if ((lane >> 4) == 0) {
      ymax[bs * 128 + col] = mx;
      ymin[bs * 128 + col] = mn;
      swsum[wid][col] = s; swsq[wid][col] = s2;
    }
  }
  __syncthreads();
  if (t < 128) {
    float v = swsum[0][t] + swsum[1][t] + swsum[2][t] + swsum[3][t];
    partial[(size_t)t * NBLK_ + blk] = v;
  } else {
    const int c = t - 128;
    float v = swsq[0][c] + swsq[1][c] + swsq[2][c] + swsq[3][c];
    partial[(size_t)t * NBLK_ + blk] = v;
  }
}

// ---------------- final: BN2+ReLU on pooled values ----------------
__global__ __launch_bounds__(256) void final_kernel(
    const float* __restrict__ ymax, const float* __restrict__ ymin,
    const float* __restrict__ ab, float* __restrict__ out) {
  const int gid = blockIdx.x * 256 + threadIdx.x;  // B*S*128
  const int col = gid & 127;
  const float a = ab[col];
  const float v = (a >= 0.f) ? ymax[gid] : ymin[gid];  // monotonicity of BN+ReLU vs sign(a)
  out[gid] = fmaxf(v * a + ab[128 + col], 0.f);
}

extern "C" void kernel_launch(void* const* d_in, const int* in_sizes, int n_in,
                              void* d_out, int out_size, void* d_ws, size_t ws_size,
                              hipStream_t stream) {
  const float* xyz = (const float*)d_in[0];
  const float* points = (const float*)d_in[1];
  const float* w0 = (const float*)d_in[2];
  const float* g0 = (const float*)d_in[4];
  const float* bt0 = (const float*)d_in[5];
  const float* w1 = (const float*)d_in[6];
  const float* g1 = (const float*)d_in[8];
  const float* bt1 = (const float*)d_in[9];
  const float* w2 = (const float*)d_in[10];
  const float* g2 = (const float*)d_in[12];
  const float* bt2 = (const float*)d_in[13];
  float* out = (float*)d_out;
  char* ws = (char*)d_ws;

  float4* sxyzp = (float4*)(ws + 0);       // 2 MB
  __bf16* w0h = (__bf16*)(ws + 2097152);   // 13312 B
  __bf16* w0l = (__bf16*)(ws + 2110464);
  __bf16* w1h = (__bf16*)(ws + 2123776);   // 9216 B
  __bf16* w1l = (__bf16*)(ws + 2132992);
  __bf16* w2h = (__bf16*)(ws + 2142208);   // 18432 B
  __bf16* w2l = (__bf16*)(ws + 2160640);
  int* idx    = (int*)(ws + 2179072);      // 2 MB
  float* y    = (float*)(ws + 4276224);    // 134217728 B (f32, reused L0->L1 in place)
  float* ymax = (float*)(ws + 138493952);  // 8388608
  float* ymin = (float*)(ws + 146882560);  // 8388608
  float* partial = (float*)(ws + 155271168); // 4194304
  float* ab   = (float*)(ws + 159465472);  // 3072
  if (ws_size < 159468544) return;

  prep_kernel<<<592, 256, 0, stream>>>(xyz, w0, w1, w2, sxyzp,
                                       w0h, w0l, w1h, w1l, w2h, w2l);
  fps_kernel<<<16, 512, 0, stream>>>(sxyzp, out);
  ballq_kernel<<<1024, 1024, 0, stream>>>(sxyzp, out, idx);
  layer0_kernel<<<NBLK_, 256, 0, stream>>>(sxyzp, points, out, idx, w0h, w0l, y, partial);
  stat_kernel<<<64, 64, 0, stream>>>(partial, g0, bt0, ab, 64);
  layer1_kernel<<<NBLK_, 256, 0, stream>>>(y, w1h, w1l, ab, partial);
  stat_kernel<<<64, 64, 0, stream>>>(partial, g1, bt1, ab + 256, 64);
  layer2_kernel<<<NBLK_, 256, 0, stream>>>(y, w2h, w2l, ab + 256, ymax, ymin, partial);
  stat_kernel<<<128, 64, 0, stream>>>(partial, g2, bt2, ab + 512, 128);
  final_kernel<<<8192, 256, 0, stream>>>(ymax, ymin, ab + 512, out + 49152);
}